// Round 1
// baseline (5454.699 us; speedup 1.0000x reference)
//
#include <hip/hip_runtime.h>
#include <math.h>

// ---------------- problem constants ----------------
// B=512, L=600, DIM=256, H=8, chunks: 22 x 75 step 25
// conv1: 1->64 k26 (len 75->50), conv2: 64->128 k26 (50->25), conv3: 128->256 k25 (25->1)
// NSEQ = 2*512*22 = 22528 sequences of 75 samples.

#define NSEQ 22528
#define HALFSEQ 11264

// ---------------- setup: transposes ----------------
// out (Bn, C, R): out[b][c][r] = in[b][r][c]
__global__ void k_transpose(const float* __restrict__ in, float* __restrict__ out,
                            int Bn, int R, int C) {
    int idx = blockIdx.x * 256 + threadIdx.x;
    int total = Bn * R * C;
    if (idx >= total) return;
    int b = idx / (R * C);
    int rem = idx - b * R * C;
    int c = rem / R;
    int r = rem - c * R;
    out[idx] = in[(b * R + r) * C + c];
}

// ---------------- setup: M = Wq Wk^T, qb, kb, c ----------------
// grid 2048 = (h*256 + e), 256 threads (f)
__global__ __launch_bounds__(256) void k_prep_attn(
    const float* __restrict__ Wq, const float* __restrict__ bq,
    const float* __restrict__ Wk, const float* __restrict__ bk,
    const float* __restrict__ WkT,
    float* __restrict__ M, float* __restrict__ qb, float* __restrict__ kb,
    float* __restrict__ cvec)
{
    int bid = blockIdx.x;
    int h = bid >> 8;
    int e = bid & 255;
    int t = threadIdx.x;
    __shared__ float qrow[256];
    __shared__ float krow[256];
    __shared__ float red[256];
    qrow[t] = Wq[(h * 256 + e) * 256 + t];
    krow[t] = Wk[(h * 256 + e) * 256 + t];
    __syncthreads();

    // M[h][e][f] = sum_o Wq[h][e][o] * Wk[h][f][o] = sum_o qrow[o]*WkT[h][o][f]
    const float* wkt = WkT + h * 65536;
    float a0 = 0.f, a1 = 0.f, a2 = 0.f, a3 = 0.f;
    for (int o = 0; o < 256; o += 4) {
        a0 += qrow[o + 0] * wkt[(o + 0) * 256 + t];
        a1 += qrow[o + 1] * wkt[(o + 1) * 256 + t];
        a2 += qrow[o + 2] * wkt[(o + 2) * 256 + t];
        a3 += qrow[o + 3] * wkt[(o + 3) * 256 + t];
    }
    M[(h * 256 + e) * 256 + t] = (a0 + a1) + (a2 + a3);

    // qb[h][e] = qrow . bk[h];  kb[h][e] = krow . bq[h]
    float p1 = qrow[t] * bk[h * 256 + t];
    float p2 = krow[t] * bq[h * 256 + t];
    red[t] = p1; __syncthreads();
    for (int s2 = 128; s2 > 0; s2 >>= 1) { if (t < s2) red[t] += red[t + s2]; __syncthreads(); }
    if (t == 0) qb[h * 256 + e] = red[0];
    __syncthreads();
    red[t] = p2; __syncthreads();
    for (int s2 = 128; s2 > 0; s2 >>= 1) { if (t < s2) red[t] += red[t + s2]; __syncthreads(); }
    if (t == 0) kb[h * 256 + e] = red[0];
    if (e == 0) {
        __syncthreads();
        red[t] = bq[h * 256 + t] * bk[h * 256 + t]; __syncthreads();
        for (int s2 = 128; s2 > 0; s2 >>= 1) { if (t < s2) red[t] += red[t + s2]; __syncthreads(); }
        if (t == 0) cvec[h] = red[0];
    }
}

// ---------------- fused conv stack ----------------
// grid 5632 blocks x 256 threads; each block handles 4 sequences.
// LDS: a1 one-seq [64][52] (pad 52 => 208B rows, 16B aligned), a2 4x[128*25] flat.
__global__ __launch_bounds__(256) void k_conv(
    const float* __restrict__ av1, const float* __restrict__ av2,
    const float* __restrict__ w1, const float* __restrict__ b1c,
    const float* __restrict__ g1, const float* __restrict__ be1,
    const float* __restrict__ m1, const float* __restrict__ v1,
    const float* __restrict__ w2T, const float* __restrict__ b2c,
    const float* __restrict__ g2, const float* __restrict__ be2,
    const float* __restrict__ m2, const float* __restrict__ v2,
    const float* __restrict__ w3T, const float* __restrict__ b3c,
    const float* __restrict__ g3, const float* __restrict__ be3,
    const float* __restrict__ m3, const float* __restrict__ v3,
    float* __restrict__ feat)
{
    __shared__ __align__(16) float s_a1[64 * 52];
    __shared__ __align__(16) float s_a2[4 * 3200];
    __shared__ float s_x[4][80];
    __shared__ float s_sc1[64], s_sh1[64], s_sc2[128], s_sh2[128];

    const int tid = threadIdx.x;
    const int seq0 = blockIdx.x * 4;

    // ---- stage inputs + folded BN params ----
    for (int j = 0; j < 4; ++j) {
        int seq = seq0 + j;
        const float* src;
        if (seq < HALFSEQ) {
            int b = seq / 22; int n = seq - b * 22;
            src = av1 + b * 600 + n * 25;
        } else {
            int s2 = seq - HALFSEQ;
            int b = s2 / 22; int n = s2 - b * 22;
            src = av2 + b * 600 + n * 25;
        }
        if (tid < 75) s_x[j][tid] = src[tid];
    }
    if (tid < 64) {
        float A = g1[tid] * rsqrtf(v1[tid] + 1e-5f);
        s_sc1[tid] = A;
        s_sh1[tid] = (b1c[tid] - m1[tid]) * A + be1[tid];
    } else if (tid < 192) {
        int o = tid - 64;
        float A = g2[o] * rsqrtf(v2[o] + 1e-5f);
        s_sc2[o] = A;
        s_sh2[o] = (b2c[o] - m2[o]) * A + be2[o];
    }
    __syncthreads();

    // ---- per sequence: conv1 then conv2 ----
    for (int j = 0; j < 4; ++j) {
        // conv1: 64 ch x 50 pos, k=26
        for (int idx = tid; idx < 3200; idx += 256) {
            int o = idx / 50;
            int p = idx - o * 50;
            const float* wr = w1 + o * 26;
            float s = 0.f;
            #pragma unroll
            for (int t = 0; t < 26; ++t) s += wr[t] * s_x[j][p + t];
            s = s * s_sc1[o] + s_sh1[o];
            s = s / (1.f + __expf(-s));
            s_a1[o * 52 + p] = s;
        }
        __syncthreads();

        // conv2: 128 ch x 25 pos, k=26, 64 in-ch.
        // o = tid&127; wave-half hh splits p-range [0,13) / [12,25) (p=12 overlap benign)
        {
            int o = tid & 127;
            int hh = tid >> 7;   // wave-uniform
            float acc[13];
            #pragma unroll
            for (int p = 0; p < 13; ++p) acc[p] = 0.f;
            const float* wbase = w2T + o;   // w2T[(i*26+t)*128 + o]
            for (int i = 0; i < 64; ++i) {
                float rb[52];
                const float4* rp = (const float4*)(s_a1 + i * 52);
                #pragma unroll
                for (int q = 0; q < 13; ++q) ((float4*)rb)[q] = rp[q];
                const float* wi = wbase + i * (26 * 128);
                if (hh == 0) {
                    #pragma unroll
                    for (int t = 0; t < 26; ++t) {
                        float w = wi[t * 128];
                        #pragma unroll
                        for (int p = 0; p < 13; ++p) acc[p] += w * rb[p + t];
                    }
                } else {
                    #pragma unroll
                    for (int t = 0; t < 26; ++t) {
                        float w = wi[t * 128];
                        #pragma unroll
                        for (int p = 0; p < 13; ++p) acc[p] += w * rb[12 + p + t];
                    }
                }
            }
            float A = s_sc2[o], C = s_sh2[o];
            int p0 = hh * 12;
            #pragma unroll
            for (int p = 0; p < 13; ++p) {
                float y = acc[p] * A + C;
                y = y / (1.f + __expf(-y));
                s_a2[j * 3200 + o * 25 + p0 + p] = y;
            }
        }
        __syncthreads();
    }

    // ---- conv3: 256 out-ch, K = 128*25 = 3200 flat, batched over 4 seqs ----
    {
        float accs[4];
        #pragma unroll
        for (int j2 = 0; j2 < 4; ++j2) accs[j2] = 0.f;
        const float* w3c = w3T + tid;   // w3T[k*256 + o]
        #pragma unroll 2
        for (int k = 0; k < 3200; k += 4) {
            float wA = w3c[(k + 0) * 256];
            float wB = w3c[(k + 1) * 256];
            float wC = w3c[(k + 2) * 256];
            float wD = w3c[(k + 3) * 256];
            #pragma unroll
            for (int j2 = 0; j2 < 4; ++j2) {
                float4 x4 = *(const float4*)(s_a2 + j2 * 3200 + k);
                accs[j2] += wA * x4.x + wB * x4.y + wC * x4.z + wD * x4.w;
            }
        }
        float A = g3[tid] * rsqrtf(v3[tid] + 1e-5f);
        float C = (b3c[tid] - m3[tid]) * A + be3[tid];
        #pragma unroll
        for (int j2 = 0; j2 < 4; ++j2) {
            float y = accs[j2] * A + C;
            y = y / (1.f + __expf(-y));
            feat[(size_t)(seq0 + j2) * 256 + tid] = y;
        }
    }
}

// ---------------- attention (per g,h), pooled-O trick ----------------
// grid 8192 = g*8 + h, 256 threads.
__global__ __launch_bounds__(256) void k_attn(
    const float* __restrict__ feat, const float* __restrict__ M,
    const float* __restrict__ qb, const float* __restrict__ kb,
    const float* __restrict__ cvec,
    const float* __restrict__ Wv, const float* __restrict__ bv,
    float* __restrict__ Obar)
{
    const int bid = blockIdx.x;
    const int g = bid >> 3;
    const int h = bid & 7;
    const int tid = threadIdx.x;
    const int FS = 260;   // feat row pad (breaks stride-1024B bank pathology)

    __shared__ __align__(16) float fL[22 * 260];
    __shared__ __align__(16) float gL[22 * 260];
    __shared__ float sS[22 * 24];
    __shared__ float sal[22], sbe[22], sab[22];
    __shared__ __align__(16) float sfb[256];

    const float* fsrc = feat + (size_t)g * 22 * 256;
    for (int idx = tid; idx < 5632; idx += 256) {
        int s = idx >> 8;
        int e = idx & 255;
        fL[s * FS + e] = fsrc[idx];
    }
    __syncthreads();

    // G[s][o] = sum_e fL[s][e] * M[h][e][o]   (o = tid)
    {
        float acc[22];
        #pragma unroll
        for (int s = 0; s < 22; ++s) acc[s] = 0.f;
        const float* Mh = M + h * 65536 + tid;
        for (int e = 0; e < 256; e += 4) {
            float w0 = Mh[(e + 0) * 256];
            float w1 = Mh[(e + 1) * 256];
            float w2 = Mh[(e + 2) * 256];
            float w3 = Mh[(e + 3) * 256];
            #pragma unroll
            for (int s = 0; s < 22; ++s) {
                float4 f4 = *(const float4*)(fL + s * FS + e);
                acc[s] += f4.x * w0 + f4.y * w1 + f4.z * w2 + f4.w * w3;
            }
        }
        #pragma unroll
        for (int s = 0; s < 22; ++s) gL[s * FS + tid] = acc[s];
    }
    // alpha[s] = fL[s] . qb[h];  beta[t] = fL[t] . kb[h]
    if (tid < 22) {
        const float* qbh = qb + h * 256;
        float a = 0.f;
        for (int e = 0; e < 256; ++e) a += fL[tid * FS + e] * qbh[e];
        sal[tid] = a;
    } else if (tid >= 64 && tid < 86) {
        int s = tid - 64;
        const float* kbh = kb + h * 256;
        float a = 0.f;
        for (int e = 0; e < 256; ++e) a += fL[s * FS + e] * kbh[e];
        sbe[s] = a;
    }
    __syncthreads();

    // S[s][t] = G[s] . fL[t] + alpha[s] + beta[t] + c
    float cval = cvec[h];
    for (int idx = tid; idx < 484; idx += 256) {
        int s = idx / 22;
        int t = idx - s * 22;
        const float* gr = gL + s * FS;
        const float* fr = fL + t * FS;
        float acc = 0.f;
        for (int e = 0; e < 256; e += 4) {
            float4 g4 = *(const float4*)(gr + e);
            float4 f4 = *(const float4*)(fr + e);
            acc += g4.x * f4.x + g4.y * f4.y + g4.z * f4.z + g4.w * f4.w;
        }
        sS[s * 24 + t] = acc + sal[s] + sbe[t] + cval;
    }
    __syncthreads();

    // softmax rows, then Abar[t] = mean_s A[s][t]
    if (tid < 22) {
        int s = tid;
        float mx = -1e30f;
        #pragma unroll
        for (int t = 0; t < 22; ++t) mx = fmaxf(mx, sS[s * 24 + t]);
        float ex[22];
        float sum = 0.f;
        #pragma unroll
        for (int t = 0; t < 22; ++t) { float e2 = __expf(sS[s * 24 + t] - mx); ex[t] = e2; sum += e2; }
        float inv = 1.f / sum;
        #pragma unroll
        for (int t = 0; t < 22; ++t) sS[s * 24 + t] = ex[t] * inv;
    }
    __syncthreads();
    if (tid < 22) {
        int t = tid;
        float a = 0.f;
        #pragma unroll
        for (int s = 0; s < 22; ++s) a += sS[s * 24 + t];
        sab[t] = a * (1.f / 22.f);
    }
    __syncthreads();

    // fbar[e] = sum_t Abar[t] * fL[t][e]   (e = tid)
    {
        float a = 0.f;
        #pragma unroll
        for (int t = 0; t < 22; ++t) a += sab[t] * fL[t * FS + tid];
        sfb[tid] = a;
    }
    __syncthreads();

    // Obar[g][h*256+o] = sum_e fbar[e]*Wv[h][e][o] + bv[h][o]  (sum_t Abar = 1)
    {
        const float* wv = Wv + h * 65536 + tid;
        float acc = bv[h * 256 + tid];
        for (int e = 0; e < 256; e += 4) {
            float4 fb4 = *(const float4*)(sfb + e);
            acc += fb4.x * wv[(e + 0) * 256] + fb4.y * wv[(e + 1) * 256]
                 + fb4.z * wv[(e + 2) * 256] + fb4.w * wv[(e + 3) * 256];
        }
        Obar[(size_t)g * 2048 + h * 256 + tid] = acc;
    }
}

// ---------------- head: pooled = Obar @ fca_w + fca_b; y = pooled @ fc_w + fc_b ----------------
// grid 1024 (g), 256 threads (d)
__global__ __launch_bounds__(256) void k_head(
    const float* __restrict__ Obar,
    const float* __restrict__ fca_w, const float* __restrict__ fca_b,
    const float* __restrict__ fc_w, const float* __restrict__ fc_b,
    float* __restrict__ out)
{
    const int g = blockIdx.x;
    const int tid = threadIdx.x;
    __shared__ __align__(16) float so[2048];
    __shared__ __align__(16) float sp[256];
    for (int idx = tid; idx < 2048; idx += 256) so[idx] = Obar[(size_t)g * 2048 + idx];
    __syncthreads();
    float acc = fca_b[tid];
    const float* wc = fca_w + tid;
    for (int k = 0; k < 2048; k += 4) {
        float4 o4 = *(const float4*)(so + k);
        acc += o4.x * wc[(k + 0) * 256] + o4.y * wc[(k + 1) * 256]
             + o4.z * wc[(k + 2) * 256] + o4.w * wc[(k + 3) * 256];
    }
    sp[tid] = acc;
    __syncthreads();
    float y = fc_b[tid];
    const float* wf = fc_w + tid;
    for (int e = 0; e < 256; e += 4) {
        float4 p4 = *(const float4*)(sp + e);
        y += p4.x * wf[(e + 0) * 256] + p4.y * wf[(e + 1) * 256]
           + p4.z * wf[(e + 2) * 256] + p4.w * wf[(e + 3) * 256];
    }
    out[(size_t)g * 256 + tid] = y;
}

// ---------------- launch ----------------
extern "C" void kernel_launch(void* const* d_in, const int* in_sizes, int n_in,
                              void* d_out, int out_size, void* d_ws, size_t ws_size,
                              hipStream_t stream) {
    (void)in_sizes; (void)n_in; (void)out_size; (void)ws_size;

    const float* av1   = (const float*)d_in[0];
    const float* av2   = (const float*)d_in[1];
    const float* w1    = (const float*)d_in[2];
    const float* b1c   = (const float*)d_in[3];
    const float* g1    = (const float*)d_in[4];
    const float* be1   = (const float*)d_in[5];
    const float* m1    = (const float*)d_in[6];
    const float* v1    = (const float*)d_in[7];
    const float* w2    = (const float*)d_in[8];
    const float* b2c   = (const float*)d_in[9];
    const float* g2    = (const float*)d_in[10];
    const float* be2   = (const float*)d_in[11];
    const float* m2    = (const float*)d_in[12];
    const float* v2    = (const float*)d_in[13];
    const float* w3    = (const float*)d_in[14];
    const float* b3c   = (const float*)d_in[15];
    const float* g3    = (const float*)d_in[16];
    const float* be3   = (const float*)d_in[17];
    const float* m3    = (const float*)d_in[18];
    const float* v3    = (const float*)d_in[19];
    const float* Wq    = (const float*)d_in[20];
    const float* bq    = (const float*)d_in[21];
    const float* Wk    = (const float*)d_in[22];
    const float* bk    = (const float*)d_in[23];
    const float* Wv    = (const float*)d_in[24];
    const float* bv    = (const float*)d_in[25];
    const float* fca_w = (const float*)d_in[26];
    const float* fca_b = (const float*)d_in[27];
    const float* fc_w  = (const float*)d_in[28];
    const float* fc_b  = (const float*)d_in[29];

    float* ws = (float*)d_ws;
    float* feat = ws;                       // 22528*256      = 5,767,168
    float* w2T  = feat + 5767168;           // 1664*128       =   212,992
    float* w3T  = w2T + 212992;             // 3200*256       =   819,200
    float* WkT  = w3T + 819200;             // 8*256*256      =   524,288
    float* Mm   = WkT + 524288;             // 8*256*256      =   524,288
    float* qb   = Mm + 524288;              // 2048
    float* kb   = qb + 2048;                // 2048
    float* cv   = kb + 2048;                // 8
    float* Obar = cv + 16;                  // 1024*2048      = 2,097,152  (total ~39.8 MB)

    // setup (independent of activations)
    k_transpose<<<832, 256, 0, stream>>>(w2, w2T, 1, 128, 1664);
    k_transpose<<<3200, 256, 0, stream>>>(w3, w3T, 1, 256, 3200);
    k_transpose<<<2048, 256, 0, stream>>>(Wk, WkT, 8, 256, 256);
    k_prep_attn<<<2048, 256, 0, stream>>>(Wq, bq, Wk, bk, WkT, Mm, qb, kb, cv);

    // main pipeline
    k_conv<<<5632, 256, 0, stream>>>(av1, av2,
        w1, b1c, g1, be1, m1, v1,
        w2T, b2c, g2, be2, m2, v2,
        w3T, b3c, g3, be3, m3, v3,
        feat);
    k_attn<<<8192, 256, 0, stream>>>(feat, Mm, qb, kb, cv, Wv, bv, Obar);
    k_head<<<1024, 256, 0, stream>>>(Obar, fca_w, fca_b, fc_w, fc_b, (float*)d_out);
}

// Round 2
// 2347.354 us; speedup vs baseline: 2.3238x; 2.3238x over previous
//
#include <hip/hip_runtime.h>
#include <hip/hip_bf16.h>
#include <math.h>

// ---------------- problem constants ----------------
// B=512, L=600, DIM=256, H=8, chunks: 22 x 75 step 25
// conv1: 1->64 k26 (75->50), conv2: 64->128 k26 (50->25), conv3: 128->256 k25 (25->1)
#define NSEQ 22528
#define HALFSEQ 11264

typedef __attribute__((ext_vector_type(8))) short short8;
typedef __attribute__((ext_vector_type(4))) float f32x4;

__device__ __forceinline__ ushort f2bf(float x) {
    __hip_bfloat16 h = __float2bfloat16(x);
    return *reinterpret_cast<ushort*>(&h);
}

// ---------------- setup: transpose (for WkT) ----------------
__global__ void k_transpose(const float* __restrict__ in, float* __restrict__ out,
                            int Bn, int R, int C) {
    int idx = blockIdx.x * 256 + threadIdx.x;
    int total = Bn * R * C;
    if (idx >= total) return;
    int b = idx / (R * C);
    int rem = idx - b * R * C;
    int c = rem / R;
    int r = rem - c * R;
    out[idx] = in[(b * R + r) * C + c];
}

// ---------------- setup: bf16 weight repacks ----------------
// W2r[oc][t*64+ic] = w2[oc][ic][t], bf16.  212992 elems.
__global__ void k_prep_w2(const float* __restrict__ w2, ushort* __restrict__ w2r) {
    int idx = blockIdx.x * 256 + threadIdx.x;
    if (idx >= 128 * 1664) return;
    int oc = idx / 1664;
    int r = idx - oc * 1664;
    int t = r >> 6;          // r / 64
    int ic = r & 63;
    w2r[idx] = f2bf(w2[oc * 1664 + ic * 26 + t]);
}
// W3r[oc][k] = w3 flat (same order), bf16. 819200 elems.
__global__ void k_prep_w3(const float* __restrict__ w3, ushort* __restrict__ w3r) {
    int idx = blockIdx.x * 256 + threadIdx.x;
    if (idx >= 256 * 3200) return;
    w3r[idx] = f2bf(w3[idx]);
}

// ---------------- setup: M = Wq Wk^T, qb, kb, c ----------------
__global__ __launch_bounds__(256) void k_prep_attn(
    const float* __restrict__ Wq, const float* __restrict__ bq,
    const float* __restrict__ Wk, const float* __restrict__ bk,
    const float* __restrict__ WkT,
    float* __restrict__ M, float* __restrict__ qb, float* __restrict__ kb,
    float* __restrict__ cvec)
{
    int bid = blockIdx.x;
    int h = bid >> 8;
    int e = bid & 255;
    int t = threadIdx.x;
    __shared__ float qrow[256];
    __shared__ float krow[256];
    __shared__ float red[256];
    qrow[t] = Wq[(h * 256 + e) * 256 + t];
    krow[t] = Wk[(h * 256 + e) * 256 + t];
    __syncthreads();

    const float* wkt = WkT + h * 65536;
    float a0 = 0.f, a1 = 0.f, a2 = 0.f, a3 = 0.f;
    for (int o = 0; o < 256; o += 4) {
        a0 += qrow[o + 0] * wkt[(o + 0) * 256 + t];
        a1 += qrow[o + 1] * wkt[(o + 1) * 256 + t];
        a2 += qrow[o + 2] * wkt[(o + 2) * 256 + t];
        a3 += qrow[o + 3] * wkt[(o + 3) * 256 + t];
    }
    M[(h * 256 + e) * 256 + t] = (a0 + a1) + (a2 + a3);

    float p1 = qrow[t] * bk[h * 256 + t];
    float p2 = krow[t] * bq[h * 256 + t];
    red[t] = p1; __syncthreads();
    for (int s2 = 128; s2 > 0; s2 >>= 1) { if (t < s2) red[t] += red[t + s2]; __syncthreads(); }
    if (t == 0) qb[h * 256 + e] = red[0];
    __syncthreads();
    red[t] = p2; __syncthreads();
    for (int s2 = 128; s2 > 0; s2 >>= 1) { if (t < s2) red[t] += red[t + s2]; __syncthreads(); }
    if (t == 0) kb[h * 256 + e] = red[0];
    if (e == 0) {
        __syncthreads();
        red[t] = bq[h * 256 + t] * bk[h * 256 + t]; __syncthreads();
        for (int s2 = 128; s2 > 0; s2 >>= 1) { if (t < s2) red[t] += red[t + s2]; __syncthreads(); }
        if (t == 0) cvec[h] = red[0];
    }
}

// ---------------- fused conv stack with MFMA (J=4 seqs/block) ----------------
// conv2 GEMM: C[oc=128][n=s*25+p (100, pad 112)] over K=1664 (k = t*64+ic), 52 ktiles
// conv3 GEMM: C[oc3=256][n=s (4, pad 16)] over K=3200 (k = ic*25+pos), 100 ktiles
__global__ __launch_bounds__(256, 2) void k_conv(
    const float* __restrict__ av1, const float* __restrict__ av2,
    const float* __restrict__ w1, const float* __restrict__ b1c,
    const float* __restrict__ g1, const float* __restrict__ be1,
    const float* __restrict__ m1, const float* __restrict__ v1,
    const ushort* __restrict__ w2r, const float* __restrict__ b2c,
    const float* __restrict__ g2, const float* __restrict__ be2,
    const float* __restrict__ m2, const float* __restrict__ v2,
    const ushort* __restrict__ w3r, const float* __restrict__ b3c,
    const float* __restrict__ g3, const float* __restrict__ be3,
    const float* __restrict__ m3, const float* __restrict__ v3,
    float* __restrict__ feat)
{
    // a1T: per seq [pos 50][ic 64] bf16, 128B rows, XOR-swizzled 16B slots. 6400 B/seq.
    __shared__ ushort s_a1[4 * 3200];
    // a2: per seq [ic2*25+pos] bf16, 6416 B/seq (16B skew to spread banks).
    __shared__ ushort s_a2[4 * 3208];
    __shared__ float s_x[4][80];
    __shared__ float s_w1t[26 * 64];
    __shared__ float s_sc1[64], s_sh1[64], s_sc2[128], s_sh2[128], s_sc3[256], s_sh3[256];

    const int tid = threadIdx.x;
    const int lane = tid & 63;
    const int wv = tid >> 6;          // wave 0..3
    const int l15 = lane & 15;
    const int grp = lane >> 4;        // 0..3
    const int seq0 = blockIdx.x * 4;

    // ---- stage inputs, w1 (transposed), folded BN params ----
    for (int s = 0; s < 4; ++s) {
        int seq = seq0 + s;
        const float* src;
        if (seq < HALFSEQ) { int b = seq / 22; int n = seq - b * 22; src = av1 + b * 600 + n * 25; }
        else { int q = seq - HALFSEQ; int b = q / 22; int n = q - b * 22; src = av2 + b * 600 + n * 25; }
        if (tid < 75) s_x[s][tid] = src[tid];
    }
    for (int i = tid; i < 1664; i += 256) {
        int o = i / 26; int t = i - o * 26;
        s_w1t[t * 64 + o] = w1[i];
    }
    if (tid < 64) { float A = g1[tid] * rsqrtf(v1[tid] + 1e-5f); s_sc1[tid] = A; s_sh1[tid] = (b1c[tid] - m1[tid]) * A + be1[tid]; }
    if (tid < 128) { float A = g2[tid] * rsqrtf(v2[tid] + 1e-5f); s_sc2[tid] = A; s_sh2[tid] = (b2c[tid] - m2[tid]) * A + be2[tid]; }
    { float A = g3[tid] * rsqrtf(v3[tid] + 1e-5f); s_sc3[tid] = A; s_sh3[tid] = (b3c[tid] - m3[tid]) * A + be3[tid]; }
    __syncthreads();

    // ---- conv1 (VALU) -> s_a1 bf16 swizzled ----
    {
        int o = lane;                 // works per 64-lane wave: o = tid&63
        int pb = tid >> 6;            // wave id = starting p
        for (int s = 0; s < 4; ++s) {
            for (int p = pb; p < 50; p += 4) {
                float acc = 0.f;
                #pragma unroll
                for (int t = 0; t < 26; ++t) acc += s_w1t[t * 64 + o] * s_x[s][p + t];
                float y = acc * s_sc1[o] + s_sh1[o];
                y = y / (1.f + __expf(-y));
                int boff = s * 6400 + p * 128 + ((o * 2) ^ ((p & 7) << 4));
                *(ushort*)((char*)s_a1 + boff) = f2bf(y);
            }
        }
    }
    __syncthreads();

    // ---- conv2 MFMA ----
    // wave -> mset = wv>>1 (oc half), nset = wv&1 (ntile split 4/3)
    {
        const int mset = wv >> 1;
        const int nset = wv & 1;
        const int NT = nset ? 3 : 4;

        int nbase[4], nrow[4];
        #pragma unroll
        for (int ni = 0; ni < 4; ++ni) {
            int n = (nset * 4 + ni) * 16 + l15;
            int s = n / 25; if (s > 3) s = 3;
            int p = n - s * 25; if (p > 24) p = 24;
            nbase[ni] = s * 6400;
            nrow[ni] = p;
        }

        f32x4 acc[4][4];
        #pragma unroll
        for (int mi = 0; mi < 4; ++mi)
            #pragma unroll
            for (int ni = 0; ni < 4; ++ni)
                acc[mi][ni] = (f32x4){0.f, 0.f, 0.f, 0.f};

        const ushort* wp = w2r + (size_t)(mset * 64 + l15) * 1664 + grp * 8;
        for (int kt = 0; kt < 52; ++kt) {
            const int t = kt >> 1;
            const int ic0b = ((kt & 1) * 32 + grp * 8) * 2;   // byte offset of ic chunk
            short8 af[4];
            #pragma unroll
            for (int mi = 0; mi < 4; ++mi)
                af[mi] = *(const short8*)(wp + kt * 32 + mi * (16 * 1664));
            #pragma unroll
            for (int ni = 0; ni < 4; ++ni) {
                if (ni >= NT) break;
                int row = nrow[ni] + t;
                int boff = nbase[ni] + row * 128 + (ic0b ^ ((row & 7) << 4));
                short8 bf = *(const short8*)((const char*)s_a1 + boff);
                #pragma unroll
                for (int mi = 0; mi < 4; ++mi)
                    acc[mi][ni] = __builtin_amdgcn_mfma_f32_16x16x32_bf16(af[mi], bf, acc[mi][ni], 0, 0, 0);
            }
        }

        // epilogue: BN2 + SiLU -> s_a2 bf16
        #pragma unroll
        for (int mi = 0; mi < 4; ++mi) {
            #pragma unroll
            for (int ni = 0; ni < 4; ++ni) {
                if (ni >= NT) break;
                int n = (nset * 4 + ni) * 16 + l15;
                if (n < 100) {
                    int s = n / 25;
                    int p = n - s * 25;
                    int ocb = mset * 64 + mi * 16 + grp * 4;
                    #pragma unroll
                    for (int r = 0; r < 4; ++r) {
                        float y = acc[mi][ni][r] * s_sc2[ocb + r] + s_sh2[ocb + r];
                        y = y / (1.f + __expf(-y));
                        s_a2[s * 3208 + (ocb + r) * 25 + p] = f2bf(y);
                    }
                }
            }
        }
    }
    __syncthreads();

    // ---- conv3 MFMA: oc3 = wv*64 + mi*16 + l15 rows; n = seq (4 valid of 16) ----
    {
        const int scl = (l15 < 4) ? l15 : 3;
        f32x4 acc3[4];
        #pragma unroll
        for (int mi = 0; mi < 4; ++mi) acc3[mi] = (f32x4){0.f, 0.f, 0.f, 0.f};

        const ushort* w3p = w3r + (size_t)(wv * 64 + l15) * 3200 + grp * 8;
        for (int kt = 0; kt < 100; ++kt) {
            short8 bf = *(const short8*)((const char*)s_a2 + scl * 6416 + kt * 64 + grp * 16);
            #pragma unroll
            for (int mi = 0; mi < 4; ++mi) {
                short8 af = *(const short8*)(w3p + kt * 32 + mi * (16 * 3200));
                acc3[mi] = __builtin_amdgcn_mfma_f32_16x16x32_bf16(af, bf, acc3[mi], 0, 0, 0);
            }
        }

        // epilogue: BN3 + SiLU -> feat (fp32)
        if (l15 < 4) {
            int seq = seq0 + l15;
            #pragma unroll
            for (int mi = 0; mi < 4; ++mi) {
                int oc = wv * 64 + mi * 16 + grp * 4;
                float4 o4;
                float y0 = acc3[mi][0] * s_sc3[oc + 0] + s_sh3[oc + 0]; o4.x = y0 / (1.f + __expf(-y0));
                float y1 = acc3[mi][1] * s_sc3[oc + 1] + s_sh3[oc + 1]; o4.y = y1 / (1.f + __expf(-y1));
                float y2 = acc3[mi][2] * s_sc3[oc + 2] + s_sh3[oc + 2]; o4.z = y2 / (1.f + __expf(-y2));
                float y3 = acc3[mi][3] * s_sc3[oc + 3] + s_sh3[oc + 3]; o4.w = y3 / (1.f + __expf(-y3));
                *(float4*)(feat + (size_t)seq * 256 + oc) = o4;
            }
        }
    }
}

// ---------------- attention (per g,h), pooled-O trick ----------------
__global__ __launch_bounds__(256) void k_attn(
    const float* __restrict__ feat, const float* __restrict__ M,
    const float* __restrict__ qb, const float* __restrict__ kb,
    const float* __restrict__ cvec,
    const float* __restrict__ Wv, const float* __restrict__ bv,
    float* __restrict__ Obar)
{
    const int bid = blockIdx.x;
    const int g = bid >> 3;
    const int h = bid & 7;
    const int tid = threadIdx.x;
    const int FS = 260;

    __shared__ __align__(16) float fL[22 * 260];
    __shared__ __align__(16) float gL[22 * 260];
    __shared__ float sS[22 * 24];
    __shared__ float sal[22], sbe[22], sab[22];
    __shared__ __align__(16) float sfb[256];

    const float* fsrc = feat + (size_t)g * 22 * 256;
    for (int idx = tid; idx < 5632; idx += 256) {
        int s = idx >> 8;
        int e = idx & 255;
        fL[s * FS + e] = fsrc[idx];
    }
    __syncthreads();

    {
        float acc[22];
        #pragma unroll
        for (int s = 0; s < 22; ++s) acc[s] = 0.f;
        const float* Mh = M + h * 65536 + tid;
        for (int e = 0; e < 256; e += 4) {
            float w0 = Mh[(e + 0) * 256];
            float w1 = Mh[(e + 1) * 256];
            float w2 = Mh[(e + 2) * 256];
            float w3 = Mh[(e + 3) * 256];
            #pragma unroll
            for (int s = 0; s < 22; ++s) {
                float4 f4 = *(const float4*)(fL + s * FS + e);
                acc[s] += f4.x * w0 + f4.y * w1 + f4.z * w2 + f4.w * w3;
            }
        }
        #pragma unroll
        for (int s = 0; s < 22; ++s) gL[s * FS + tid] = acc[s];
    }
    if (tid < 22) {
        const float* qbh = qb + h * 256;
        float a = 0.f;
        for (int e = 0; e < 256; ++e) a += fL[tid * FS + e] * qbh[e];
        sal[tid] = a;
    } else if (tid >= 64 && tid < 86) {
        int s = tid - 64;
        const float* kbh = kb + h * 256;
        float a = 0.f;
        for (int e = 0; e < 256; ++e) a += fL[s * FS + e] * kbh[e];
        sbe[s] = a;
    }
    __syncthreads();

    float cval = cvec[h];
    for (int idx = tid; idx < 484; idx += 256) {
        int s = idx / 22;
        int t = idx - s * 22;
        const float* gr = gL + s * FS;
        const float* fr = fL + t * FS;
        float acc = 0.f;
        for (int e = 0; e < 256; e += 4) {
            float4 g4 = *(const float4*)(gr + e);
            float4 f4 = *(const float4*)(fr + e);
            acc += g4.x * f4.x + g4.y * f4.y + g4.z * f4.z + g4.w * f4.w;
        }
        sS[s * 24 + t] = acc + sal[s] + sbe[t] + cval;
    }
    __syncthreads();

    if (tid < 22) {
        int s = tid;
        float mx = -1e30f;
        #pragma unroll
        for (int t = 0; t < 22; ++t) mx = fmaxf(mx, sS[s * 24 + t]);
        float ex[22];
        float sum = 0.f;
        #pragma unroll
        for (int t = 0; t < 22; ++t) { float e2 = __expf(sS[s * 24 + t] - mx); ex[t] = e2; sum += e2; }
        float inv = 1.f / sum;
        #pragma unroll
        for (int t = 0; t < 22; ++t) sS[s * 24 + t] = ex[t] * inv;
    }
    __syncthreads();
    if (tid < 22) {
        int t = tid;
        float a = 0.f;
        #pragma unroll
        for (int s = 0; s < 22; ++s) a += sS[s * 24 + t];
        sab[t] = a * (1.f / 22.f);
    }
    __syncthreads();

    {
        float a = 0.f;
        #pragma unroll
        for (int t = 0; t < 22; ++t) a += sab[t] * fL[t * FS + tid];
        sfb[tid] = a;
    }
    __syncthreads();

    {
        const float* wv = Wv + h * 65536 + tid;
        float acc = bv[h * 256 + tid];
        for (int e = 0; e < 256; e += 4) {
            float4 fb4 = *(const float4*)(sfb + e);
            acc += fb4.x * wv[(e + 0) * 256] + fb4.y * wv[(e + 1) * 256]
                 + fb4.z * wv[(e + 2) * 256] + fb4.w * wv[(e + 3) * 256];
        }
        Obar[(size_t)g * 2048 + h * 256 + tid] = acc;
    }
}

// ---------------- head ----------------
__global__ __launch_bounds__(256) void k_head(
    const float* __restrict__ Obar,
    const float* __restrict__ fca_w, const float* __restrict__ fca_b,
    const float* __restrict__ fc_w, const float* __restrict__ fc_b,
    float* __restrict__ out)
{
    const int g = blockIdx.x;
    const int tid = threadIdx.x;
    __shared__ __align__(16) float so[2048];
    __shared__ __align__(16) float sp[256];
    for (int idx = tid; idx < 2048; idx += 256) so[idx] = Obar[(size_t)g * 2048 + idx];
    __syncthreads();
    float acc = fca_b[tid];
    const float* wc = fca_w + tid;
    for (int k = 0; k < 2048; k += 4) {
        float4 o4 = *(const float4*)(so + k);
        acc += o4.x * wc[(k + 0) * 256] + o4.y * wc[(k + 1) * 256]
             + o4.z * wc[(k + 2) * 256] + o4.w * wc[(k + 3) * 256];
    }
    sp[tid] = acc;
    __syncthreads();
    float y = fc_b[tid];
    const float* wf = fc_w + tid;
    for (int e = 0; e < 256; e += 4) {
        float4 p4 = *(const float4*)(sp + e);
        y += p4.x * wf[(e + 0) * 256] + p4.y * wf[(e + 1) * 256]
           + p4.z * wf[(e + 2) * 256] + p4.w * wf[(e + 3) * 256];
    }
    out[(size_t)g * 256 + tid] = y;
}

// ---------------- launch ----------------
extern "C" void kernel_launch(void* const* d_in, const int* in_sizes, int n_in,
                              void* d_out, int out_size, void* d_ws, size_t ws_size,
                              hipStream_t stream) {
    (void)in_sizes; (void)n_in; (void)out_size; (void)ws_size;

    const float* av1   = (const float*)d_in[0];
    const float* av2   = (const float*)d_in[1];
    const float* w1    = (const float*)d_in[2];
    const float* b1c   = (const float*)d_in[3];
    const float* g1    = (const float*)d_in[4];
    const float* be1   = (const float*)d_in[5];
    const float* m1    = (const float*)d_in[6];
    const float* v1    = (const float*)d_in[7];
    const float* w2    = (const float*)d_in[8];
    const float* b2c   = (const float*)d_in[9];
    const float* g2    = (const float*)d_in[10];
    const float* be2   = (const float*)d_in[11];
    const float* m2    = (const float*)d_in[12];
    const float* v2    = (const float*)d_in[13];
    const float* w3    = (const float*)d_in[14];
    const float* b3c   = (const float*)d_in[15];
    const float* g3    = (const float*)d_in[16];
    const float* be3   = (const float*)d_in[17];
    const float* m3    = (const float*)d_in[18];
    const float* v3    = (const float*)d_in[19];
    const float* Wq    = (const float*)d_in[20];
    const float* bq    = (const float*)d_in[21];
    const float* Wk    = (const float*)d_in[22];
    const float* bk    = (const float*)d_in[23];
    const float* Wv    = (const float*)d_in[24];
    const float* bv    = (const float*)d_in[25];
    const float* fca_w = (const float*)d_in[26];
    const float* fca_b = (const float*)d_in[27];
    const float* fc_w  = (const float*)d_in[28];
    const float* fc_b  = (const float*)d_in[29];

    float* ws = (float*)d_ws;
    float* feat = ws;                        // 5,767,168 f
    float* Mm   = feat + 5767168;            //   524,288 f
    float* WkT  = Mm + 524288;               //   524,288 f
    float* qb   = WkT + 524288;              //     2,048 f
    float* kb   = qb + 2048;                 //     2,048 f
    float* cv   = kb + 2048;                 //        16 f
    float* Obar = cv + 16;                   // 2,097,152 f
    ushort* w2r = (ushort*)(Obar + 2097152); //   212,992 u16
    ushort* w3r = w2r + 212992;              //   819,200 u16  (total ~37.7 MB)

    // setup (weights only)
    k_prep_w2<<<832, 256, 0, stream>>>(w2, w2r);
    k_prep_w3<<<3200, 256, 0, stream>>>(w3, w3r);
    k_transpose<<<2048, 256, 0, stream>>>(Wk, WkT, 8, 256, 256);
    k_prep_attn<<<2048, 256, 0, stream>>>(Wq, bq, Wk, bk, WkT, Mm, qb, kb, cv);

    // main pipeline
    k_conv<<<5632, 256, 0, stream>>>(av1, av2,
        w1, b1c, g1, be1, m1, v1,
        w2r, b2c, g2, be2, m2, v2,
        w3r, b3c, g3, be3, m3, v3,
        feat);
    k_attn<<<8192, 256, 0, stream>>>(feat, Mm, qb, kb, cv, Wv, bv, Obar);
    k_head<<<1024, 256, 0, stream>>>(Obar, fca_w, fca_b, fc_w, fc_b, (float*)d_out);
}

// Round 3
// 1302.037 us; speedup vs baseline: 4.1894x; 1.8028x over previous
//
#include <hip/hip_runtime.h>
#include <hip/hip_bf16.h>
#include <math.h>

// ---------------- problem constants ----------------
// B=512, L=600, DIM=256, H=8, chunks: 22 x 75 step 25
// conv1: 1->64 k26 (75->50), conv2: 64->128 k26 (50->25), conv3: 128->256 k25 (25->1)
#define NSEQ 22528
#define HALFSEQ 11264

typedef __attribute__((ext_vector_type(8))) short short8;
typedef __attribute__((ext_vector_type(4))) float f32x4;

__device__ __forceinline__ ushort f2bf(float x) {
    __hip_bfloat16 h = __float2bfloat16(x);
    return *reinterpret_cast<ushort*>(&h);
}

// ---------------- setup: transpose (for WkT) ----------------
__global__ void k_transpose(const float* __restrict__ in, float* __restrict__ out,
                            int Bn, int R, int C) {
    int idx = blockIdx.x * 256 + threadIdx.x;
    int total = Bn * R * C;
    if (idx >= total) return;
    int b = idx / (R * C);
    int rem = idx - b * R * C;
    int c = rem / R;
    int r = rem - c * R;
    out[idx] = in[(b * R + r) * C + c];
}

// ---------------- setup: bf16 weight repacks in MFMA FRAGMENT ORDER ----------------
// conv2 A-tiles: (kt 0..51, mt 0..7): elem (lane,j): oc = mt*16+(lane&15),
// k = kt*32 + (lane>>4)*8 + j, with k-order t*64+ic.
__global__ void k_prep_w2(const float* __restrict__ w2, ushort* __restrict__ w2f) {
    int idx = blockIdx.x * 256 + threadIdx.x;
    if (idx >= 212992) return;
    int j = idx & 7;
    int lane = (idx >> 3) & 63;
    int mt = (idx >> 9) & 7;
    int kt = idx >> 12;
    int oc = mt * 16 + (lane & 15);
    int k = kt * 32 + ((lane >> 4) << 3) + j;
    int t = k >> 6;
    int ic = k & 63;
    w2f[idx] = f2bf(w2[(oc * 64 + ic) * 26 + t]);
}
// conv3 A-tiles: (kt 0..99, mt 0..15): oc = mt*16+(lane&15), k = kt*32+(lane>>4)*8+j
// k-order = ic*25+pos (w3 natural flat order).
__global__ void k_prep_w3(const float* __restrict__ w3, ushort* __restrict__ w3f) {
    int idx = blockIdx.x * 256 + threadIdx.x;
    if (idx >= 819200) return;
    int j = idx & 7;
    int lane = (idx >> 3) & 63;
    int mt = (idx >> 9) & 15;
    int kt = idx >> 13;
    int oc = mt * 16 + (lane & 15);
    int k = kt * 32 + ((lane >> 4) << 3) + j;
    w3f[idx] = f2bf(w3[oc * 3200 + k]);
}

// ---------------- setup: M = Wq Wk^T (16-row tiles, low traffic) ----------------
// grid 128 = h*16 + etile, 256 threads (f)
__global__ __launch_bounds__(256) void k_prep_attn_m(
    const float* __restrict__ Wq, const float* __restrict__ WkT,
    float* __restrict__ M)
{
    const int h = blockIdx.x >> 4;
    const int e0 = (blockIdx.x & 15) * 16;
    const int tid = threadIdx.x;
    __shared__ float sq[16][256];
    for (int idx = tid; idx < 4096; idx += 256) {
        int r = idx >> 8;
        int c = idx & 255;
        sq[r][c] = Wq[(size_t)(h * 256 + e0 + r) * 256 + c];
    }
    __syncthreads();
    float acc[16];
    #pragma unroll
    for (int r = 0; r < 16; ++r) acc[r] = 0.f;
    const float* wkt = WkT + (size_t)h * 65536 + tid;
    for (int o = 0; o < 256; ++o) {
        float wk = wkt[o * 256];
        #pragma unroll
        for (int r = 0; r < 16; ++r) acc[r] += sq[r][o] * wk;
    }
    #pragma unroll
    for (int r = 0; r < 16; ++r)
        M[(size_t)(h * 256 + e0 + r) * 256 + tid] = acc[r];
}

// ---------------- setup: qb, kb, cvec ----------------
// grid 8 (h), 256 threads (e)
__global__ __launch_bounds__(256) void k_prep_bias(
    const float* __restrict__ Wq, const float* __restrict__ bq,
    const float* __restrict__ Wk, const float* __restrict__ bk,
    float* __restrict__ qb, float* __restrict__ kb, float* __restrict__ cvec)
{
    const int h = blockIdx.x;
    const int tid = threadIdx.x;
    __shared__ float sbk[256], sbq[256], red[256];
    sbk[tid] = bk[h * 256 + tid];
    sbq[tid] = bq[h * 256 + tid];
    __syncthreads();
    const float* wq = Wq + (size_t)(h * 256 + tid) * 256;
    const float* wk = Wk + (size_t)(h * 256 + tid) * 256;
    float a = 0.f, b = 0.f;
    for (int o = 0; o < 256; ++o) { a += wq[o] * sbk[o]; b += wk[o] * sbq[o]; }
    qb[h * 256 + tid] = a;
    kb[h * 256 + tid] = b;
    red[tid] = sbq[tid] * sbk[tid];
    __syncthreads();
    for (int s2 = 128; s2 > 0; s2 >>= 1) { if (tid < s2) red[tid] += red[tid + s2]; __syncthreads(); }
    if (tid == 0) cvec[h] = red[0];
}

// ---------------- conv1 + conv2 (MFMA), J=4 seqs/block, a2 -> global bf16 ----------------
__global__ __launch_bounds__(256, 3) void k_conv(
    const float* __restrict__ av1, const float* __restrict__ av2,
    const float* __restrict__ w1,
    const float* __restrict__ b1c, const float* __restrict__ g1,
    const float* __restrict__ be1, const float* __restrict__ m1, const float* __restrict__ v1,
    const ushort* __restrict__ w2f,
    const float* __restrict__ b2c, const float* __restrict__ g2,
    const float* __restrict__ be2, const float* __restrict__ m2, const float* __restrict__ v2,
    ushort* __restrict__ a2g, int seqoff)
{
    // a1T: per seq [pos 50][ic 64] bf16, 128B rows, XOR-swizzled 16B slots.
    __shared__ ushort s_a1[4 * 3200];
    __shared__ float s_x[4][80];
    __shared__ float s_w1t[26 * 64];
    __shared__ float s_sc1[64], s_sh1[64], s_sc2[128], s_sh2[128];

    const int tid = threadIdx.x;
    const int lane = tid & 63;
    const int wv = tid >> 6;
    const int l15 = lane & 15;
    const int grp = lane >> 4;
    const int lseq0 = blockIdx.x * 4;
    const int gseq0 = seqoff + lseq0;

    for (int s = 0; s < 4; ++s) {
        int seq = gseq0 + s;
        const float* src;
        if (seq < HALFSEQ) { int b = seq / 22; int n = seq - b * 22; src = av1 + b * 600 + n * 25; }
        else { int q = seq - HALFSEQ; int b = q / 22; int n = q - b * 22; src = av2 + b * 600 + n * 25; }
        if (tid < 75) s_x[s][tid] = src[tid];
    }
    for (int i = tid; i < 1664; i += 256) {
        int o = i / 26; int t = i - o * 26;
        s_w1t[t * 64 + o] = w1[i];
    }
    if (tid < 64) { float A = g1[tid] * rsqrtf(v1[tid] + 1e-5f); s_sc1[tid] = A; s_sh1[tid] = (b1c[tid] - m1[tid]) * A + be1[tid]; }
    if (tid < 128) { float A = g2[tid] * rsqrtf(v2[tid] + 1e-5f); s_sc2[tid] = A; s_sh2[tid] = (b2c[tid] - m2[tid]) * A + be2[tid]; }
    __syncthreads();

    // ---- conv1 (VALU) -> s_a1 bf16 swizzled ----
    {
        int o = lane;
        int pb = wv;
        for (int s = 0; s < 4; ++s) {
            for (int p = pb; p < 50; p += 4) {
                float acc = 0.f;
                #pragma unroll
                for (int t = 0; t < 26; ++t) acc += s_w1t[t * 64 + o] * s_x[s][p + t];
                float y = acc * s_sc1[o] + s_sh1[o];
                y = y / (1.f + __expf(-y));
                int boff = s * 6400 + p * 128 + ((o * 2) ^ ((p & 7) << 4));
                *(ushort*)((char*)s_a1 + boff) = f2bf(y);
            }
        }
    }
    __syncthreads();

    // ---- conv2 MFMA: C[oc 128][n = s*25+p, 100 of 112] over K=1664 ----
    {
        const int mset = wv >> 1;
        const int nset = wv & 1;
        const int NT = nset ? 3 : 4;

        int nbase[4], nrow[4];
        #pragma unroll
        for (int ni = 0; ni < 4; ++ni) {
            int n = (nset * 4 + ni) * 16 + l15;
            int s = n / 25; if (s > 3) s = 3;
            int p = n - s * 25; if (p > 24) p = 24;
            nbase[ni] = s * 6400;
            nrow[ni] = p;
        }

        f32x4 acc[4][4];
        #pragma unroll
        for (int mi = 0; mi < 4; ++mi)
            #pragma unroll
            for (int ni = 0; ni < 4; ++ni)
                acc[mi][ni] = (f32x4){0.f, 0.f, 0.f, 0.f};

        // fragment-order A: tile (kt, mt) at (kt*8+mt)*512 + lane*8 (coalesced)
        const ushort* wfp = w2f + (size_t)(mset * 4) * 512 + lane * 8;
        short8 afn[4];
        #pragma unroll
        for (int mi = 0; mi < 4; ++mi) afn[mi] = *(const short8*)(wfp + mi * 512);

        for (int kt = 0; kt < 52; ++kt) {
            const int t = kt >> 1;
            const int ic0b = ((kt & 1) * 32 + grp * 8) * 2;
            short8 af[4];
            #pragma unroll
            for (int mi = 0; mi < 4; ++mi) af[mi] = afn[mi];
            if (kt < 51) {
                #pragma unroll
                for (int mi = 0; mi < 4; ++mi)
                    afn[mi] = *(const short8*)(wfp + (kt + 1) * 4096 + mi * 512);
            }
            #pragma unroll
            for (int ni = 0; ni < 4; ++ni) {
                if (ni >= NT) break;
                int row = nrow[ni] + t;
                int boff = nbase[ni] + row * 128 + (ic0b ^ ((row & 7) << 4));
                short8 bf = *(const short8*)((const char*)s_a1 + boff);
                #pragma unroll
                for (int mi = 0; mi < 4; ++mi)
                    acc[mi][ni] = __builtin_amdgcn_mfma_f32_16x16x32_bf16(af[mi], bf, acc[mi][ni], 0, 0, 0);
            }
        }

        // epilogue: BN2 + SiLU -> a2g bf16 [seq][oc*25+p]
        #pragma unroll
        for (int mi = 0; mi < 4; ++mi) {
            #pragma unroll
            for (int ni = 0; ni < 4; ++ni) {
                if (ni >= NT) break;
                int n = (nset * 4 + ni) * 16 + l15;
                if (n < 100) {
                    int s = n / 25;
                    int p = n - s * 25;
                    int ocb = mset * 64 + mi * 16 + grp * 4;
                    ushort* dst = a2g + (size_t)(lseq0 + s) * 3200 + p;
                    #pragma unroll
                    for (int r = 0; r < 4; ++r) {
                        float y = acc[mi][ni][r] * s_sc2[ocb + r] + s_sh2[ocb + r];
                        y = y / (1.f + __expf(-y));
                        dst[(ocb + r) * 25] = f2bf(y);
                    }
                }
            }
        }
    }
}

// ---------------- conv3 MFMA GEMM: M=256, N=16 seqs (all valid), K=3200 ----------------
// grid = nseq_chunk/16, 256 threads. No LDS, no barriers.
__global__ __launch_bounds__(256) void k_conv3(
    const ushort* __restrict__ a2g, const ushort* __restrict__ w3f,
    const float* __restrict__ b3c, const float* __restrict__ g3,
    const float* __restrict__ be3, const float* __restrict__ m3, const float* __restrict__ v3,
    float* __restrict__ feat, int seqoff)
{
    const int tid = threadIdx.x;
    const int lane = tid & 63;
    const int wv = tid >> 6;
    const int l15 = lane & 15;
    const int grp = lane >> 4;
    const int lseq0 = blockIdx.x * 16;

    f32x4 acc3[4];
    #pragma unroll
    for (int mi = 0; mi < 4; ++mi) acc3[mi] = (f32x4){0.f, 0.f, 0.f, 0.f};

    // B: per-lane from a2g[seq][k]; 4 lanes share each 64B line.
    const ushort* bp = a2g + (size_t)(lseq0 + l15) * 3200 + grp * 8;
    // A: fragment order, tile (kt, mt=wv*4+mi) at (kt*16+mt)*512 + lane*8 (coalesced)
    const ushort* ap = w3f + (size_t)(wv * 4) * 512 + lane * 8;

    for (int kt = 0; kt < 100; ++kt) {
        short8 bf = *(const short8*)(bp + kt * 32);
        #pragma unroll
        for (int mi = 0; mi < 4; ++mi) {
            short8 af = *(const short8*)(ap + (size_t)kt * 8192 + mi * 512);
            acc3[mi] = __builtin_amdgcn_mfma_f32_16x16x32_bf16(af, bf, acc3[mi], 0, 0, 0);
        }
    }

    // epilogue: BN3 + SiLU -> feat fp32. C: col=l15 (seq), row = grp*4+r (oc local)
    int gseq = seqoff + lseq0 + l15;
    #pragma unroll
    for (int mi = 0; mi < 4; ++mi) {
        int oc = wv * 64 + mi * 16 + grp * 4;
        float4 o4;
        {
            float A = g3[oc + 0] * rsqrtf(v3[oc + 0] + 1e-5f);
            float y = acc3[mi][0] * A + (b3c[oc + 0] - m3[oc + 0]) * A + be3[oc + 0];
            o4.x = y / (1.f + __expf(-y));
        }
        {
            float A = g3[oc + 1] * rsqrtf(v3[oc + 1] + 1e-5f);
            float y = acc3[mi][1] * A + (b3c[oc + 1] - m3[oc + 1]) * A + be3[oc + 1];
            o4.y = y / (1.f + __expf(-y));
        }
        {
            float A = g3[oc + 2] * rsqrtf(v3[oc + 2] + 1e-5f);
            float y = acc3[mi][2] * A + (b3c[oc + 2] - m3[oc + 2]) * A + be3[oc + 2];
            o4.z = y / (1.f + __expf(-y));
        }
        {
            float A = g3[oc + 3] * rsqrtf(v3[oc + 3] + 1e-5f);
            float y = acc3[mi][3] * A + (b3c[oc + 3] - m3[oc + 3]) * A + be3[oc + 3];
            o4.w = y / (1.f + __expf(-y));
        }
        *(float4*)(feat + (size_t)gseq * 256 + oc) = o4;
    }
}

// ---------------- attention (per g,h), pooled-O trick ----------------
__global__ __launch_bounds__(256) void k_attn(
    const float* __restrict__ feat, const float* __restrict__ M,
    const float* __restrict__ qb, const float* __restrict__ kb,
    const float* __restrict__ cvec,
    const float* __restrict__ Wv, const float* __restrict__ bv,
    float* __restrict__ Obar)
{
    const int bid = blockIdx.x;
    const int g = bid >> 3;
    const int h = bid & 7;
    const int tid = threadIdx.x;
    const int FS = 260;

    __shared__ __align__(16) float fL[22 * 260];
    __shared__ __align__(16) float gL[22 * 260];
    __shared__ float sS[22 * 24];
    __shared__ float sal[22], sbe[22], sab[22];
    __shared__ __align__(16) float sfb[256];

    const float* fsrc = feat + (size_t)g * 22 * 256;
    for (int idx = tid; idx < 5632; idx += 256) {
        int s = idx >> 8;
        int e = idx & 255;
        fL[s * FS + e] = fsrc[idx];
    }
    __syncthreads();

    {
        float acc[22];
        #pragma unroll
        for (int s = 0; s < 22; ++s) acc[s] = 0.f;
        const float* Mh = M + h * 65536 + tid;
        for (int e = 0; e < 256; e += 4) {
            float w0 = Mh[(e + 0) * 256];
            float w1 = Mh[(e + 1) * 256];
            float w2 = Mh[(e + 2) * 256];
            float w3 = Mh[(e + 3) * 256];
            #pragma unroll
            for (int s = 0; s < 22; ++s) {
                float4 f4 = *(const float4*)(fL + s * FS + e);
                acc[s] += f4.x * w0 + f4.y * w1 + f4.z * w2 + f4.w * w3;
            }
        }
        #pragma unroll
        for (int s = 0; s < 22; ++s) gL[s * FS + tid] = acc[s];
    }
    if (tid < 22) {
        const float* qbh = qb + h * 256;
        float a = 0.f;
        for (int e = 0; e < 256; ++e) a += fL[tid * FS + e] * qbh[e];
        sal[tid] = a;
    } else if (tid >= 64 && tid < 86) {
        int s = tid - 64;
        const float* kbh = kb + h * 256;
        float a = 0.f;
        for (int e = 0; e < 256; ++e) a += fL[s * FS + e] * kbh[e];
        sbe[s] = a;
    }
    __syncthreads();

    float cval = cvec[h];
    for (int idx = tid; idx < 484; idx += 256) {
        int s = idx / 22;
        int t = idx - s * 22;
        const float* gr = gL + s * FS;
        const float* fr = fL + t * FS;
        float acc = 0.f;
        for (int e = 0; e < 256; e += 4) {
            float4 g4 = *(const float4*)(gr + e);
            float4 f4 = *(const float4*)(fr + e);
            acc += g4.x * f4.x + g4.y * f4.y + g4.z * f4.z + g4.w * f4.w;
        }
        sS[s * 24 + t] = acc + sal[s] + sbe[t] + cval;
    }
    __syncthreads();

    if (tid < 22) {
        int s = tid;
        float mx = -1e30f;
        #pragma unroll
        for (int t = 0; t < 22; ++t) mx = fmaxf(mx, sS[s * 24 + t]);
        float ex[22];
        float sum = 0.f;
        #pragma unroll
        for (int t = 0; t < 22; ++t) { float e2 = __expf(sS[s * 24 + t] - mx); ex[t] = e2; sum += e2; }
        float inv = 1.f / sum;
        #pragma unroll
        for (int t = 0; t < 22; ++t) sS[s * 24 + t] = ex[t] * inv;
    }
    __syncthreads();
    if (tid < 22) {
        int t = tid;
        float a = 0.f;
        #pragma unroll
        for (int s = 0; s < 22; ++s) a += sS[s * 24 + t];
        sab[t] = a * (1.f / 22.f);
    }
    __syncthreads();

    {
        float a = 0.f;
        #pragma unroll
        for (int t = 0; t < 22; ++t) a += sab[t] * fL[t * FS + tid];
        sfb[tid] = a;
    }
    __syncthreads();

    {
        const float* wv = Wv + h * 65536 + tid;
        float acc = bv[h * 256 + tid];
        for (int e = 0; e < 256; e += 4) {
            float4 fb4 = *(const float4*)(sfb + e);
            acc += fb4.x * wv[(e + 0) * 256] + fb4.y * wv[(e + 1) * 256]
                 + fb4.z * wv[(e + 2) * 256] + fb4.w * wv[(e + 3) * 256];
        }
        Obar[(size_t)g * 2048 + h * 256 + tid] = acc;
    }
}

// ---------------- head ----------------
__global__ __launch_bounds__(256) void k_head(
    const float* __restrict__ Obar,
    const float* __restrict__ fca_w, const float* __restrict__ fca_b,
    const float* __restrict__ fc_w, const float* __restrict__ fc_b,
    float* __restrict__ out)
{
    const int g = blockIdx.x;
    const int tid = threadIdx.x;
    __shared__ __align__(16) float so[2048];
    __shared__ __align__(16) float sp[256];
    for (int idx = tid; idx < 2048; idx += 256) so[idx] = Obar[(size_t)g * 2048 + idx];
    __syncthreads();
    float acc = fca_b[tid];
    const float* wc = fca_w + tid;
    for (int k = 0; k < 2048; k += 4) {
        float4 o4 = *(const float4*)(so + k);
        acc += o4.x * wc[(k + 0) * 256] + o4.y * wc[(k + 1) * 256]
             + o4.z * wc[(k + 2) * 256] + o4.w * wc[(k + 3) * 256];
    }
    sp[tid] = acc;
    __syncthreads();
    float y = fc_b[tid];
    const float* wf = fc_w + tid;
    for (int e = 0; e < 256; e += 4) {
        float4 p4 = *(const float4*)(sp + e);
        y += p4.x * wf[(e + 0) * 256] + p4.y * wf[(e + 1) * 256]
           + p4.z * wf[(e + 2) * 256] + p4.w * wf[(e + 3) * 256];
    }
    out[(size_t)g * 256 + tid] = y;
}

// ---------------- launch ----------------
extern "C" void kernel_launch(void* const* d_in, const int* in_sizes, int n_in,
                              void* d_out, int out_size, void* d_ws, size_t ws_size,
                              hipStream_t stream) {
    (void)in_sizes; (void)n_in; (void)out_size;

    const float* av1   = (const float*)d_in[0];
    const float* av2   = (const float*)d_in[1];
    const float* w1    = (const float*)d_in[2];
    const float* b1c   = (const float*)d_in[3];
    const float* g1    = (const float*)d_in[4];
    const float* be1   = (const float*)d_in[5];
    const float* m1    = (const float*)d_in[6];
    const float* v1    = (const float*)d_in[7];
    const float* w2    = (const float*)d_in[8];
    const float* b2c   = (const float*)d_in[9];
    const float* g2    = (const float*)d_in[10];
    const float* be2   = (const float*)d_in[11];
    const float* m2    = (const float*)d_in[12];
    const float* v2    = (const float*)d_in[13];
    const float* w3    = (const float*)d_in[14];
    const float* b3c   = (const float*)d_in[15];
    const float* g3    = (const float*)d_in[16];
    const float* be3   = (const float*)d_in[17];
    const float* m3    = (const float*)d_in[18];
    const float* v3    = (const float*)d_in[19];
    const float* Wq    = (const float*)d_in[20];
    const float* bq    = (const float*)d_in[21];
    const float* Wk    = (const float*)d_in[22];
    const float* bk    = (const float*)d_in[23];
    const float* Wv    = (const float*)d_in[24];
    const float* bv    = (const float*)d_in[25];
    const float* fca_w = (const float*)d_in[26];
    const float* fca_b = (const float*)d_in[27];
    const float* fc_w  = (const float*)d_in[28];
    const float* fc_b  = (const float*)d_in[29];

    float* ws = (float*)d_ws;
    float* feat = ws;                        // 5,767,168 f
    float* Mm   = feat + 5767168;            //   524,288 f
    float* WkT  = Mm + 524288;               //   524,288 f
    float* qb   = WkT + 524288;              //     2,048 f
    float* kb   = qb + 2048;                 //     2,048 f
    float* cv   = kb + 2048;                 //        16 f
    float* Obar = cv + 16;                   // 2,097,152 f
    ushort* w2f = (ushort*)(Obar + 2097152); //   212,992 u16
    ushort* w3f = w2f + 212992;              //   819,200 u16
    ushort* a2g = w3f + 819200;              // 72,089,600/c u16

    // pick a2 chunking that fits ws_size
    size_t base_bytes = (size_t)((char*)a2g - (char*)d_ws);
    int nchunk = 16;
    const int cand[5] = {1, 2, 4, 8, 16};
    for (int i = 0; i < 5; ++i) {
        int c = cand[i];
        if (ws_size >= base_bytes + (size_t)144179200 / c + 64) { nchunk = c; break; }
    }
    const int seqs_per_chunk = NSEQ / nchunk;

    // setup (weights only)
    k_prep_w2<<<832, 256, 0, stream>>>(w2, w2f);
    k_prep_w3<<<3200, 256, 0, stream>>>(w3, w3f);
    k_transpose<<<2048, 256, 0, stream>>>(Wk, WkT, 8, 256, 256);
    k_prep_attn_m<<<128, 256, 0, stream>>>(Wq, WkT, Mm);
    k_prep_bias<<<8, 256, 0, stream>>>(Wq, bq, Wk, bk, qb, kb, cv);

    // conv pipeline (chunked through a2 scratch)
    for (int c = 0; c < nchunk; ++c) {
        int seqoff = c * seqs_per_chunk;
        k_conv<<<seqs_per_chunk / 4, 256, 0, stream>>>(av1, av2,
            w1, b1c, g1, be1, m1, v1,
            w2f, b2c, g2, be2, m2, v2,
            a2g, seqoff);
        k_conv3<<<seqs_per_chunk / 16, 256, 0, stream>>>(a2g, w3f,
            b3c, g3, be3, m3, v3, feat, seqoff);
    }

    k_attn<<<8192, 256, 0, stream>>>(feat, Mm, qb, kb, cv, Wv, bv, Obar);
    k_head<<<1024, 256, 0, stream>>>(Obar, fca_w, fca_b, fc_w, fc_b, (float*)d_out);
}

// Round 4
// 863.152 us; speedup vs baseline: 6.3195x; 1.5085x over previous
//
#include <hip/hip_runtime.h>
#include <hip/hip_bf16.h>
#include <math.h>

// ---------------- problem constants ----------------
#define NSEQ 22528
#define HALFSEQ 11264

typedef __attribute__((ext_vector_type(8))) short short8;
typedef __attribute__((ext_vector_type(4))) float f32x4;
typedef __attribute__((ext_vector_type(4))) ushort ushort4v;

__device__ __forceinline__ ushort f2bf(float x) {
    __hip_bfloat16 h = __float2bfloat16(x);
    return *reinterpret_cast<ushort*>(&h);
}
__device__ __forceinline__ float bf2f(ushort u) {
    unsigned v = ((unsigned)u) << 16;
    return *reinterpret_cast<float*>(&v);
}

// ---------------- setup: transpose (for WkT) ----------------
__global__ void k_transpose(const float* __restrict__ in, float* __restrict__ out,
                            int Bn, int R, int C) {
    int idx = blockIdx.x * 256 + threadIdx.x;
    int total = Bn * R * C;
    if (idx >= total) return;
    int b = idx / (R * C);
    int rem = idx - b * R * C;
    int c = rem / R;
    int r = rem - c * R;
    out[idx] = in[(b * R + r) * C + c];
}

// ---------------- setup: bf16 weight repacks in MFMA fragment order ----------------
__global__ void k_prep_w2(const float* __restrict__ w2, ushort* __restrict__ w2f) {
    int idx = blockIdx.x * 256 + threadIdx.x;
    if (idx >= 212992) return;
    int j = idx & 7;
    int lane = (idx >> 3) & 63;
    int mt = (idx >> 9) & 7;
    int kt = idx >> 12;
    int oc = mt * 16 + (lane & 15);
    int k = kt * 32 + ((lane >> 4) << 3) + j;
    int t = k >> 6;
    int ic = k & 63;
    w2f[idx] = f2bf(w2[(oc * 64 + ic) * 26 + t]);
}
__global__ void k_prep_w3(const float* __restrict__ w3, ushort* __restrict__ w3f) {
    int idx = blockIdx.x * 256 + threadIdx.x;
    if (idx >= 819200) return;
    int j = idx & 7;
    int lane = (idx >> 3) & 63;
    int mt = (idx >> 9) & 15;
    int kt = idx >> 13;
    int oc = mt * 16 + (lane & 15);
    int k = kt * 32 + ((lane >> 4) << 3) + j;
    w3f[idx] = f2bf(w3[oc * 3200 + k]);
}

// ---------------- setup: M = Wq Wk^T (16-row tiles) ----------------
__global__ __launch_bounds__(256) void k_prep_attn_m(
    const float* __restrict__ Wq, const float* __restrict__ WkT,
    float* __restrict__ M)
{
    const int h = blockIdx.x >> 4;
    const int e0 = (blockIdx.x & 15) * 16;
    const int tid = threadIdx.x;
    __shared__ float sq[16][256];
    for (int idx = tid; idx < 4096; idx += 256) {
        int r = idx >> 8;
        int c = idx & 255;
        sq[r][c] = Wq[(size_t)(h * 256 + e0 + r) * 256 + c];
    }
    __syncthreads();
    float acc[16];
    #pragma unroll
    for (int r = 0; r < 16; ++r) acc[r] = 0.f;
    const float* wkt = WkT + (size_t)h * 65536 + tid;
    for (int o = 0; o < 256; ++o) {
        float wk = wkt[o * 256];
        #pragma unroll
        for (int r = 0; r < 16; ++r) acc[r] += sq[r][o] * wk;
    }
    #pragma unroll
    for (int r = 0; r < 16; ++r)
        M[(size_t)(h * 256 + e0 + r) * 256 + tid] = acc[r];
}

// ---------------- setup: Mfrag bf16 fragment-packed (8 heads) ----------------
// Mfrag[((h*8+kt)*16+mt)*512 + lane*8 + j] = M[h][e=kt*32+(lane>>4)*8+j][o=mt*16+(lane&15)]
__global__ void k_prep_mfrag(const float* __restrict__ M, ushort* __restrict__ Mfrag) {
    int idx = blockIdx.x * 256 + threadIdx.x;   // 524288 total
    int j = idx & 7;
    int lane = (idx >> 3) & 63;
    int mt = (idx >> 9) & 15;
    int kt = (idx >> 13) & 7;
    int h = idx >> 16;
    int e = kt * 32 + ((lane >> 4) << 3) + j;
    int o = mt * 16 + (lane & 15);
    Mfrag[idx] = f2bf(M[(size_t)(h * 256 + e) * 256 + o]);
}

// ---------------- setup: kb[h][e] = Wk[h][e] . bq[h] ----------------
__global__ __launch_bounds__(256) void k_prep_kb(
    const float* __restrict__ Wk, const float* __restrict__ bq,
    float* __restrict__ kb)
{
    const int h = blockIdx.x;
    const int tid = threadIdx.x;
    __shared__ float sbq[256];
    sbq[tid] = bq[h * 256 + tid];
    __syncthreads();
    const float* wk = Wk + (size_t)(h * 256 + tid) * 256;
    float a = 0.f;
    for (int o = 0; o < 256; ++o) a += wk[o] * sbq[o];
    kb[h * 256 + tid] = a;
}

// ---------------- setup: F[h] = Wv[h] @ fca_w[h*256:(h+1)*256,:] ----------------
__global__ __launch_bounds__(256) void k_prep_F(
    const float* __restrict__ Wv, const float* __restrict__ fca_w,
    float* __restrict__ F)
{
    const int h = blockIdx.x >> 4;
    const int e0 = (blockIdx.x & 15) * 16;
    const int tid = threadIdx.x;
    __shared__ float sq[16][256];
    for (int idx = tid; idx < 4096; idx += 256) {
        int r = idx >> 8;
        int c = idx & 255;
        sq[r][c] = Wv[(size_t)h * 65536 + (e0 + r) * 256 + c];
    }
    __syncthreads();
    float acc[16];
    #pragma unroll
    for (int r = 0; r < 16; ++r) acc[r] = 0.f;
    for (int o = 0; o < 256; ++o) {
        float w = fca_w[(size_t)(h * 256 + o) * 256 + tid];
        #pragma unroll
        for (int r = 0; r < 16; ++r) acc[r] += sq[r][o] * w;
    }
    #pragma unroll
    for (int r = 0; r < 16; ++r)
        F[(size_t)(h * 256 + e0 + r) * 256 + tid] = acc[r];
}

// ---------------- setup: bvc[d] = bv(2048) . fca_w(2048x256) + fca_b ----------------
__global__ __launch_bounds__(256) void k_prep_bvc(
    const float* __restrict__ bv, const float* __restrict__ fca_w,
    const float* __restrict__ fca_b, float* __restrict__ bvc)
{
    const int tid = threadIdx.x;
    __shared__ float sbv[2048];
    for (int i = tid; i < 2048; i += 256) sbv[i] = bv[i];
    __syncthreads();
    float acc = fca_b[tid];
    for (int k = 0; k < 2048; ++k) acc += sbv[k] * fca_w[(size_t)k * 256 + tid];
    bvc[tid] = acc;
}

// ---------------- conv1 + conv2 (MFMA), J=4 seqs/block ----------------
__global__ __launch_bounds__(256, 3) void k_conv(
    const float* __restrict__ av1, const float* __restrict__ av2,
    const float* __restrict__ w1,
    const float* __restrict__ b1c, const float* __restrict__ g1,
    const float* __restrict__ be1, const float* __restrict__ m1, const float* __restrict__ v1,
    const ushort* __restrict__ w2f,
    const float* __restrict__ b2c, const float* __restrict__ g2,
    const float* __restrict__ be2, const float* __restrict__ m2, const float* __restrict__ v2,
    ushort* __restrict__ a2g, int seqoff)
{
    __shared__ ushort s_a1[4 * 3200];
    __shared__ float s_x[4][80];
    __shared__ float s_w1t[26 * 64];
    __shared__ float s_sc1[64], s_sh1[64], s_sc2[128], s_sh2[128];

    const int tid = threadIdx.x;
    const int lane = tid & 63;
    const int wv = tid >> 6;
    const int l15 = lane & 15;
    const int grp = lane >> 4;
    const int lseq0 = blockIdx.x * 4;
    const int gseq0 = seqoff + lseq0;

    for (int s = 0; s < 4; ++s) {
        int seq = gseq0 + s;
        const float* src;
        if (seq < HALFSEQ) { int b = seq / 22; int n = seq - b * 22; src = av1 + b * 600 + n * 25; }
        else { int q = seq - HALFSEQ; int b = q / 22; int n = q - b * 22; src = av2 + b * 600 + n * 25; }
        if (tid < 75) s_x[s][tid] = src[tid];
    }
    for (int i = tid; i < 1664; i += 256) {
        int o = i / 26; int t = i - o * 26;
        s_w1t[t * 64 + o] = w1[i];
    }
    if (tid < 64) { float A = g1[tid] * rsqrtf(v1[tid] + 1e-5f); s_sc1[tid] = A; s_sh1[tid] = (b1c[tid] - m1[tid]) * A + be1[tid]; }
    if (tid < 128) { float A = g2[tid] * rsqrtf(v2[tid] + 1e-5f); s_sc2[tid] = A; s_sh2[tid] = (b2c[tid] - m2[tid]) * A + be2[tid]; }
    __syncthreads();

    {
        int o = lane;
        int pb = wv;
        for (int s = 0; s < 4; ++s) {
            for (int p = pb; p < 50; p += 4) {
                float acc = 0.f;
                #pragma unroll
                for (int t = 0; t < 26; ++t) acc += s_w1t[t * 64 + o] * s_x[s][p + t];
                float y = acc * s_sc1[o] + s_sh1[o];
                y = y / (1.f + __expf(-y));
                int boff = s * 6400 + p * 128 + ((o * 2) ^ ((p & 7) << 4));
                *(ushort*)((char*)s_a1 + boff) = f2bf(y);
            }
        }
    }
    __syncthreads();

    {
        const int mset = wv >> 1;
        const int nset = wv & 1;
        const int NT = nset ? 3 : 4;

        int nbase[4], nrow[4];
        #pragma unroll
        for (int ni = 0; ni < 4; ++ni) {
            int n = (nset * 4 + ni) * 16 + l15;
            int s = n / 25; if (s > 3) s = 3;
            int p = n - s * 25; if (p > 24) p = 24;
            nbase[ni] = s * 6400;
            nrow[ni] = p;
        }

        f32x4 acc[4][4];
        #pragma unroll
        for (int mi = 0; mi < 4; ++mi)
            #pragma unroll
            for (int ni = 0; ni < 4; ++ni)
                acc[mi][ni] = (f32x4){0.f, 0.f, 0.f, 0.f};

        const ushort* wfp = w2f + (size_t)(mset * 4) * 512 + lane * 8;
        short8 afn[4];
        #pragma unroll
        for (int mi = 0; mi < 4; ++mi) afn[mi] = *(const short8*)(wfp + mi * 512);

        for (int kt = 0; kt < 52; ++kt) {
            const int t = kt >> 1;
            const int ic0b = ((kt & 1) * 32 + grp * 8) * 2;
            short8 af[4];
            #pragma unroll
            for (int mi = 0; mi < 4; ++mi) af[mi] = afn[mi];
            if (kt < 51) {
                #pragma unroll
                for (int mi = 0; mi < 4; ++mi)
                    afn[mi] = *(const short8*)(wfp + (kt + 1) * 4096 + mi * 512);
            }
            #pragma unroll
            for (int ni = 0; ni < 4; ++ni) {
                if (ni >= NT) break;
                int row = nrow[ni] + t;
                int boff = nbase[ni] + row * 128 + (ic0b ^ ((row & 7) << 4));
                short8 bf = *(const short8*)((const char*)s_a1 + boff);
                #pragma unroll
                for (int mi = 0; mi < 4; ++mi)
                    acc[mi][ni] = __builtin_amdgcn_mfma_f32_16x16x32_bf16(af[mi], bf, acc[mi][ni], 0, 0, 0);
            }
        }

        #pragma unroll
        for (int mi = 0; mi < 4; ++mi) {
            #pragma unroll
            for (int ni = 0; ni < 4; ++ni) {
                if (ni >= NT) break;
                int n = (nset * 4 + ni) * 16 + l15;
                if (n < 100) {
                    int s = n / 25;
                    int p = n - s * 25;
                    int ocb = mset * 64 + mi * 16 + grp * 4;
                    ushort* dst = a2g + (size_t)(lseq0 + s) * 3200 + p;
                    #pragma unroll
                    for (int r = 0; r < 4; ++r) {
                        float y = acc[mi][ni][r] * s_sc2[ocb + r] + s_sh2[ocb + r];
                        y = y / (1.f + __expf(-y));
                        dst[(ocb + r) * 25] = f2bf(y);
                    }
                }
            }
        }
    }
}

// ---------------- conv3 MFMA GEMM: M=256, N=32 seqs, K=3200; writes feat + featb ----------------
__global__ __launch_bounds__(256) void k_conv3(
    const ushort* __restrict__ a2g, const ushort* __restrict__ w3f,
    const float* __restrict__ b3c, const float* __restrict__ g3,
    const float* __restrict__ be3, const float* __restrict__ m3, const float* __restrict__ v3,
    float* __restrict__ feat, ushort* __restrict__ featb, int seqoff)
{
    const int tid = threadIdx.x;
    const int lane = tid & 63;
    const int wv = tid >> 6;
    const int l15 = lane & 15;
    const int grp = lane >> 4;
    const int lseq0 = blockIdx.x * 32;

    f32x4 acc3[4][2];
    #pragma unroll
    for (int mi = 0; mi < 4; ++mi)
        #pragma unroll
        for (int nt = 0; nt < 2; ++nt)
            acc3[mi][nt] = (f32x4){0.f, 0.f, 0.f, 0.f};

    const ushort* bp0 = a2g + (size_t)(lseq0 + l15) * 3200 + grp * 8;
    const ushort* bp1 = a2g + (size_t)(lseq0 + 16 + l15) * 3200 + grp * 8;
    const ushort* ap = w3f + (size_t)(wv * 4) * 512 + lane * 8;

    for (int kt = 0; kt < 100; ++kt) {
        short8 bf0 = *(const short8*)(bp0 + kt * 32);
        short8 bf1 = *(const short8*)(bp1 + kt * 32);
        #pragma unroll
        for (int mi = 0; mi < 4; ++mi) {
            short8 af = *(const short8*)(ap + (size_t)kt * 8192 + mi * 512);
            acc3[mi][0] = __builtin_amdgcn_mfma_f32_16x16x32_bf16(af, bf0, acc3[mi][0], 0, 0, 0);
            acc3[mi][1] = __builtin_amdgcn_mfma_f32_16x16x32_bf16(af, bf1, acc3[mi][1], 0, 0, 0);
        }
    }

    #pragma unroll
    for (int nt = 0; nt < 2; ++nt) {
        int gseq = seqoff + lseq0 + nt * 16 + l15;
        #pragma unroll
        for (int mi = 0; mi < 4; ++mi) {
            int oc = wv * 64 + mi * 16 + grp * 4;
            float4 o4;
            ushort4v u4;
            #pragma unroll
            for (int r = 0; r < 4; ++r) {
                float A = g3[oc + r] * rsqrtf(v3[oc + r] + 1e-5f);
                float y = acc3[mi][nt][r] * A + (b3c[oc + r] - m3[oc + r]) * A + be3[oc + r];
                y = y / (1.f + __expf(-y));
                ((float*)&o4)[r] = y;
                u4[r] = f2bf(y);
            }
            *(float4*)(feat + (size_t)gseq * 256 + oc) = o4;
            *(ushort4v*)(featb + (size_t)gseq * 256 + oc) = u4;
        }
    }
}

// ---------------- beta_all[row*8+h] = feat[row] . kb[h] ----------------
__global__ __launch_bounds__(256) void k_beta(
    const float* __restrict__ feat, const float* __restrict__ kb,
    float* __restrict__ beta_all)
{
    const int tid = threadIdx.x;
    const int row0 = blockIdx.x * 32;
    __shared__ float sf[32 * 260];
    __shared__ float skb[8 * 260];
    for (int idx = tid; idx < 8192; idx += 256) {
        int r = idx >> 8; int c = idx & 255;
        sf[r * 260 + c] = feat[(size_t)(row0 + r) * 256 + c];
    }
    for (int idx = tid; idx < 2048; idx += 256) {
        int hh = idx >> 8; int c = idx & 255;
        skb[hh * 260 + c] = kb[idx];
    }
    __syncthreads();
    int r = tid >> 3;
    int h = tid & 7;
    float a = 0.f;
    const float* fr = sf + r * 260;
    const float* kr = skb + h * 260;
    for (int e = 0; e < 256; ++e) a += fr[e] * kr[e];
    beta_all[(size_t)(row0 + r) * 8 + h] = a;
}

// ---------------- phase A: Gall = featb @ M (per head), MFMA, no LDS ----------------
// grid = (seqs/32) * 8;  h = bid&7, sb = bid>>3. Gall local rows (chunk).
__global__ __launch_bounds__(256) void k_gemmG(
    const ushort* __restrict__ featb, const ushort* __restrict__ Mfrag,
    ushort* __restrict__ Gall, int seq0)
{
    const int bid = blockIdx.x;
    const int h = bid & 7;
    const int sb = bid >> 3;
    const int tid = threadIdx.x;
    const int lane = tid & 63;
    const int wv = tid >> 6;
    const int l15 = lane & 15;
    const int grp = lane >> 4;

    f32x4 acc[4][2];
    #pragma unroll
    for (int mi = 0; mi < 4; ++mi)
        #pragma unroll
        for (int nt = 0; nt < 2; ++nt)
            acc[mi][nt] = (f32x4){0.f, 0.f, 0.f, 0.f};

    const ushort* bp0 = featb + (size_t)(seq0 + sb * 32 + l15) * 256 + grp * 8;
    const ushort* bp1 = bp0 + 16 * 256;
    const ushort* mf = Mfrag + ((size_t)(h * 8) * 16 + wv * 4) * 512 + lane * 8;

    for (int kt = 0; kt < 8; ++kt) {
        short8 bf0 = *(const short8*)(bp0 + kt * 32);
        short8 bf1 = *(const short8*)(bp1 + kt * 32);
        #pragma unroll
        for (int mi = 0; mi < 4; ++mi) {
            short8 af = *(const short8*)(mf + kt * 8192 + mi * 512);
            acc[mi][0] = __builtin_amdgcn_mfma_f32_16x16x32_bf16(af, bf0, acc[mi][0], 0, 0, 0);
            acc[mi][1] = __builtin_amdgcn_mfma_f32_16x16x32_bf16(af, bf1, acc[mi][1], 0, 0, 0);
        }
    }

    #pragma unroll
    for (int nt = 0; nt < 2; ++nt) {
        int lrow = sb * 32 + nt * 16 + l15;   // chunk-local row
        #pragma unroll
        for (int mi = 0; mi < 4; ++mi) {
            int o = wv * 64 + mi * 16 + grp * 4;
            ushort4v u4;
            #pragma unroll
            for (int r = 0; r < 4; ++r) u4[r] = f2bf(acc[mi][nt][r]);
            *(ushort4v*)(Gall + (size_t)lrow * 2048 + h * 256 + o) = u4;
        }
    }
}

// ---------------- phase B: S, softmax, Abar, fbar (per g,h) ----------------
// grid = groups_c * 8; g_local = bid>>3, h = bid&7.
__global__ __launch_bounds__(256) void k_attn2(
    const float* __restrict__ feat, const ushort* __restrict__ Gall,
    const float* __restrict__ beta_all,
    float* __restrict__ fbar_all, int g0)
{
    const int bid = blockIdx.x;
    const int gl = bid >> 3;
    const int h = bid & 7;
    const int g = g0 + gl;
    const int tid = threadIdx.x;
    const int FS = 260;

    __shared__ __align__(16) float fL[22 * 260];
    __shared__ __align__(16) float gL[22 * 260];
    __shared__ float sS[22 * 24];
    __shared__ float sbe[22], sab[22];

    const float* fsrc = feat + (size_t)g * 22 * 256;
    const ushort* gsrc = Gall + (size_t)gl * 22 * 2048 + h * 256;
    for (int idx = tid; idx < 5632; idx += 256) {
        int s = idx >> 8;
        int e = idx & 255;
        fL[s * FS + e] = fsrc[idx];
        gL[s * FS + e] = bf2f(gsrc[(size_t)s * 2048 + e]);
    }
    if (tid < 22) sbe[tid] = beta_all[((size_t)g * 22 + tid) * 8 + h];
    __syncthreads();

    for (int idx = tid; idx < 484; idx += 256) {
        int s = idx / 22;
        int t = idx - s * 22;
        const float* gr = gL + s * FS;
        const float* fr = fL + t * FS;
        float acc = 0.f;
        for (int e = 0; e < 256; e += 4) {
            float4 g4 = *(const float4*)(gr + e);
            float4 f4 = *(const float4*)(fr + e);
            acc += g4.x * f4.x + g4.y * f4.y + g4.z * f4.z + g4.w * f4.w;
        }
        sS[s * 24 + t] = acc + sbe[t];
    }
    __syncthreads();

    if (tid < 22) {
        int s = tid;
        float mx = -1e30f;
        #pragma unroll
        for (int t = 0; t < 22; ++t) mx = fmaxf(mx, sS[s * 24 + t]);
        float ex[22];
        float sum = 0.f;
        #pragma unroll
        for (int t = 0; t < 22; ++t) { float e2 = __expf(sS[s * 24 + t] - mx); ex[t] = e2; sum += e2; }
        float inv = 1.f / sum;
        #pragma unroll
        for (int t = 0; t < 22; ++t) sS[s * 24 + t] = ex[t] * inv;
    }
    __syncthreads();
    if (tid < 22) {
        int t = tid;
        float a = 0.f;
        #pragma unroll
        for (int s = 0; s < 22; ++s) a += sS[s * 24 + t];
        sab[t] = a * (1.f / 22.f);
    }
    __syncthreads();

    {
        float a = 0.f;
        #pragma unroll
        for (int t = 0; t < 22; ++t) a += sab[t] * fL[t * FS + tid];
        fbar_all[((size_t)g * 8 + h) * 256 + tid] = a;
    }
}

// ---------------- k_pool: pooled = sum_h fbar@F[h] + bvc; y = pooled@fc_w + fc_b ----------------
// grid 256, 4 groups per block.
__global__ __launch_bounds__(256) void k_pool(
    const float* __restrict__ fbar_all, const float* __restrict__ F,
    const float* __restrict__ bvc,
    const float* __restrict__ fc_w, const float* __restrict__ fc_b,
    float* __restrict__ out)
{
    const int g0 = blockIdx.x * 4;
    const int tid = threadIdx.x;
    __shared__ __align__(16) float sfb[32 * 256];
    __shared__ __align__(16) float sp[4 * 256];
    for (int idx = tid; idx < 8192; idx += 256)
        sfb[idx] = fbar_all[(size_t)g0 * 8 * 256 + idx];
    __syncthreads();

    float p[4];
    float bb = bvc[tid];
    #pragma unroll
    for (int j = 0; j < 4; ++j) p[j] = bb;
    for (int k = 0; k < 2048; ++k) {
        float f = F[(size_t)k * 256 + tid];
        int rk = (k >> 8) * 256 + (k & 255);
        #pragma unroll
        for (int j = 0; j < 4; ++j) p[j] += sfb[j * 2048 + rk] * f;
    }
    #pragma unroll
    for (int j = 0; j < 4; ++j) sp[j * 256 + tid] = p[j];
    __syncthreads();

    float y[4];
    float fb = fc_b[tid];
    #pragma unroll
    for (int j = 0; j < 4; ++j) y[j] = fb;
    for (int e = 0; e < 256; ++e) {
        float w = fc_w[(size_t)e * 256 + tid];
        #pragma unroll
        for (int j = 0; j < 4; ++j) y[j] += sp[j * 256 + e] * w;
    }
    #pragma unroll
    for (int j = 0; j < 4; ++j)
        out[(size_t)(g0 + j) * 256 + tid] = y[j];
}

// ---------------- launch ----------------
extern "C" void kernel_launch(void* const* d_in, const int* in_sizes, int n_in,
                              void* d_out, int out_size, void* d_ws, size_t ws_size,
                              hipStream_t stream) {
    (void)in_sizes; (void)n_in; (void)out_size;

    const float* av1   = (const float*)d_in[0];
    const float* av2   = (const float*)d_in[1];
    const float* w1    = (const float*)d_in[2];
    const float* b1c   = (const float*)d_in[3];
    const float* g1    = (const float*)d_in[4];
    const float* be1   = (const float*)d_in[5];
    const float* m1    = (const float*)d_in[6];
    const float* v1    = (const float*)d_in[7];
    const float* w2    = (const float*)d_in[8];
    const float* b2c   = (const float*)d_in[9];
    const float* g2    = (const float*)d_in[10];
    const float* be2   = (const float*)d_in[11];
    const float* m2    = (const float*)d_in[12];
    const float* v2    = (const float*)d_in[13];
    const float* w3    = (const float*)d_in[14];
    const float* b3c   = (const float*)d_in[15];
    const float* g3    = (const float*)d_in[16];
    const float* be3   = (const float*)d_in[17];
    const float* m3    = (const float*)d_in[18];
    const float* v3    = (const float*)d_in[19];
    const float* Wq    = (const float*)d_in[20];
    const float* bq    = (const float*)d_in[21];
    const float* Wk    = (const float*)d_in[22];
    const float* bk    = (const float*)d_in[23];
    const float* Wv    = (const float*)d_in[24];
    const float* bv    = (const float*)d_in[25];
    const float* fca_w = (const float*)d_in[26];
    const float* fca_b = (const float*)d_in[27];
    const float* fc_w  = (const float*)d_in[28];
    const float* fc_b  = (const float*)d_in[29];
    (void)bk;

    float* ws = (float*)d_ws;
    float* feat = ws;                         //  5,767,168 f
    float* Mm   = feat + 5767168;             //    524,288 f
    float* WkT  = Mm + 524288;                //    524,288 f
    float* kb   = WkT + 524288;               //      2,048 f
    float* bvc  = kb + 2048;                  //        256 f
    float* F    = bvc + 256;                  //    524,288 f
    float* fbar = F + 524288;                 //  2,097,152 f
    float* beta = fbar + 2097152;             //    180,224 f
    ushort* w2f = (ushort*)(beta + 180224);   //    212,992 u16
    ushort* w3f = w2f + 212992;               //    819,200 u16
    ushort* featb = w3f + 819200;             //  5,767,168 u16
    ushort* mfr = featb + 5767168;            //    524,288 u16
    ushort* region = mfr + 524288;            // shared: a2g / Gall chunk

    size_t base_bytes = (size_t)((char*)region - (char*)d_ws);
    size_t budget = (ws_size > base_bytes + 4096) ? (ws_size - base_bytes - 4096) : 0;
    int ncA = 16, ncG = 16;
    const int cand[5] = {1, 2, 4, 8, 16};
    for (int i = 0; i < 5; ++i) { if ((size_t)144179200 / cand[i] <= budget) { ncA = cand[i]; break; } }
    for (int i = 0; i < 5; ++i) { if ((size_t)92274688 / cand[i] <= budget) { ncG = cand[i]; break; } }
    const int seqsA = NSEQ / ncA;
    const int grpG = 1024 / ncG;

    // setup
    k_prep_w2<<<832, 256, 0, stream>>>(w2, w2f);
    k_prep_w3<<<3200, 256, 0, stream>>>(w3, w3f);
    k_transpose<<<2048, 256, 0, stream>>>(Wk, WkT, 8, 256, 256);
    k_prep_attn_m<<<128, 256, 0, stream>>>(Wq, WkT, Mm);
    k_prep_mfrag<<<2048, 256, 0, stream>>>(Mm, mfr);
    k_prep_kb<<<8, 256, 0, stream>>>(Wk, bq, kb);
    k_prep_F<<<128, 256, 0, stream>>>(Wv, fca_w, F);
    k_prep_bvc<<<1, 256, 0, stream>>>(bv, fca_w, fca_b, bvc);

    // conv pipeline (a2g chunked through region)
    ushort* a2g = region;
    for (int c = 0; c < ncA; ++c) {
        int seqoff = c * seqsA;
        k_conv<<<seqsA / 4, 256, 0, stream>>>(av1, av2,
            w1, b1c, g1, be1, m1, v1,
            w2f, b2c, g2, be2, m2, v2,
            a2g, seqoff);
        k_conv3<<<seqsA / 32, 256, 0, stream>>>(a2g, w3f,
            b3c, g3, be3, m3, v3, feat, featb, seqoff);
    }

    k_beta<<<704, 256, 0, stream>>>(feat, kb, beta);

    // attention pipeline (Gall chunked through region)
    ushort* Gall = region;
    for (int c = 0; c < ncG; ++c) {
        int g0 = c * grpG;
        int seq0 = g0 * 22;
        k_gemmG<<<(grpG * 22 / 32) * 8, 256, 0, stream>>>(featb, mfr, Gall, seq0);
        k_attn2<<<grpG * 8, 256, 0, stream>>>(feat, Gall, beta, fbar, g0);
    }

    k_pool<<<256, 256, 0, stream>>>(fbar, F, bvc, fc_w, fc_b, (float*)d_out);
}

// Round 5
// 703.468 us; speedup vs baseline: 7.7540x; 1.2270x over previous
//
#include <hip/hip_runtime.h>
#include <hip/hip_bf16.h>
#include <math.h>

// ---------------- problem constants ----------------
#define NSEQ 22528
#define HALFSEQ 11264

typedef __attribute__((ext_vector_type(8))) short short8;
typedef __attribute__((ext_vector_type(4))) float f32x4;
typedef __attribute__((ext_vector_type(4))) ushort ushort4v;

__device__ __forceinline__ ushort f2bf(float x) {
    __hip_bfloat16 h = __float2bfloat16(x);
    return *reinterpret_cast<ushort*>(&h);
}
__device__ __forceinline__ float bf2f(ushort u) {
    unsigned v = ((unsigned)u) << 16;
    return *reinterpret_cast<float*>(&v);
}

// ---------------- setup: transpose (for WkT) ----------------
__global__ void k_transpose(const float* __restrict__ in, float* __restrict__ out,
                            int Bn, int R, int C) {
    int idx = blockIdx.x * 256 + threadIdx.x;
    int total = Bn * R * C;
    if (idx >= total) return;
    int b = idx / (R * C);
    int rem = idx - b * R * C;
    int c = rem / R;
    int r = rem - c * R;
    out[idx] = in[(b * R + r) * C + c];
}

// ---------------- setup: bf16 weight repacks in MFMA fragment order ----------------
__global__ void k_prep_w2(const float* __restrict__ w2, ushort* __restrict__ w2f) {
    int idx = blockIdx.x * 256 + threadIdx.x;
    if (idx >= 212992) return;
    int j = idx & 7;
    int lane = (idx >> 3) & 63;
    int mt = (idx >> 9) & 7;
    int kt = idx >> 12;
    int oc = mt * 16 + (lane & 15);
    int k = kt * 32 + ((lane >> 4) << 3) + j;
    int t = k >> 6;
    int ic = k & 63;
    w2f[idx] = f2bf(w2[(oc * 64 + ic) * 26 + t]);
}
__global__ void k_prep_w3(const float* __restrict__ w3, ushort* __restrict__ w3f) {
    int idx = blockIdx.x * 256 + threadIdx.x;
    if (idx >= 819200) return;
    int j = idx & 7;
    int lane = (idx >> 3) & 63;
    int mt = (idx >> 9) & 15;
    int kt = idx >> 13;
    int oc = mt * 16 + (lane & 15);
    int k = kt * 32 + ((lane >> 4) << 3) + j;
    w3f[idx] = f2bf(w3[oc * 3200 + k]);
}

// ---------------- setup: M = Wq Wk^T (16-row tiles) ----------------
__global__ __launch_bounds__(256) void k_prep_attn_m(
    const float* __restrict__ Wq, const float* __restrict__ WkT,
    float* __restrict__ M)
{
    const int h = blockIdx.x >> 4;
    const int e0 = (blockIdx.x & 15) * 16;
    const int tid = threadIdx.x;
    __shared__ float sq[16][256];
    for (int idx = tid; idx < 4096; idx += 256) {
        int r = idx >> 8;
        int c = idx & 255;
        sq[r][c] = Wq[(size_t)(h * 256 + e0 + r) * 256 + c];
    }
    __syncthreads();
    float acc[16];
    #pragma unroll
    for (int r = 0; r < 16; ++r) acc[r] = 0.f;
    const float* wkt = WkT + (size_t)h * 65536 + tid;
    for (int o = 0; o < 256; ++o) {
        float wk = wkt[o * 256];
        #pragma unroll
        for (int r = 0; r < 16; ++r) acc[r] += sq[r][o] * wk;
    }
    #pragma unroll
    for (int r = 0; r < 16; ++r)
        M[(size_t)(h * 256 + e0 + r) * 256 + tid] = acc[r];
}

// ---------------- setup: Mfrag bf16 fragment-packed (8 heads) ----------------
// Mfrag[((h*8+kt)*16+mt)*512 + lane*8 + j] = M[h][e=kt*32+(lane>>4)*8+j][o=mt*16+(lane&15)]
__global__ void k_prep_mfrag(const float* __restrict__ M, ushort* __restrict__ Mfrag) {
    int idx = blockIdx.x * 256 + threadIdx.x;   // 524288 total
    int j = idx & 7;
    int lane = (idx >> 3) & 63;
    int mt = (idx >> 9) & 15;
    int kt = (idx >> 13) & 7;
    int h = idx >> 16;
    int e = kt * 32 + ((lane >> 4) << 3) + j;
    int o = mt * 16 + (lane & 15);
    Mfrag[idx] = f2bf(M[(size_t)(h * 256 + e) * 256 + o]);
}

// ---------------- setup: kb[h][e] = Wk[h][e] . bq[h] ----------------
__global__ __launch_bounds__(256) void k_prep_kb(
    const float* __restrict__ Wk, const float* __restrict__ bq,
    float* __restrict__ kb)
{
    const int h = blockIdx.x;
    const int tid = threadIdx.x;
    __shared__ float sbq[256];
    sbq[tid] = bq[h * 256 + tid];
    __syncthreads();
    const float* wk = Wk + (size_t)(h * 256 + tid) * 256;
    float a = 0.f;
    for (int o = 0; o < 256; ++o) a += wk[o] * sbq[o];
    kb[h * 256 + tid] = a;
}

// ---------------- setup: F[h] = Wv[h] @ fca_w[h*256:(h+1)*256,:] ----------------
__global__ __launch_bounds__(256) void k_prep_F(
    const float* __restrict__ Wv, const float* __restrict__ fca_w,
    float* __restrict__ F)
{
    const int h = blockIdx.x >> 4;
    const int e0 = (blockIdx.x & 15) * 16;
    const int tid = threadIdx.x;
    __shared__ float sq[16][256];
    for (int idx = tid; idx < 4096; idx += 256) {
        int r = idx >> 8;
        int c = idx & 255;
        sq[r][c] = Wv[(size_t)h * 65536 + (e0 + r) * 256 + c];
    }
    __syncthreads();
    float acc[16];
    #pragma unroll
    for (int r = 0; r < 16; ++r) acc[r] = 0.f;
    for (int o = 0; o < 256; ++o) {
        float w = fca_w[(size_t)(h * 256 + o) * 256 + tid];
        #pragma unroll
        for (int r = 0; r < 16; ++r) acc[r] += sq[r][o] * w;
    }
    #pragma unroll
    for (int r = 0; r < 16; ++r)
        F[(size_t)(h * 256 + e0 + r) * 256 + tid] = acc[r];
}

// ---------------- setup: bvc[d] = bv(2048) . fca_w(2048x256) + fca_b ----------------
__global__ __launch_bounds__(256) void k_prep_bvc(
    const float* __restrict__ bv, const float* __restrict__ fca_w,
    const float* __restrict__ fca_b, float* __restrict__ bvc)
{
    const int tid = threadIdx.x;
    __shared__ float sbv[2048];
    for (int i = tid; i < 2048; i += 256) sbv[i] = bv[i];
    __syncthreads();
    float acc = fca_b[tid];
    for (int k = 0; k < 2048; ++k) acc += sbv[k] * fca_w[(size_t)k * 256 + tid];
    bvc[tid] = acc;
}

// ---------------- conv1 (MFMA) + conv2 (MFMA), J=4 seqs/block ----------------
__global__ __launch_bounds__(256, 4) void k_conv(
    const float* __restrict__ av1, const float* __restrict__ av2,
    const float* __restrict__ w1,
    const float* __restrict__ b1c, const float* __restrict__ g1,
    const float* __restrict__ be1, const float* __restrict__ m1, const float* __restrict__ v1,
    const ushort* __restrict__ w2f,
    const float* __restrict__ b2c, const float* __restrict__ g2,
    const float* __restrict__ be2, const float* __restrict__ m2, const float* __restrict__ v2,
    ushort* __restrict__ a2g, int seqoff)
{
    __shared__ ushort s_a1[4 * 3200];     // per seq [p 50][ic 64] bf16, swizzled 16B slots
    __shared__ ushort s_w1f[2048];        // conv1 A fragments: 4 mt x 512
    __shared__ float s_x[4][80];
    __shared__ ushort s_xb[4][80];
    __shared__ float s_sc1[64], s_sh1[64], s_sc2[128], s_sh2[128];

    const int tid = threadIdx.x;
    const int lane = tid & 63;
    const int wv = tid >> 6;
    const int l15 = lane & 15;
    const int grp = lane >> 4;
    const int lseq0 = blockIdx.x * 4;
    const int gseq0 = seqoff + lseq0;

    // ---- stage x (fp32 + bf16), w1 fragments, BN params ----
    for (int s = 0; s < 4; ++s) {
        int seq = gseq0 + s;
        const float* src;
        if (seq < HALFSEQ) { int b = seq / 22; int n = seq - b * 22; src = av1 + b * 600 + n * 25; }
        else { int q = seq - HALFSEQ; int b = q / 22; int n = q - b * 22; src = av2 + b * 600 + n * 25; }
        if (tid < 80) {
            float v = (tid < 75) ? src[tid] : 0.f;
            s_x[s][tid] = v;
            s_xb[s][tid] = f2bf(v);
        }
    }
    for (int idx = tid; idx < 2048; idx += 256) {
        int j = idx & 7;
        int ln = (idx >> 3) & 63;
        int mt = idx >> 9;
        int oc = mt * 16 + (ln & 15);
        int k = ((ln >> 4) << 3) + j;
        s_w1f[idx] = (k < 26) ? f2bf(w1[oc * 26 + k]) : (ushort)0;
    }
    if (tid < 64) { float A = g1[tid] * rsqrtf(v1[tid] + 1e-5f); s_sc1[tid] = A; s_sh1[tid] = (b1c[tid] - m1[tid]) * A + be1[tid]; }
    if (tid < 128) { float A = g2[tid] * rsqrtf(v2[tid] + 1e-5f); s_sc2[tid] = A; s_sh2[tid] = (b2c[tid] - m2[tid]) * A + be2[tid]; }
    __syncthreads();

    // ---- conv1 MFMA: M=64 (4 mt), N=200 (13 nt, n=s*50+p), K=32 (t pad) ----
    {
        short8 a1f[4];
        #pragma unroll
        for (int mt = 0; mt < 4; ++mt)
            a1f[mt] = *(const short8*)(s_w1f + mt * 512 + lane * 8);

        for (int nt = wv; nt < 13; nt += 4) {
            int n = nt * 16 + l15;
            int s = (n >= 50) + (n >= 100) + (n >= 150);
            int p = n - s * 50;
            if (p > 49) p = 49;   // dummy lanes (n>=200)
            // B fragment: x[s][p + t], t = grp*8+j (0 for t>=26)
            short8 bf;
            #pragma unroll
            for (int j = 0; j < 8; ++j) {
                int t = grp * 8 + j;
                bf[j] = (t < 26) ? (short)s_xb[s][p + t] : (short)0;
            }
            f32x4 acc1[4];
            #pragma unroll
            for (int mt = 0; mt < 4; ++mt) {
                acc1[mt] = (f32x4){0.f, 0.f, 0.f, 0.f};
                acc1[mt] = __builtin_amdgcn_mfma_f32_16x16x32_bf16(a1f[mt], bf, acc1[mt], 0, 0, 0);
            }
            if (n < 200) {
                #pragma unroll
                for (int mt = 0; mt < 4; ++mt) {
                    #pragma unroll
                    for (int r = 0; r < 4; ++r) {
                        int oc = mt * 16 + grp * 4 + r;
                        float y = acc1[mt][r] * s_sc1[oc] + s_sh1[oc];
                        y = y / (1.f + __expf(-y));
                        int boff = s * 6400 + p * 128 + ((oc * 2) ^ ((p & 7) << 4));
                        *(ushort*)((char*)s_a1 + boff) = f2bf(y);
                    }
                }
            }
        }
    }
    __syncthreads();

    // ---- conv2 MFMA: C[oc 128][n = s*25+p, 100 of 112] over K=1664 ----
    {
        const int mset = wv >> 1;
        const int nset = wv & 1;
        const int NT = nset ? 3 : 4;

        int nbase[4], nrow[4];
        #pragma unroll
        for (int ni = 0; ni < 4; ++ni) {
            int n = (nset * 4 + ni) * 16 + l15;
            int s = n / 25; if (s > 3) s = 3;
            int p = n - s * 25; if (p > 24) p = 24;
            nbase[ni] = s * 6400;
            nrow[ni] = p;
        }

        f32x4 acc[4][4];
        #pragma unroll
        for (int mi = 0; mi < 4; ++mi)
            #pragma unroll
            for (int ni = 0; ni < 4; ++ni)
                acc[mi][ni] = (f32x4){0.f, 0.f, 0.f, 0.f};

        const ushort* wfp = w2f + (size_t)(mset * 4) * 512 + lane * 8;
        short8 afn[4];
        #pragma unroll
        for (int mi = 0; mi < 4; ++mi) afn[mi] = *(const short8*)(wfp + mi * 512);

        for (int kt = 0; kt < 52; ++kt) {
            const int t = kt >> 1;
            const int ic0b = ((kt & 1) * 32 + grp * 8) * 2;
            short8 af[4];
            #pragma unroll
            for (int mi = 0; mi < 4; ++mi) af[mi] = afn[mi];
            if (kt < 51) {
                #pragma unroll
                for (int mi = 0; mi < 4; ++mi)
                    afn[mi] = *(const short8*)(wfp + (kt + 1) * 4096 + mi * 512);
            }
            #pragma unroll
            for (int ni = 0; ni < 4; ++ni) {
                if (ni >= NT) break;
                int row = nrow[ni] + t;
                int boff = nbase[ni] + row * 128 + (ic0b ^ ((row & 7) << 4));
                short8 bf = *(const short8*)((const char*)s_a1 + boff);
                #pragma unroll
                for (int mi = 0; mi < 4; ++mi)
                    acc[mi][ni] = __builtin_amdgcn_mfma_f32_16x16x32_bf16(af[mi], bf, acc[mi][ni], 0, 0, 0);
            }
        }

        #pragma unroll
        for (int mi = 0; mi < 4; ++mi) {
            #pragma unroll
            for (int ni = 0; ni < 4; ++ni) {
                if (ni >= NT) break;
                int n = (nset * 4 + ni) * 16 + l15;
                if (n < 100) {
                    int s = n / 25;
                    int p = n - s * 25;
                    int ocb = mset * 64 + mi * 16 + grp * 4;
                    ushort* dst = a2g + (size_t)(lseq0 + s) * 3200 + p;
                    #pragma unroll
                    for (int r = 0; r < 4; ++r) {
                        float y = acc[mi][ni][r] * s_sc2[ocb + r] + s_sh2[ocb + r];
                        y = y / (1.f + __expf(-y));
                        dst[(ocb + r) * 25] = f2bf(y);
                    }
                }
            }
        }
    }
}

// ---------------- conv3 MFMA GEMM: M=256, N=32 seqs, K=3200 ----------------
__global__ __launch_bounds__(256) void k_conv3(
    const ushort* __restrict__ a2g, const ushort* __restrict__ w3f,
    const float* __restrict__ b3c, const float* __restrict__ g3,
    const float* __restrict__ be3, const float* __restrict__ m3, const float* __restrict__ v3,
    float* __restrict__ feat, int seqoff)
{
    const int tid = threadIdx.x;
    const int lane = tid & 63;
    const int wv = tid >> 6;
    const int l15 = lane & 15;
    const int grp = lane >> 4;
    const int lseq0 = blockIdx.x * 32;

    f32x4 acc3[4][2];
    #pragma unroll
    for (int mi = 0; mi < 4; ++mi)
        #pragma unroll
        for (int nt = 0; nt < 2; ++nt)
            acc3[mi][nt] = (f32x4){0.f, 0.f, 0.f, 0.f};

    const ushort* bp0 = a2g + (size_t)(lseq0 + l15) * 3200 + grp * 8;
    const ushort* bp1 = a2g + (size_t)(lseq0 + 16 + l15) * 3200 + grp * 8;
    const ushort* ap = w3f + (size_t)(wv * 4) * 512 + lane * 8;

    for (int kt = 0; kt < 100; ++kt) {
        short8 bf0 = *(const short8*)(bp0 + kt * 32);
        short8 bf1 = *(const short8*)(bp1 + kt * 32);
        #pragma unroll
        for (int mi = 0; mi < 4; ++mi) {
            short8 af = *(const short8*)(ap + (size_t)kt * 8192 + mi * 512);
            acc3[mi][0] = __builtin_amdgcn_mfma_f32_16x16x32_bf16(af, bf0, acc3[mi][0], 0, 0, 0);
            acc3[mi][1] = __builtin_amdgcn_mfma_f32_16x16x32_bf16(af, bf1, acc3[mi][1], 0, 0, 0);
        }
    }

    #pragma unroll
    for (int nt = 0; nt < 2; ++nt) {
        int gseq = seqoff + lseq0 + nt * 16 + l15;
        #pragma unroll
        for (int mi = 0; mi < 4; ++mi) {
            int oc = wv * 64 + mi * 16 + grp * 4;
            float4 o4;
            #pragma unroll
            for (int r = 0; r < 4; ++r) {
                float A = g3[oc + r] * rsqrtf(v3[oc + r] + 1e-5f);
                float y = acc3[mi][nt][r] * A + (b3c[oc + r] - m3[oc + r]) * A + be3[oc + r];
                ((float*)&o4)[r] = y / (1.f + __expf(-y));
            }
            *(float4*)(feat + (size_t)gseq * 256 + oc) = o4;
        }
    }
}

// ---------------- fused attention: per g, all 8 heads, MFMA S ----------------
// grid 1024. G and S via MFMA; softmax/Abar/fbar in-block; beta in-block.
__global__ __launch_bounds__(256, 2) void k_attn_f(
    const float* __restrict__ feat, const ushort* __restrict__ Mfrag,
    const float* __restrict__ kb, float* __restrict__ fbar_all)
{
    const int g = blockIdx.x;
    const int tid = threadIdx.x;
    const int lane = tid & 63;
    const int wv = tid >> 6;
    const int l15 = lane & 15;
    const int grp = lane >> 4;

    __shared__ __align__(16) float sfL[22 * 260];      // fp32 feat rows
    __shared__ __align__(16) ushort sfb[32 * 256];     // bf16 feat, XOR-swizzled rows
    __shared__ __align__(16) ushort sG[32 * 256];      // bf16 G, XOR-swizzled rows
    __shared__ float sS[22 * 24];
    __shared__ float sbet[8][24];
    __shared__ float sab[24];

    // ---- load feat -> sfL (fp32) + sfb (bf16 swizzled), zero pad rows ----
    const float* fsrc = feat + (size_t)g * 5632;
    for (int idx = tid; idx < 8192; idx += 256) {
        int s = idx >> 8;
        int e = idx & 255;
        float f = 0.f;
        if (s < 22) { f = fsrc[s * 256 + e]; sfL[s * 260 + e] = f; }
        int byte = s * 512 + ((e * 2) ^ ((s & 7) << 4));
        *(ushort*)((char*)sfb + byte) = f2bf(f);
    }
    __syncthreads();

    // ---- beta[t][h] = sfL[t] . kb[h] ----
    if (tid < 176) {
        int t = tid >> 3;
        int h = tid & 7;
        const float* kr = kb + h * 256;
        const float* fr = sfL + t * 260;
        float a = 0.f;
        for (int e = 0; e < 256; ++e) a += fr[e] * kr[e];
        sbet[h][t] = a;
    }
    __syncthreads();

    for (int h = 0; h < 8; ++h) {
        // ---- step 1: G[s][f] = sum_e fL[s][e] M[e][f];  wave wv owns f-tiles wv*4.. ----
        {
            f32x4 accg[2][4];
            #pragma unroll
            for (int mt = 0; mt < 2; ++mt)
                #pragma unroll
                for (int fi = 0; fi < 4; ++fi)
                    accg[mt][fi] = (f32x4){0.f, 0.f, 0.f, 0.f};

            const ushort* mfb = Mfrag + (size_t)h * 65536;
            for (int kt = 0; kt < 8; ++kt) {
                int e0b = (kt * 32 + grp * 8) * 2;
                int rA0 = l15, rA1 = 16 + l15;
                short8 af0 = *(const short8*)((const char*)sfb + rA0 * 512 + (e0b ^ ((rA0 & 7) << 4)));
                short8 af1 = *(const short8*)((const char*)sfb + rA1 * 512 + (e0b ^ ((rA1 & 7) << 4)));
                #pragma unroll
                for (int fi = 0; fi < 4; ++fi) {
                    int ft = wv * 4 + fi;
                    short8 bfm = *(const short8*)(mfb + (size_t)((kt * 16 + ft) << 9) + lane * 8);
                    accg[0][fi] = __builtin_amdgcn_mfma_f32_16x16x32_bf16(af0, bfm, accg[0][fi], 0, 0, 0);
                    accg[1][fi] = __builtin_amdgcn_mfma_f32_16x16x32_bf16(af1, bfm, accg[1][fi], 0, 0, 0);
                }
            }
            #pragma unroll
            for (int mt = 0; mt < 2; ++mt) {
                #pragma unroll
                for (int fi = 0; fi < 4; ++fi) {
                    int f = (wv * 4 + fi) * 16 + l15;
                    #pragma unroll
                    for (int r = 0; r < 4; ++r) {
                        int s = mt * 16 + grp * 4 + r;
                        if (s < 22) {
                            int byte = s * 512 + ((f * 2) ^ ((s & 7) << 4));
                            *(ushort*)((char*)sG + byte) = f2bf(accg[mt][fi][r]);
                        }
                    }
                }
            }
        }
        __syncthreads();

        // ---- step 2: S[s][t] = sum_f G[s][f] fL[t][f] + beta[t]; 4 tiles, 1/wave ----
        {
            int mt2 = wv >> 1;
            int nt2 = wv & 1;
            f32x4 sacc = (f32x4){0.f, 0.f, 0.f, 0.f};
            int sA = mt2 * 16 + l15;
            int tB = nt2 * 16 + l15;
            for (int kt = 0; kt < 8; ++kt) {
                int f0b = (kt * 32 + grp * 8) * 2;
                short8 ga = *(const short8*)((const char*)sG + sA * 512 + (f0b ^ ((sA & 7) << 4)));
                short8 fb = *(const short8*)((const char*)sfb + tB * 512 + (f0b ^ ((tB & 7) << 4)));
                sacc = __builtin_amdgcn_mfma_f32_16x16x32_bf16(ga, fb, sacc, 0, 0, 0);
            }
            #pragma unroll
            for (int r = 0; r < 4; ++r) {
                int s = mt2 * 16 + grp * 4 + r;
                int t = nt2 * 16 + l15;
                if (s < 22 && t < 22) sS[s * 24 + t] = sacc[r] + sbet[h][t];
            }
        }
        __syncthreads();

        // ---- softmax rows ----
        if (tid < 22) {
            int s = tid;
            float mx = -1e30f;
            #pragma unroll
            for (int t = 0; t < 22; ++t) mx = fmaxf(mx, sS[s * 24 + t]);
            float ex[22];
            float sum = 0.f;
            #pragma unroll
            for (int t = 0; t < 22; ++t) { float e2 = __expf(sS[s * 24 + t] - mx); ex[t] = e2; sum += e2; }
            float inv = 1.f / sum;
            #pragma unroll
            for (int t = 0; t < 22; ++t) sS[s * 24 + t] = ex[t] * inv;
        }
        __syncthreads();
        if (tid < 22) {
            int t = tid;
            float a = 0.f;
            #pragma unroll
            for (int s = 0; s < 22; ++s) a += sS[s * 24 + t];
            sab[t] = a * (1.f / 22.f);
        }
        __syncthreads();

        // ---- fbar[e] = sum_t Abar[t] fL[t][e] ----
        {
            float a = 0.f;
            #pragma unroll
            for (int t = 0; t < 22; ++t) a += sab[t] * sfL[t * 260 + tid];
            fbar_all[((size_t)g * 8 + h) * 256 + tid] = a;
        }
        // no barrier needed: next head's writes (sG) don't race current reads,
        // and sS/sab rewrites are behind >=2 barriers.
    }
}

// ---------------- k_pool: pooled = sum_h fbar@F[h] + bvc; y = pooled@fc_w + fc_b ----------------
__global__ __launch_bounds__(256) void k_pool(
    const float* __restrict__ fbar_all, const float* __restrict__ F,
    const float* __restrict__ bvc,
    const float* __restrict__ fc_w, const float* __restrict__ fc_b,
    float* __restrict__ out)
{
    const int g0 = blockIdx.x * 4;
    const int tid = threadIdx.x;
    __shared__ __align__(16) float sfb[32 * 256];
    __shared__ __align__(16) float sp[4 * 256];
    for (int idx = tid; idx < 8192; idx += 256)
        sfb[idx] = fbar_all[(size_t)g0 * 8 * 256 + idx];
    __syncthreads();

    float p[4];
    float bb = bvc[tid];
    #pragma unroll
    for (int j = 0; j < 4; ++j) p[j] = bb;
    for (int k = 0; k < 2048; ++k) {
        float f = F[(size_t)k * 256 + tid];
        #pragma unroll
        for (int j = 0; j < 4; ++j) p[j] += sfb[j * 2048 + k] * f;
    }
    #pragma unroll
    for (int j = 0; j < 4; ++j) sp[j * 256 + tid] = p[j];
    __syncthreads();

    float y[4];
    float fb = fc_b[tid];
    #pragma unroll
    for (int j = 0; j < 4; ++j) y[j] = fb;
    for (int e = 0; e < 256; ++e) {
        float w = fc_w[(size_t)e * 256 + tid];
        #pragma unroll
        for (int j = 0; j < 4; ++j) y[j] += sp[j * 256 + e] * w;
    }
    #pragma unroll
    for (int j = 0; j < 4; ++j)
        out[(size_t)(g0 + j) * 256 + tid] = y[j];
}

// ---------------- launch ----------------
extern "C" void kernel_launch(void* const* d_in, const int* in_sizes, int n_in,
                              void* d_out, int out_size, void* d_ws, size_t ws_size,
                              hipStream_t stream) {
    (void)in_sizes; (void)n_in; (void)out_size;

    const float* av1   = (const float*)d_in[0];
    const float* av2   = (const float*)d_in[1];
    const float* w1    = (const float*)d_in[2];
    const float* b1c   = (const float*)d_in[3];
    const float* g1    = (const float*)d_in[4];
    const float* be1   = (const float*)d_in[5];
    const float* m1    = (const float*)d_in[6];
    const float* v1    = (const float*)d_in[7];
    const float* w2    = (const float*)d_in[8];
    const float* b2c   = (const float*)d_in[9];
    const float* g2    = (const float*)d_in[10];
    const float* be2   = (const float*)d_in[11];
    const float* m2    = (const float*)d_in[12];
    const float* v2    = (const float*)d_in[13];
    const float* w3    = (const float*)d_in[14];
    const float* b3c   = (const float*)d_in[15];
    const float* g3    = (const float*)d_in[16];
    const float* be3   = (const float*)d_in[17];
    const float* m3    = (const float*)d_in[18];
    const float* v3    = (const float*)d_in[19];
    const float* Wq    = (const float*)d_in[20];
    const float* bq    = (const float*)d_in[21];
    const float* Wk    = (const float*)d_in[22];
    const float* bk    = (const float*)d_in[23];
    const float* Wv    = (const float*)d_in[24];
    const float* bv    = (const float*)d_in[25];
    const float* fca_w = (const float*)d_in[26];
    const float* fca_b = (const float*)d_in[27];
    const float* fc_w  = (const float*)d_in[28];
    const float* fc_b  = (const float*)d_in[29];
    (void)bk;

    float* ws = (float*)d_ws;
    float* feat = ws;                         //  5,767,168 f
    float* Mm   = feat + 5767168;             //    524,288 f
    float* WkT  = Mm + 524288;                //    524,288 f
    float* kb   = WkT + 524288;               //      2,048 f
    float* bvc  = kb + 2048;                  //        256 f
    float* F    = bvc + 256;                  //    524,288 f
    float* fbar = F + 524288;                 //  2,097,152 f
    ushort* w2f = (ushort*)(fbar + 2097152);  //    212,992 u16
    ushort* w3f = w2f + 212992;               //    819,200 u16
    ushort* mfr = w3f + 819200;               //    524,288 u16
    ushort* region = mfr + 524288;            // a2g chunk

    size_t base_bytes = (size_t)((char*)region - (char*)d_ws);
    size_t budget = (ws_size > base_bytes + 4096) ? (ws_size - base_bytes - 4096) : 0;
    int ncA = 16;
    const int cand[5] = {1, 2, 4, 8, 16};
    for (int i = 0; i < 5; ++i) { if ((size_t)144179200 / cand[i] <= budget) { ncA = cand[i]; break; } }
    const int seqsA = NSEQ / ncA;

    // setup
    k_prep_w2<<<832, 256, 0, stream>>>(w2, w2f);
    k_prep_w3<<<3200, 256, 0, stream>>>(w3, w3f);
    k_transpose<<<2048, 256, 0, stream>>>(Wk, WkT, 8, 256, 256);
    k_prep_attn_m<<<128, 256, 0, stream>>>(Wq, WkT, Mm);
    k_prep_mfrag<<<2048, 256, 0, stream>>>(Mm, mfr);
    k_prep_kb<<<8, 256, 0, stream>>>(Wk, bq, kb);
    k_prep_F<<<128, 256, 0, stream>>>(Wv, fca_w, F);
    k_prep_bvc<<<1, 256, 0, stream>>>(bv, fca_w, fca_b, bvc);

    // conv pipeline (a2g chunked through region)
    ushort* a2g = region;
    for (int c = 0; c < ncA; ++c) {
        int seqoff = c * seqsA;
        k_conv<<<seqsA / 4, 256, 0, stream>>>(av1, av2,
            w1, b1c, g1, be1, m1, v1,
            w2f, b2c, g2, be2, m2, v2,
            a2g, seqoff);
        k_conv3<<<seqsA / 32, 256, 0, stream>>>(a2g, w3f,
            b3c, g3, be3, m3, v3, feat, seqoff);
    }

    // fused attention + head
    k_attn_f<<<1024, 256, 0, stream>>>(feat, mfr, kb, fbar);
    k_pool<<<256, 256, 0, stream>>>(fbar, F, bvc, fc_w, fc_b, (float*)d_out);
}

// Round 6
// 666.324 us; speedup vs baseline: 8.1863x; 1.0557x over previous
//
#include <hip/hip_runtime.h>
#include <hip/hip_bf16.h>
#include <math.h>

// ---------------- problem constants ----------------
#define NSEQ 22528
#define HALFSEQ 11264

typedef __attribute__((ext_vector_type(8))) short short8;
typedef __attribute__((ext_vector_type(4))) float f32x4;
typedef __attribute__((ext_vector_type(4))) ushort ushort4v;

__device__ __forceinline__ ushort f2bf(float x) {
    __hip_bfloat16 h = __float2bfloat16(x);
    return *reinterpret_cast<ushort*>(&h);
}
__device__ __forceinline__ float bf2f(ushort u) {
    unsigned v = ((unsigned)u) << 16;
    return *reinterpret_cast<float*>(&v);
}

// ---------------- setup: transpose (for WkT) ----------------
__global__ void k_transpose(const float* __restrict__ in, float* __restrict__ out,
                            int Bn, int R, int C) {
    int idx = blockIdx.x * 256 + threadIdx.x;
    int total = Bn * R * C;
    if (idx >= total) return;
    int b = idx / (R * C);
    int rem = idx - b * R * C;
    int c = rem / R;
    int r = rem - c * R;
    out[idx] = in[(b * R + r) * C + c];
}

// ---------------- setup: bf16 weight repacks in MFMA fragment order ----------------
__global__ void k_prep_w2(const float* __restrict__ w2, ushort* __restrict__ w2f) {
    int idx = blockIdx.x * 256 + threadIdx.x;
    if (idx >= 212992) return;
    int j = idx & 7;
    int lane = (idx >> 3) & 63;
    int mt = (idx >> 9) & 7;
    int kt = idx >> 12;
    int oc = mt * 16 + (lane & 15);
    int k = kt * 32 + ((lane >> 4) << 3) + j;
    int t = k >> 6;
    int ic = k & 63;
    w2f[idx] = f2bf(w2[(oc * 64 + ic) * 26 + t]);
}
// conv3 A-tiles with k-order = pos*128 + ic (matches fragment-packed a2):
__global__ void k_prep_w3(const float* __restrict__ w3, ushort* __restrict__ w3f) {
    int idx = blockIdx.x * 256 + threadIdx.x;
    if (idx >= 819200) return;
    int j = idx & 7;
    int lane = (idx >> 3) & 63;
    int mt = (idx >> 9) & 15;
    int kt = idx >> 13;
    int oc = mt * 16 + (lane & 15);
    int k = kt * 32 + ((lane >> 4) << 3) + j;
    int ic = k & 127;
    int pos = k >> 7;
    w3f[idx] = f2bf(w3[oc * 3200 + ic * 25 + pos]);
}

// ---------------- setup: M = Wq Wk^T (16-row tiles) ----------------
__global__ __launch_bounds__(256) void k_prep_attn_m(
    const float* __restrict__ Wq, const float* __restrict__ WkT,
    float* __restrict__ M)
{
    const int h = blockIdx.x >> 4;
    const int e0 = (blockIdx.x & 15) * 16;
    const int tid = threadIdx.x;
    __shared__ float sq[16][256];
    for (int idx = tid; idx < 4096; idx += 256) {
        int r = idx >> 8;
        int c = idx & 255;
        sq[r][c] = Wq[(size_t)(h * 256 + e0 + r) * 256 + c];
    }
    __syncthreads();
    float acc[16];
    #pragma unroll
    for (int r = 0; r < 16; ++r) acc[r] = 0.f;
    const float* wkt = WkT + (size_t)h * 65536 + tid;
    for (int o = 0; o < 256; ++o) {
        float wk = wkt[o * 256];
        #pragma unroll
        for (int r = 0; r < 16; ++r) acc[r] += sq[r][o] * wk;
    }
    #pragma unroll
    for (int r = 0; r < 16; ++r)
        M[(size_t)(h * 256 + e0 + r) * 256 + tid] = acc[r];
}

// ---------------- setup: Mfrag bf16 fragment-packed (8 heads) ----------------
__global__ void k_prep_mfrag(const float* __restrict__ M, ushort* __restrict__ Mfrag) {
    int idx = blockIdx.x * 256 + threadIdx.x;   // 524288 total
    int j = idx & 7;
    int lane = (idx >> 3) & 63;
    int mt = (idx >> 9) & 15;
    int kt = (idx >> 13) & 7;
    int h = idx >> 16;
    int e = kt * 32 + ((lane >> 4) << 3) + j;
    int o = mt * 16 + (lane & 15);
    Mfrag[idx] = f2bf(M[(size_t)(h * 256 + e) * 256 + o]);
}

// ---------------- setup: kb[h][e] = Wk[h][e] . bq[h] ----------------
__global__ __launch_bounds__(256) void k_prep_kb(
    const float* __restrict__ Wk, const float* __restrict__ bq,
    float* __restrict__ kb)
{
    const int h = blockIdx.x;
    const int tid = threadIdx.x;
    __shared__ float sbq[256];
    sbq[tid] = bq[h * 256 + tid];
    __syncthreads();
    const float* wk = Wk + (size_t)(h * 256 + tid) * 256;
    float a = 0.f;
    for (int o = 0; o < 256; ++o) a += wk[o] * sbq[o];
    kb[h * 256 + tid] = a;
}

// ---------------- setup: F[h] = Wv[h] @ fca_w block ----------------
__global__ __launch_bounds__(256) void k_prep_F(
    const float* __restrict__ Wv, const float* __restrict__ fca_w,
    float* __restrict__ F)
{
    const int h = blockIdx.x >> 4;
    const int e0 = (blockIdx.x & 15) * 16;
    const int tid = threadIdx.x;
    __shared__ float sq[16][256];
    for (int idx = tid; idx < 4096; idx += 256) {
        int r = idx >> 8;
        int c = idx & 255;
        sq[r][c] = Wv[(size_t)h * 65536 + (e0 + r) * 256 + c];
    }
    __syncthreads();
    float acc[16];
    #pragma unroll
    for (int r = 0; r < 16; ++r) acc[r] = 0.f;
    for (int o = 0; o < 256; ++o) {
        float w = fca_w[(size_t)(h * 256 + o) * 256 + tid];
        #pragma unroll
        for (int r = 0; r < 16; ++r) acc[r] += sq[r][o] * w;
    }
    #pragma unroll
    for (int r = 0; r < 16; ++r)
        F[(size_t)(h * 256 + e0 + r) * 256 + tid] = acc[r];
}

// ---------------- setup: bvc[d] = bv . fca_w + fca_b ----------------
__global__ __launch_bounds__(256) void k_prep_bvc(
    const float* __restrict__ bv, const float* __restrict__ fca_w,
    const float* __restrict__ fca_b, float* __restrict__ bvc)
{
    const int tid = threadIdx.x;
    __shared__ float sbv[2048];
    for (int i = tid; i < 2048; i += 256) sbv[i] = bv[i];
    __syncthreads();
    float acc = fca_b[tid];
    for (int k = 0; k < 2048; ++k) acc += sbv[k] * fca_w[(size_t)k * 256 + tid];
    bvc[tid] = acc;
}

// ---------------- conv1 (MFMA) + conv2 (MFMA), J=4 seqs/block ----------------
// a2 output: conv3-fragment order: a2f[(sb*100 + kt)*512 + flane*8 + j],
// sb=seq/16, flane=(seq&15)+16*((k>>3)&3), k=p*128+oc (kt=k>>5, j=k&7).
__global__ __launch_bounds__(256, 4) void k_conv(
    const float* __restrict__ av1, const float* __restrict__ av2,
    const float* __restrict__ w1,
    const float* __restrict__ b1c, const float* __restrict__ g1,
    const float* __restrict__ be1, const float* __restrict__ m1, const float* __restrict__ v1,
    const ushort* __restrict__ w2f,
    const float* __restrict__ b2c, const float* __restrict__ g2,
    const float* __restrict__ be2, const float* __restrict__ m2, const float* __restrict__ v2,
    ushort* __restrict__ a2f, int seqoff)
{
    __shared__ ushort s_a1[4 * 3200];     // per seq [p 50][ic 64] bf16, swizzled 16B slots
    __shared__ ushort s_w1f[2048];        // conv1 A fragments
    __shared__ ushort s_xb[4][80];
    __shared__ float s_sc1[64], s_sh1[64], s_sc2[128], s_sh2[128];

    const int tid = threadIdx.x;
    const int lane = tid & 63;
    const int wv = tid >> 6;
    const int l15 = lane & 15;
    const int grp = lane >> 4;
    const int lseq0 = blockIdx.x * 4;
    const int gseq0 = seqoff + lseq0;

    // ---- stage x (bf16), w1 fragments, BN params ----
    for (int s = 0; s < 4; ++s) {
        int seq = gseq0 + s;
        const float* src;
        if (seq < HALFSEQ) { int b = seq / 22; int n = seq - b * 22; src = av1 + b * 600 + n * 25; }
        else { int q = seq - HALFSEQ; int b = q / 22; int n = q - b * 22; src = av2 + b * 600 + n * 25; }
        if (tid < 80) s_xb[s][tid] = f2bf((tid < 75) ? src[tid] : 0.f);
    }
    for (int idx = tid; idx < 2048; idx += 256) {
        int j = idx & 7;
        int ln = (idx >> 3) & 63;
        int mt = idx >> 9;
        int oc = mt * 16 + (ln & 15);
        int k = ((ln >> 4) << 3) + j;
        s_w1f[idx] = (k < 26) ? f2bf(w1[oc * 26 + k]) : (ushort)0;
    }
    if (tid < 64) { float A = g1[tid] * rsqrtf(v1[tid] + 1e-5f); s_sc1[tid] = A; s_sh1[tid] = (b1c[tid] - m1[tid]) * A + be1[tid]; }
    if (tid < 128) { float A = g2[tid] * rsqrtf(v2[tid] + 1e-5f); s_sc2[tid] = A; s_sh2[tid] = (b2c[tid] - m2[tid]) * A + be2[tid]; }
    __syncthreads();

    // ---- conv1 MFMA: M=64, N=200 (13 nt), K=32 ----
    {
        short8 a1f[4];
        #pragma unroll
        for (int mt = 0; mt < 4; ++mt)
            a1f[mt] = *(const short8*)(s_w1f + mt * 512 + lane * 8);

        for (int nt = wv; nt < 13; nt += 4) {
            int n = nt * 16 + l15;
            int s = (n >= 50) + (n >= 100) + (n >= 150);
            int p = n - s * 50;
            if (p > 49) p = 49;
            short8 bf;
            #pragma unroll
            for (int j = 0; j < 8; ++j) {
                int t = grp * 8 + j;
                bf[j] = (t < 26) ? (short)s_xb[s][p + t] : (short)0;
            }
            f32x4 acc1[4];
            #pragma unroll
            for (int mt = 0; mt < 4; ++mt) {
                acc1[mt] = (f32x4){0.f, 0.f, 0.f, 0.f};
                acc1[mt] = __builtin_amdgcn_mfma_f32_16x16x32_bf16(a1f[mt], bf, acc1[mt], 0, 0, 0);
            }
            if (n < 200) {
                #pragma unroll
                for (int mt = 0; mt < 4; ++mt) {
                    #pragma unroll
                    for (int r = 0; r < 4; ++r) {
                        int oc = mt * 16 + grp * 4 + r;
                        float y = acc1[mt][r] * s_sc1[oc] + s_sh1[oc];
                        y = y / (1.f + __expf(-y));
                        int boff = s * 6400 + p * 128 + ((oc * 2) ^ ((p & 7) << 4));
                        *(ushort*)((char*)s_a1 + boff) = f2bf(y);
                    }
                }
            }
        }
    }
    __syncthreads();

    // ---- conv2 MFMA: C[oc 128][n = s*25+p, 100 of 112] over K=1664 ----
    {
        const int mset = wv >> 1;
        const int nset = wv & 1;
        const int NT = nset ? 3 : 4;

        int nbase[4], nrow[4];
        #pragma unroll
        for (int ni = 0; ni < 4; ++ni) {
            int n = (nset * 4 + ni) * 16 + l15;
            int s = n / 25; if (s > 3) s = 3;
            int p = n - s * 25; if (p > 24) p = 24;
            nbase[ni] = s * 6400;
            nrow[ni] = p;
        }

        f32x4 acc[4][4];
        #pragma unroll
        for (int mi = 0; mi < 4; ++mi)
            #pragma unroll
            for (int ni = 0; ni < 4; ++ni)
                acc[mi][ni] = (f32x4){0.f, 0.f, 0.f, 0.f};

        const ushort* wfp = w2f + (size_t)(mset * 4) * 512 + lane * 8;
        short8 afn[4];
        #pragma unroll
        for (int mi = 0; mi < 4; ++mi) afn[mi] = *(const short8*)(wfp + mi * 512);

        for (int kt = 0; kt < 52; ++kt) {
            const int t = kt >> 1;
            const int ic0b = ((kt & 1) * 32 + grp * 8) * 2;
            short8 af[4];
            #pragma unroll
            for (int mi = 0; mi < 4; ++mi) af[mi] = afn[mi];
            if (kt < 51) {
                #pragma unroll
                for (int mi = 0; mi < 4; ++mi)
                    afn[mi] = *(const short8*)(wfp + (kt + 1) * 4096 + mi * 512);
            }
            #pragma unroll
            for (int ni = 0; ni < 4; ++ni) {
                if (ni >= NT) break;
                int row = nrow[ni] + t;
                int boff = nbase[ni] + row * 128 + (ic0b ^ ((row & 7) << 4));
                short8 bf = *(const short8*)((const char*)s_a1 + boff);
                #pragma unroll
                for (int mi = 0; mi < 4; ++mi)
                    acc[mi][ni] = __builtin_amdgcn_mfma_f32_16x16x32_bf16(af[mi], bf, acc[mi][ni], 0, 0, 0);
            }
        }

        // epilogue: BN2 + SiLU -> a2f (fragment order, ushort4 stores)
        #pragma unroll
        for (int mi = 0; mi < 4; ++mi) {
            const int ocb = mset * 64 + mi * 16 + grp * 4;
            const int grp_dst = (ocb & 31) >> 3;
            const int jb = ocb & 7;
            const int kthi = ocb >> 5;
            #pragma unroll
            for (int ni = 0; ni < 4; ++ni) {
                if (ni >= NT) break;
                int n = (nset * 4 + ni) * 16 + l15;
                if (n < 100) {
                    int s = n / 25;
                    int p = n - s * 25;
                    int seq = lseq0 + s;
                    int kt3 = p * 4 + kthi;
                    ushort4v u;
                    #pragma unroll
                    for (int r = 0; r < 4; ++r) {
                        float y = acc[mi][ni][r] * s_sc2[ocb + r] + s_sh2[ocb + r];
                        y = y / (1.f + __expf(-y));
                        u[r] = f2bf(y);
                    }
                    *(ushort4v*)(a2f + (((size_t)(seq >> 4) * 100 + kt3) << 9)
                                 + ((seq & 15) + 16 * grp_dst) * 8 + jb) = u;
                }
            }
        }
    }
}

// ---------------- conv3 MFMA GEMM: M=256, N=32 seqs, K=3200; all loads coalesced ----------------
__global__ __launch_bounds__(256) void k_conv3(
    const ushort* __restrict__ a2f, const ushort* __restrict__ w3f,
    const float* __restrict__ b3c, const float* __restrict__ g3,
    const float* __restrict__ be3, const float* __restrict__ m3, const float* __restrict__ v3,
    float* __restrict__ feat, int seqoff)
{
    const int tid = threadIdx.x;
    const int lane = tid & 63;
    const int wv = tid >> 6;
    const int l15 = lane & 15;
    const int grp = lane >> 4;
    const int lseq0 = blockIdx.x * 32;

    f32x4 acc3[4][2];
    #pragma unroll
    for (int mi = 0; mi < 4; ++mi)
        #pragma unroll
        for (int nt = 0; nt < 2; ++nt)
            acc3[mi][nt] = (f32x4){0.f, 0.f, 0.f, 0.f};

    const ushort* bp = a2f + ((size_t)(lseq0 >> 4) * 100) * 512 + lane * 8;
    const ushort* ap = w3f + (size_t)(wv * 4) * 512 + lane * 8;

    for (int kt = 0; kt < 100; ++kt) {
        short8 bf0 = *(const short8*)(bp + (size_t)kt * 512);
        short8 bf1 = *(const short8*)(bp + (size_t)(100 + kt) * 512);
        #pragma unroll
        for (int mi = 0; mi < 4; ++mi) {
            short8 af = *(const short8*)(ap + (size_t)kt * 8192 + mi * 512);
            acc3[mi][0] = __builtin_amdgcn_mfma_f32_16x16x32_bf16(af, bf0, acc3[mi][0], 0, 0, 0);
            acc3[mi][1] = __builtin_amdgcn_mfma_f32_16x16x32_bf16(af, bf1, acc3[mi][1], 0, 0, 0);
        }
    }

    #pragma unroll
    for (int nt = 0; nt < 2; ++nt) {
        int gseq = seqoff + lseq0 + nt * 16 + l15;
        #pragma unroll
        for (int mi = 0; mi < 4; ++mi) {
            int oc = wv * 64 + mi * 16 + grp * 4;
            float4 o4;
            #pragma unroll
            for (int r = 0; r < 4; ++r) {
                float A = g3[oc + r] * rsqrtf(v3[oc + r] + 1e-5f);
                float y = acc3[mi][nt][r] * A + (b3c[oc + r] - m3[oc + r]) * A + be3[oc + r];
                ((float*)&o4)[r] = y / (1.f + __expf(-y));
            }
            *(float4*)(feat + (size_t)gseq * 256 + oc) = o4;
        }
    }
}

// ---------------- fused attention: per g, all 8 heads, MFMA ----------------
__global__ __launch_bounds__(256, 2) void k_attn_f(
    const float* __restrict__ feat, const ushort* __restrict__ Mfrag,
    const float* __restrict__ kb, float* __restrict__ fbar_all)
{
    const int g = blockIdx.x;
    const int tid = threadIdx.x;
    const int lane = tid & 63;
    const int wv = tid >> 6;
    const int l15 = lane & 15;
    const int grp = lane >> 4;

    __shared__ __align__(16) float sfL[22 * 260];
    __shared__ __align__(16) ushort sfb[32 * 256];
    __shared__ __align__(16) ushort sG[32 * 256];
    __shared__ float sS[22 * 24];
    __shared__ float sbet[8][24];
    __shared__ float sab[24];

    const float* fsrc = feat + (size_t)g * 5632;
    for (int idx = tid; idx < 8192; idx += 256) {
        int s = idx >> 8;
        int e = idx & 255;
        float f = 0.f;
        if (s < 22) { f = fsrc[s * 256 + e]; sfL[s * 260 + e] = f; }
        int byte = s * 512 + ((e * 2) ^ ((s & 7) << 4));
        *(ushort*)((char*)sfb + byte) = f2bf(f);
    }
    __syncthreads();

    if (tid < 176) {
        int t = tid >> 3;
        int h = tid & 7;
        const float* kr = kb + h * 256;
        const float* fr = sfL + t * 260;
        float a = 0.f;
        for (int e = 0; e < 256; ++e) a += fr[e] * kr[e];
        sbet[h][t] = a;
    }
    __syncthreads();

    for (int h = 0; h < 8; ++h) {
        {
            f32x4 accg[2][4];
            #pragma unroll
            for (int mt = 0; mt < 2; ++mt)
                #pragma unroll
                for (int fi = 0; fi < 4; ++fi)
                    accg[mt][fi] = (f32x4){0.f, 0.f, 0.f, 0.f};

            const ushort* mfb = Mfrag + (size_t)h * 65536;
            for (int kt = 0; kt < 8; ++kt) {
                int e0b = (kt * 32 + grp * 8) * 2;
                int rA0 = l15, rA1 = 16 + l15;
                short8 af0 = *(const short8*)((const char*)sfb + rA0 * 512 + (e0b ^ ((rA0 & 7) << 4)));
                short8 af1 = *(const short8*)((const char*)sfb + rA1 * 512 + (e0b ^ ((rA1 & 7) << 4)));
                #pragma unroll
                for (int fi = 0; fi < 4; ++fi) {
                    int ft = wv * 4 + fi;
                    short8 bfm = *(const short8*)(mfb + (size_t)((kt * 16 + ft) << 9) + lane * 8);
                    accg[0][fi] = __builtin_amdgcn_mfma_f32_16x16x32_bf16(af0, bfm, accg[0][fi], 0, 0, 0);
                    accg[1][fi] = __builtin_amdgcn_mfma_f32_16x16x32_bf16(af1, bfm, accg[1][fi], 0, 0, 0);
                }
            }
            #pragma unroll
            for (int mt = 0; mt < 2; ++mt) {
                #pragma unroll
                for (int fi = 0; fi < 4; ++fi) {
                    int f = (wv * 4 + fi) * 16 + l15;
                    #pragma unroll
                    for (int r = 0; r < 4; ++r) {
                        int s = mt * 16 + grp * 4 + r;
                        if (s < 22) {
                            int byte = s * 512 + ((f * 2) ^ ((s & 7) << 4));
                            *(ushort*)((char*)sG + byte) = f2bf(accg[mt][fi][r]);
                        }
                    }
                }
            }
        }
        __syncthreads();

        {
            int mt2 = wv >> 1;
            int nt2 = wv & 1;
            f32x4 sacc = (f32x4){0.f, 0.f, 0.f, 0.f};
            int sA = mt2 * 16 + l15;
            int tB = nt2 * 16 + l15;
            for (int kt = 0; kt < 8; ++kt) {
                int f0b = (kt * 32 + grp * 8) * 2;
                short8 ga = *(const short8*)((const char*)sG + sA * 512 + (f0b ^ ((sA & 7) << 4)));
                short8 fb = *(const short8*)((const char*)sfb + tB * 512 + (f0b ^ ((tB & 7) << 4)));
                sacc = __builtin_amdgcn_mfma_f32_16x16x32_bf16(ga, fb, sacc, 0, 0, 0);
            }
            #pragma unroll
            for (int r = 0; r < 4; ++r) {
                int s = mt2 * 16 + grp * 4 + r;
                int t = nt2 * 16 + l15;
                if (s < 22 && t < 22) sS[s * 24 + t] = sacc[r] + sbet[h][t];
            }
        }
        __syncthreads();

        if (tid < 22) {
            int s = tid;
            float mx = -1e30f;
            #pragma unroll
            for (int t = 0; t < 22; ++t) mx = fmaxf(mx, sS[s * 24 + t]);
            float ex[22];
            float sum = 0.f;
            #pragma unroll
            for (int t = 0; t < 22; ++t) { float e2 = __expf(sS[s * 24 + t] - mx); ex[t] = e2; sum += e2; }
            float inv = 1.f / sum;
            #pragma unroll
            for (int t = 0; t < 22; ++t) sS[s * 24 + t] = ex[t] * inv;
        }
        __syncthreads();
        if (tid < 22) {
            int t = tid;
            float a = 0.f;
            #pragma unroll
            for (int s = 0; s < 22; ++s) a += sS[s * 24 + t];
            sab[t] = a * (1.f / 22.f);
        }
        __syncthreads();

        {
            float a = 0.f;
            #pragma unroll
            for (int t = 0; t < 22; ++t) a += sab[t] * sfL[t * 260 + tid];
            fbar_all[((size_t)g * 8 + h) * 256 + tid] = a;
        }
    }
}

// ---------------- k_pool ----------------
__global__ __launch_bounds__(256) void k_pool(
    const float* __restrict__ fbar_all, const float* __restrict__ F,
    const float* __restrict__ bvc,
    const float* __restrict__ fc_w, const float* __restrict__ fc_b,
    float* __restrict__ out)
{
    const int g0 = blockIdx.x * 4;
    const int tid = threadIdx.x;
    __shared__ __align__(16) float sfb[32 * 256];
    __shared__ __align__(16) float sp[4 * 256];
    for (int idx = tid; idx < 8192; idx += 256)
        sfb[idx] = fbar_all[(size_t)g0 * 8 * 256 + idx];
    __syncthreads();

    float p[4];
    float bb = bvc[tid];
    #pragma unroll
    for (int j = 0; j < 4; ++j) p[j] = bb;
    for (int k = 0; k < 2048; ++k) {
        float f = F[(size_t)k * 256 + tid];
        #pragma unroll
        for (int j = 0; j < 4; ++j) p[j] += sfb[j * 2048 + k] * f;
    }
    #pragma unroll
    for (int j = 0; j < 4; ++j) sp[j * 256 + tid] = p[j];
    __syncthreads();

    float y[4];
    float fb = fc_b[tid];
    #pragma unroll
    for (int j = 0; j < 4; ++j) y[j] = fb;
    for (int e = 0; e < 256; ++e) {
        float w = fc_w[(size_t)e * 256 + tid];
        #pragma unroll
        for (int j = 0; j < 4; ++j) y[j] += sp[j * 256 + e] * w;
    }
    #pragma unroll
    for (int j = 0; j < 4; ++j)
        out[(size_t)(g0 + j) * 256 + tid] = y[j];
}

// ---------------- launch ----------------
extern "C" void kernel_launch(void* const* d_in, const int* in_sizes, int n_in,
                              void* d_out, int out_size, void* d_ws, size_t ws_size,
                              hipStream_t stream) {
    (void)in_sizes; (void)n_in; (void)out_size;

    const float* av1   = (const float*)d_in[0];
    const float* av2   = (const float*)d_in[1];
    const float* w1    = (const float*)d_in[2];
    const float* b1c   = (const float*)d_in[3];
    const float* g1    = (const float*)d_in[4];
    const float* be1   = (const float*)d_in[5];
    const float* m1    = (const float*)d_in[6];
    const float* v1    = (const float*)d_in[7];
    const float* w2    = (const float*)d_in[8];
    const float* b2c   = (const float*)d_in[9];
    const float* g2    = (const float*)d_in[10];
    const float* be2   = (const float*)d_in[11];
    const float* m2    = (const float*)d_in[12];
    const float* v2    = (const float*)d_in[13];
    const float* w3    = (const float*)d_in[14];
    const float* b3c   = (const float*)d_in[15];
    const float* g3    = (const float*)d_in[16];
    const float* be3   = (const float*)d_in[17];
    const float* m3    = (const float*)d_in[18];
    const float* v3    = (const float*)d_in[19];
    const float* Wq    = (const float*)d_in[20];
    const float* bq    = (const float*)d_in[21];
    const float* Wk    = (const float*)d_in[22];
    const float* bk    = (const float*)d_in[23];
    const float* Wv    = (const float*)d_in[24];
    const float* bv    = (const float*)d_in[25];
    const float* fca_w = (const float*)d_in[26];
    const float* fca_b = (const float*)d_in[27];
    const float* fc_w  = (const float*)d_in[28];
    const float* fc_b  = (const float*)d_in[29];
    (void)bk;

    float* ws = (float*)d_ws;
    float* feat = ws;                         //  5,767,168 f
    float* Mm   = feat + 5767168;             //    524,288 f
    float* WkT  = Mm + 524288;                //    524,288 f
    float* kb   = WkT + 524288;               //      2,048 f
    float* bvc  = kb + 2048;                  //        256 f
    float* F    = bvc + 256;                  //    524,288 f
    float* fbar = F + 524288;                 //  2,097,152 f
    ushort* w2f = (ushort*)(fbar + 2097152);  //    212,992 u16
    ushort* w3f = w2f + 212992;               //    819,200 u16
    ushort* mfr = w3f + 819200;               //    524,288 u16
    ushort* region = mfr + 524288;            // a2f chunk

    size_t base_bytes = (size_t)((char*)region - (char*)d_ws);
    size_t budget = (ws_size > base_bytes + 4096) ? (ws_size - base_bytes - 4096) : 0;
    int ncA = 16;
    const int cand[5] = {1, 2, 4, 8, 16};
    for (int i = 0; i < 5; ++i) { if ((size_t)144179200 / cand[i] <= budget) { ncA = cand[i]; break; } }
    const int seqsA = NSEQ / ncA;

    // setup
    k_prep_w2<<<832, 256, 0, stream>>>(w2, w2f);
    k_prep_w3<<<3200, 256, 0, stream>>>(w3, w3f);
    k_transpose<<<2048, 256, 0, stream>>>(Wk, WkT, 8, 256, 256);
    k_prep_attn_m<<<128, 256, 0, stream>>>(Wq, WkT, Mm);
    k_prep_mfrag<<<2048, 256, 0, stream>>>(Mm, mfr);
    k_prep_kb<<<8, 256, 0, stream>>>(Wk, bq, kb);
    k_prep_F<<<128, 256, 0, stream>>>(Wv, fca_w, F);
    k_prep_bvc<<<1, 256, 0, stream>>>(bv, fca_w, fca_b, bvc);

    // conv pipeline (a2f chunked through region)
    ushort* a2f = region;
    for (int c = 0; c < ncA; ++c) {
        int seqoff = c * seqsA;
        k_conv<<<seqsA / 4, 256, 0, stream>>>(av1, av2,
            w1, b1c, g1, be1, m1, v1,
            w2f, b2c, g2, be2, m2, v2,
            a2f, seqoff);
        k_conv3<<<seqsA / 32, 256, 0, stream>>>(a2f, w3f,
            b3c, g3, be3, m3, v3, feat, seqoff);
    }

    // fused attention + head
    k_attn_f<<<1024, 256, 0, stream>>>(feat, mfr, kb, fbar);
    k_pool<<<256, 256, 0, stream>>>(fbar, F, bvc, fc_w, fc_b, (float*)d_out);
}

// Round 7
// 601.408 us; speedup vs baseline: 9.0699x; 1.1079x over previous
//
#include <hip/hip_runtime.h>
#include <hip/hip_bf16.h>
#include <math.h>

// ---------------- problem constants ----------------
#define NSEQ 22528
#define HALFSEQ 11264

typedef __attribute__((ext_vector_type(8))) short short8;
typedef __attribute__((ext_vector_type(4))) float f32x4;
typedef __attribute__((ext_vector_type(4))) ushort ushort4v;

__device__ __forceinline__ ushort f2bf(float x) {
    __hip_bfloat16 h = __float2bfloat16(x);
    return *reinterpret_cast<ushort*>(&h);
}
__device__ __forceinline__ float bf2f(ushort u) {
    unsigned v = ((unsigned)u) << 16;
    return *reinterpret_cast<float*>(&v);
}

// ---------------- merged setup: w2f, w3f, WkT, kb, bvc, F ----------------
// grid 6217: [0,832) w2f | [832,4032) w3f | [4032,6080) WkT | [6080,6088) kb
//            [6088] bvc | [6089,6217) F
__global__ __launch_bounds__(256) void k_prep_misc(
    const float* __restrict__ w2, ushort* __restrict__ w2f,
    const float* __restrict__ w3, ushort* __restrict__ w3f,
    const float* __restrict__ Wk, float* __restrict__ WkT,
    const float* __restrict__ bq, float* __restrict__ kb,
    const float* __restrict__ bv, const float* __restrict__ fca_w,
    const float* __restrict__ fca_b, float* __restrict__ bvc,
    const float* __restrict__ Wv, float* __restrict__ F)
{
    __shared__ float smem[16 * 256];
    const int bid = blockIdx.x;
    const int tid = threadIdx.x;

    if (bid < 832) {
        // w2f fragment pack: tiles (kt 0..51, mt 0..7)
        int idx = bid * 256 + tid;
        if (idx < 212992) {
            int j = idx & 7;
            int lane = (idx >> 3) & 63;
            int mt = (idx >> 9) & 7;
            int kt = idx >> 12;
            int oc = mt * 16 + (lane & 15);
            int k = kt * 32 + ((lane >> 4) << 3) + j;
            int t = k >> 6;
            int ic = k & 63;
            w2f[idx] = f2bf(w2[(oc * 64 + ic) * 26 + t]);
        }
    } else if (bid < 4032) {
        // w3f fragment pack, k-order pos*128+ic
        int idx = (bid - 832) * 256 + tid;
        if (idx < 819200) {
            int j = idx & 7;
            int lane = (idx >> 3) & 63;
            int mt = (idx >> 9) & 15;
            int kt = idx >> 13;
            int oc = mt * 16 + (lane & 15);
            int k = kt * 32 + ((lane >> 4) << 3) + j;
            int ic = k & 127;
            int pos = k >> 7;
            w3f[idx] = f2bf(w3[oc * 3200 + ic * 25 + pos]);
        }
    } else if (bid < 6080) {
        // WkT[h][o][f] = Wk[h][f][o]
        int idx = (bid - 4032) * 256 + tid;
        int b = idx >> 16;
        int rem = idx & 65535;
        int c = rem >> 8;
        int r = rem & 255;
        WkT[idx] = Wk[(size_t)(b * 256 + r) * 256 + c];
    } else if (bid < 6088) {
        // kb[h][e] = Wk[h][e] . bq[h]
        int h = bid - 6080;
        smem[tid] = bq[h * 256 + tid];
        __syncthreads();
        const float* wk = Wk + (size_t)(h * 256 + tid) * 256;
        float a = 0.f;
        for (int o = 0; o < 256; ++o) a += wk[o] * smem[o];
        kb[h * 256 + tid] = a;
    } else if (bid < 6089) {
        // bvc = bv . fca_w + fca_b
        for (int i = tid; i < 2048; i += 256) smem[i] = bv[i];
        __syncthreads();
        float acc = fca_b[tid];
        for (int k = 0; k < 2048; ++k) acc += smem[k] * fca_w[(size_t)k * 256 + tid];
        bvc[tid] = acc;
    } else {
        // F[h] = Wv[h] @ fca_w block
        int lb = bid - 6089;
        int h = lb >> 4;
        int e0 = (lb & 15) * 16;
        for (int idx = tid; idx < 4096; idx += 256) {
            int r = idx >> 8;
            int c = idx & 255;
            smem[r * 256 + c] = Wv[(size_t)h * 65536 + (e0 + r) * 256 + c];
        }
        __syncthreads();
        float acc[16];
        #pragma unroll
        for (int r = 0; r < 16; ++r) acc[r] = 0.f;
        for (int o = 0; o < 256; ++o) {
            float w = fca_w[(size_t)(h * 256 + o) * 256 + tid];
            #pragma unroll
            for (int r = 0; r < 16; ++r) acc[r] += smem[r * 256 + o] * w;
        }
        #pragma unroll
        for (int r = 0; r < 16; ++r)
            F[(size_t)(h * 256 + e0 + r) * 256 + tid] = acc[r];
    }
}

// ---------------- setup: M = Wq Wk^T (16-row tiles) ----------------
__global__ __launch_bounds__(256) void k_prep_attn_m(
    const float* __restrict__ Wq, const float* __restrict__ WkT,
    float* __restrict__ M)
{
    const int h = blockIdx.x >> 4;
    const int e0 = (blockIdx.x & 15) * 16;
    const int tid = threadIdx.x;
    __shared__ float sq[16][256];
    for (int idx = tid; idx < 4096; idx += 256) {
        int r = idx >> 8;
        int c = idx & 255;
        sq[r][c] = Wq[(size_t)(h * 256 + e0 + r) * 256 + c];
    }
    __syncthreads();
    float acc[16];
    #pragma unroll
    for (int r = 0; r < 16; ++r) acc[r] = 0.f;
    const float* wkt = WkT + (size_t)h * 65536 + tid;
    for (int o = 0; o < 256; ++o) {
        float wk = wkt[o * 256];
        #pragma unroll
        for (int r = 0; r < 16; ++r) acc[r] += sq[r][o] * wk;
    }
    #pragma unroll
    for (int r = 0; r < 16; ++r)
        M[(size_t)(h * 256 + e0 + r) * 256 + tid] = acc[r];
}

// ---------------- setup: Mfrag bf16 fragment-packed ----------------
__global__ void k_prep_mfrag(const float* __restrict__ M, ushort* __restrict__ Mfrag) {
    int idx = blockIdx.x * 256 + threadIdx.x;   // 524288 total
    int j = idx & 7;
    int lane = (idx >> 3) & 63;
    int mt = (idx >> 9) & 15;
    int kt = (idx >> 13) & 7;
    int h = idx >> 16;
    int e = kt * 32 + ((lane >> 4) << 3) + j;
    int o = mt * 16 + (lane & 15);
    Mfrag[idx] = f2bf(M[(size_t)(h * 256 + e) * 256 + o]);
}

// ---------------- conv1 + conv2 MFMA, J=8 seqs/block, 512 threads ----------------
// a1 LDS layout per seq: [icb 8][p 50][8 ic] ushort (6400 B), conflict-free 16B rows.
// waves: mset = w&3 (32 oc), nset = w>>2 (n-half). N = 8*25 = 200 (of 224).
__global__ __launch_bounds__(512, 4) void k_conv(
    const float* __restrict__ av1, const float* __restrict__ av2,
    const float* __restrict__ w1,
    const float* __restrict__ b1c, const float* __restrict__ g1,
    const float* __restrict__ be1, const float* __restrict__ m1, const float* __restrict__ v1,
    const ushort* __restrict__ w2f,
    const float* __restrict__ b2c, const float* __restrict__ g2,
    const float* __restrict__ be2, const float* __restrict__ m2, const float* __restrict__ v2,
    ushort* __restrict__ a2f, int seqoff)
{
    __shared__ ushort s_a1[8 * 3200];     // 8 seq x 6400 B
    __shared__ ushort s_w1f[2048];
    __shared__ ushort s_xb[8][80];
    __shared__ float s_sc1[64], s_sh1[64], s_sc2[128], s_sh2[128];

    const int tid = threadIdx.x;
    const int lane = tid & 63;
    const int w = tid >> 6;           // wave 0..7
    const int l15 = lane & 15;
    const int grp = lane >> 4;
    const int lseq0 = blockIdx.x * 8;
    const int gseq0 = seqoff + lseq0;

    // ---- stage inputs (bf16), w1 fragments, BN params ----
    for (int idx = tid; idx < 640; idx += 512) {
        int s = idx / 80;
        int i = idx - s * 80;
        int seq = gseq0 + s;
        const float* src;
        if (seq < HALFSEQ) { int b = seq / 22; int n = seq - b * 22; src = av1 + b * 600 + n * 25; }
        else { int q = seq - HALFSEQ; int b = q / 22; int n = q - b * 22; src = av2 + b * 600 + n * 25; }
        s_xb[s][i] = f2bf((i < 75) ? src[i] : 0.f);
    }
    for (int idx = tid; idx < 2048; idx += 512) {
        int j = idx & 7;
        int ln = (idx >> 3) & 63;
        int mt = idx >> 9;
        int oc = mt * 16 + (ln & 15);
        int k = ((ln >> 4) << 3) + j;
        s_w1f[idx] = (k < 26) ? f2bf(w1[oc * 26 + k]) : (ushort)0;
    }
    if (tid < 64) { float A = g1[tid] * rsqrtf(v1[tid] + 1e-5f); s_sc1[tid] = A; s_sh1[tid] = (b1c[tid] - m1[tid]) * A + be1[tid]; }
    if (tid >= 128 && tid < 256) {
        int o = tid - 128;
        float A = g2[o] * rsqrtf(v2[o] + 1e-5f); s_sc2[o] = A; s_sh2[o] = (b2c[o] - m2[o]) * A + be2[o];
    }
    __syncthreads();

    // ---- conv1 MFMA: M=64 (4 mt), N=400 (25 nt), K=32 ----
    {
        short8 a1f[4];
        #pragma unroll
        for (int mt = 0; mt < 4; ++mt)
            a1f[mt] = *(const short8*)(s_w1f + mt * 512 + lane * 8);

        for (int nt = w; nt < 25; nt += 8) {
            int n = nt * 16 + l15;
            int s = n / 50;
            int p = n - s * 50;
            short8 bf;
            #pragma unroll
            for (int j = 0; j < 8; ++j) {
                int t = grp * 8 + j;
                bf[j] = (t < 26) ? (short)s_xb[s][p + t] : (short)0;
            }
            #pragma unroll
            for (int mt = 0; mt < 4; ++mt) {
                f32x4 acc1 = (f32x4){0.f, 0.f, 0.f, 0.f};
                acc1 = __builtin_amdgcn_mfma_f32_16x16x32_bf16(a1f[mt], bf, acc1, 0, 0, 0);
                // store 4 consecutive oc as one b64: layout [icb][p][ic&7]
                int oc0 = mt * 16 + grp * 4;
                int icb = oc0 >> 3;                 // 2*mt + (grp>>1)
                int boff = s * 6400 + icb * 800 + p * 16 + (oc0 & 7) * 2;
                ushort4v u;
                #pragma unroll
                for (int r = 0; r < 4; ++r) {
                    float y = acc1[r] * s_sc1[oc0 + r] + s_sh1[oc0 + r];
                    y = y / (1.f + __expf(-y));
                    u[r] = f2bf(y);
                }
                *(ushort4v*)((char*)s_a1 + boff) = u;
            }
        }
    }
    __syncthreads();

    // ---- conv2 MFMA: C[oc 128][n 224 (200 valid)] over K=1664 ----
    {
        const int mset = w & 3;
        const int nset = w >> 2;
        const int NT = nset ? 6 : 7;   // nset1 tile 13 fully invalid

        // per-lane LDS byte addr for B, linear in t; half1 = +3200 (icb +4)
        int vaddr[7];
        #pragma unroll
        for (int ni = 0; ni < 7; ++ni) {
            int nt = nset * 7 + ni;
            int n = nt * 16 + l15;
            int s = n / 25; if (s > 7) s = 7;
            int p = n - s * 25; if (p > 24) p = 24;
            vaddr[ni] = s * 6400 + grp * 800 + p * 16;
        }

        f32x4 acc[2][7];
        #pragma unroll
        for (int mi = 0; mi < 2; ++mi)
            #pragma unroll
            for (int ni = 0; ni < 7; ++ni)
                acc[mi][ni] = (f32x4){0.f, 0.f, 0.f, 0.f};

        const ushort* wpt = w2f + (size_t)(mset * 2) * 512 + lane * 8;
        short8 afA0 = *(const short8*)(wpt);
        short8 afA1 = *(const short8*)(wpt + 512);
        short8 afB0 = *(const short8*)(wpt + 4096);
        short8 afB1 = *(const short8*)(wpt + 4096 + 512);

        for (int t = 0; t < 26; ++t) {
            // half 0 (kt = 2t)
            #pragma unroll
            for (int ni = 0; ni < 7; ++ni) {
                if (ni >= NT) break;
                short8 bf = *(const short8*)((const char*)s_a1 + vaddr[ni]);
                acc[0][ni] = __builtin_amdgcn_mfma_f32_16x16x32_bf16(afA0, bf, acc[0][ni], 0, 0, 0);
                acc[1][ni] = __builtin_amdgcn_mfma_f32_16x16x32_bf16(afA1, bf, acc[1][ni], 0, 0, 0);
            }
            if (t < 25) {
                afA0 = *(const short8*)(wpt + 8192);
                afA1 = *(const short8*)(wpt + 8192 + 512);
            }
            // half 1 (kt = 2t+1): icb +4 -> +3200 B
            #pragma unroll
            for (int ni = 0; ni < 7; ++ni) {
                if (ni >= NT) break;
                short8 bf = *(const short8*)((const char*)s_a1 + vaddr[ni] + 3200);
                acc[0][ni] = __builtin_amdgcn_mfma_f32_16x16x32_bf16(afB0, bf, acc[0][ni], 0, 0, 0);
                acc[1][ni] = __builtin_amdgcn_mfma_f32_16x16x32_bf16(afB1, bf, acc[1][ni], 0, 0, 0);
            }
            if (t < 25) {
                afB0 = *(const short8*)(wpt + 12288);
                afB1 = *(const short8*)(wpt + 12288 + 512);
                wpt += 8192;
            }
            #pragma unroll
            for (int ni = 0; ni < 7; ++ni) vaddr[ni] += 16;
        }

        // epilogue: BN2 + SiLU -> a2f (conv3 fragment order, ushort4 stores)
        #pragma unroll
        for (int mi = 0; mi < 2; ++mi) {
            const int ocb = mset * 32 + mi * 16 + grp * 4;
            const int grp_dst = (ocb >> 3) & 3;
            const int jb = ocb & 7;
            const int kthi = ocb >> 5;
            #pragma unroll
            for (int ni = 0; ni < 7; ++ni) {
                if (ni >= NT) break;
                int n = (nset * 7 + ni) * 16 + l15;
                if (n < 200) {
                    int s = n / 25;
                    int p = n - s * 25;
                    int seq = lseq0 + s;
                    int kt3 = p * 4 + kthi;
                    ushort4v u;
                    #pragma unroll
                    for (int r = 0; r < 4; ++r) {
                        float y = acc[mi][ni][r] * s_sc2[ocb + r] + s_sh2[ocb + r];
                        y = y / (1.f + __expf(-y));
                        u[r] = f2bf(y);
                    }
                    *(ushort4v*)(a2f + (((size_t)(seq >> 4) * 100 + kt3) << 9)
                                 + ((seq & 15) + 16 * grp_dst) * 8 + jb) = u;
                }
            }
        }
    }
}

// ---------------- conv3 MFMA GEMM: M=256, N=64 seqs, K=3200 ----------------
__global__ __launch_bounds__(256) void k_conv3(
    const ushort* __restrict__ a2f, const ushort* __restrict__ w3f,
    const float* __restrict__ b3c, const float* __restrict__ g3,
    const float* __restrict__ be3, const float* __restrict__ m3, const float* __restrict__ v3,
    float* __restrict__ feat, int seqoff)
{
    const int tid = threadIdx.x;
    const int lane = tid & 63;
    const int wv = tid >> 6;
    const int l15 = lane & 15;
    const int grp = lane >> 4;
    const int lseq0 = blockIdx.x * 64;

    f32x4 acc3[4][4];
    #pragma unroll
    for (int mi = 0; mi < 4; ++mi)
        #pragma unroll
        for (int nt = 0; nt < 4; ++nt)
            acc3[mi][nt] = (f32x4){0.f, 0.f, 0.f, 0.f};

    const ushort* bp = a2f + ((size_t)(lseq0 >> 4) * 100) * 512 + lane * 8;
    const ushort* ap = w3f + (size_t)(wv * 4) * 512 + lane * 8;

    for (int kt = 0; kt < 100; ++kt) {
        short8 bf[4];
        #pragma unroll
        for (int nt = 0; nt < 4; ++nt)
            bf[nt] = *(const short8*)(bp + (size_t)(nt * 100 + kt) * 512);
        #pragma unroll
        for (int mi = 0; mi < 4; ++mi) {
            short8 af = *(const short8*)(ap + (size_t)kt * 8192 + mi * 512);
            #pragma unroll
            for (int nt = 0; nt < 4; ++nt)
                acc3[mi][nt] = __builtin_amdgcn_mfma_f32_16x16x32_bf16(af, bf[nt], acc3[mi][nt], 0, 0, 0);
        }
    }

    #pragma unroll
    for (int nt = 0; nt < 4; ++nt) {
        int gseq = seqoff + lseq0 + nt * 16 + l15;
        #pragma unroll
        for (int mi = 0; mi < 4; ++mi) {
            int oc = wv * 64 + mi * 16 + grp * 4;
            float4 o4;
            #pragma unroll
            for (int r = 0; r < 4; ++r) {
                float A = g3[oc + r] * rsqrtf(v3[oc + r] + 1e-5f);
                float y = acc3[mi][nt][r] * A + (b3c[oc + r] - m3[oc + r]) * A + be3[oc + r];
                ((float*)&o4)[r] = y / (1.f + __expf(-y));
            }
            *(float4*)(feat + (size_t)gseq * 256 + oc) = o4;
        }
    }
}

// ---------------- fused attention: per g, all 8 heads, MFMA ----------------
__global__ __launch_bounds__(256, 2) void k_attn_f(
    const float* __restrict__ feat, const ushort* __restrict__ Mfrag,
    const float* __restrict__ kb, float* __restrict__ fbar_all)
{
    const int g = blockIdx.x;
    const int tid = threadIdx.x;
    const int lane = tid & 63;
    const int wv = tid >> 6;
    const int l15 = lane & 15;
    const int grp = lane >> 4;

    __shared__ __align__(16) float sfL[22 * 260];
    __shared__ __align__(16) ushort sfb[32 * 256];
    __shared__ __align__(16) ushort sG[32 * 256];
    __shared__ float sS[22 * 24];
    __shared__ float sbet[8][24];
    __shared__ float sab[24];

    const float* fsrc = feat + (size_t)g * 5632;
    for (int idx = tid; idx < 8192; idx += 256) {
        int s = idx >> 8;
        int e = idx & 255;
        float f = 0.f;
        if (s < 22) { f = fsrc[s * 256 + e]; sfL[s * 260 + e] = f; }
        int byte = s * 512 + ((e * 2) ^ ((s & 7) << 4));
        *(ushort*)((char*)sfb + byte) = f2bf(f);
    }
    __syncthreads();

    if (tid < 176) {
        int t = tid >> 3;
        int h = tid & 7;
        const float* kr = kb + h * 256;
        const float* fr = sfL + t * 260;
        float a = 0.f;
        for (int e = 0; e < 256; ++e) a += fr[e] * kr[e];
        sbet[h][t] = a;
    }
    __syncthreads();

    for (int h = 0; h < 8; ++h) {
        {
            f32x4 accg[2][4];
            #pragma unroll
            for (int mt = 0; mt < 2; ++mt)
                #pragma unroll
                for (int fi = 0; fi < 4; ++fi)
                    accg[mt][fi] = (f32x4){0.f, 0.f, 0.f, 0.f};

            const ushort* mfb = Mfrag + (size_t)h * 65536;
            for (int kt = 0; kt < 8; ++kt) {
                int e0b = (kt * 32 + grp * 8) * 2;
                int rA0 = l15, rA1 = 16 + l15;
                short8 af0 = *(const short8*)((const char*)sfb + rA0 * 512 + (e0b ^ ((rA0 & 7) << 4)));
                short8 af1 = *(const short8*)((const char*)sfb + rA1 * 512 + (e0b ^ ((rA1 & 7) << 4)));
                #pragma unroll
                for (int fi = 0; fi < 4; ++fi) {
                    int ft = wv * 4 + fi;
                    short8 bfm = *(const short8*)(mfb + (size_t)((kt * 16 + ft) << 9) + lane * 8);
                    accg[0][fi] = __builtin_amdgcn_mfma_f32_16x16x32_bf16(af0, bfm, accg[0][fi], 0, 0, 0);
                    accg[1][fi] = __builtin_amdgcn_mfma_f32_16x16x32_bf16(af1, bfm, accg[1][fi], 0, 0, 0);
                }
            }
            #pragma unroll
            for (int mt = 0; mt < 2; ++mt) {
                #pragma unroll
                for (int fi = 0; fi < 4; ++fi) {
                    int f = (wv * 4 + fi) * 16 + l15;
                    #pragma unroll
                    for (int r = 0; r < 4; ++r) {
                        int s = mt * 16 + grp * 4 + r;
                        if (s < 22) {
                            int byte = s * 512 + ((f * 2) ^ ((s & 7) << 4));
                            *(ushort*)((char*)sG + byte) = f2bf(accg[mt][fi][r]);
                        }
                    }
                }
            }
        }
        __syncthreads();

        {
            int mt2 = wv >> 1;
            int nt2 = wv & 1;
            f32x4 sacc = (f32x4){0.f, 0.f, 0.f, 0.f};
            int sA = mt2 * 16 + l15;
            int tB = nt2 * 16 + l15;
            for (int kt = 0; kt < 8; ++kt) {
                int f0b = (kt * 32 + grp * 8) * 2;
                short8 ga = *(const short8*)((const char*)sG + sA * 512 + (f0b ^ ((sA & 7) << 4)));
                short8 fb = *(const short8*)((const char*)sfb + tB * 512 + (f0b ^ ((tB & 7) << 4)));
                sacc = __builtin_amdgcn_mfma_f32_16x16x32_bf16(ga, fb, sacc, 0, 0, 0);
            }
            #pragma unroll
            for (int r = 0; r < 4; ++r) {
                int s = mt2 * 16 + grp * 4 + r;
                int t = nt2 * 16 + l15;
                if (s < 22 && t < 22) sS[s * 24 + t] = sacc[r] + sbet[h][t];
            }
        }
        __syncthreads();

        if (tid < 22) {
            int s = tid;
            float mx = -1e30f;
            #pragma unroll
            for (int t = 0; t < 22; ++t) mx = fmaxf(mx, sS[s * 24 + t]);
            float ex[22];
            float sum = 0.f;
            #pragma unroll
            for (int t = 0; t < 22; ++t) { float e2 = __expf(sS[s * 24 + t] - mx); ex[t] = e2; sum += e2; }
            float inv = 1.f / sum;
            #pragma unroll
            for (int t = 0; t < 22; ++t) sS[s * 24 + t] = ex[t] * inv;
        }
        __syncthreads();
        if (tid < 22) {
            int t = tid;
            float a = 0.f;
            #pragma unroll
            for (int s = 0; s < 22; ++s) a += sS[s * 24 + t];
            sab[t] = a * (1.f / 22.f);
        }
        __syncthreads();

        {
            float a = 0.f;
            #pragma unroll
            for (int t = 0; t < 22; ++t) a += sab[t] * sfL[t * 260 + tid];
            fbar_all[((size_t)g * 8 + h) * 256 + tid] = a;
        }
    }
}

// ---------------- k_pool ----------------
__global__ __launch_bounds__(256) void k_pool(
    const float* __restrict__ fbar_all, const float* __restrict__ F,
    const float* __restrict__ bvc,
    const float* __restrict__ fc_w, const float* __restrict__ fc_b,
    float* __restrict__ out)
{
    const int g0 = blockIdx.x * 4;
    const int tid = threadIdx.x;
    __shared__ __align__(16) float sfb[32 * 256];
    __shared__ __align__(16) float sp[4 * 256];
    for (int idx = tid; idx < 8192; idx += 256)
        sfb[idx] = fbar_all[(size_t)g0 * 8 * 256 + idx];
    __syncthreads();

    float p[4];
    float bb = bvc[tid];
    #pragma unroll
    for (int j = 0; j < 4; ++j) p[j] = bb;
    for (int k = 0; k < 2048; ++k) {
        float f = F[(size_t)k * 256 + tid];
        #pragma unroll
        for (int j = 0; j < 4; ++j) p[j] += sfb[j * 2048 + k] * f;
    }
    #pragma unroll
    for (int j = 0; j < 4; ++j) sp[j * 256 + tid] = p[j];
    __syncthreads();

    float y[4];
    float fb = fc_b[tid];
    #pragma unroll
    for (int j = 0; j < 4; ++j) y[j] = fb;
    for (int e = 0; e < 256; ++e) {
        float w = fc_w[(size_t)e * 256 + tid];
        #pragma unroll
        for (int j = 0; j < 4; ++j) y[j] += sp[j * 256 + e] * w;
    }
    #pragma unroll
    for (int j = 0; j < 4; ++j)
        out[(size_t)(g0 + j) * 256 + tid] = y[j];
}

// ---------------- launch ----------------
extern "C" void kernel_launch(void* const* d_in, const int* in_sizes, int n_in,
                              void* d_out, int out_size, void* d_ws, size_t ws_size,
                              hipStream_t stream) {
    (void)in_sizes; (void)n_in; (void)out_size;

    const float* av1   = (const float*)d_in[0];
    const float* av2   = (const float*)d_in[1];
    const float* w1    = (const float*)d_in[2];
    const float* b1c   = (const float*)d_in[3];
    const float* g1    = (const float*)d_in[4];
    const float* be1   = (const float*)d_in[5];
    const float* m1    = (const float*)d_in[6];
    const float* v1    = (const float*)d_in[7];
    const float* w2    = (const float*)d_in[8];
    const float* b2c   = (const float*)d_in[9];
    const float* g2    = (const float*)d_in[10];
    const float* be2   = (const float*)d_in[11];
    const float* m2    = (const float*)d_in[12];
    const float* v2    = (const float*)d_in[13];
    const float* w3    = (const float*)d_in[14];
    const float* b3c   = (const float*)d_in[15];
    const float* g3    = (const float*)d_in[16];
    const float* be3   = (const float*)d_in[17];
    const float* m3    = (const float*)d_in[18];
    const float* v3    = (const float*)d_in[19];
    const float* Wq    = (const float*)d_in[20];
    const float* bq    = (const float*)d_in[21];
    const float* Wk    = (const float*)d_in[22];
    const float* bk    = (const float*)d_in[23];
    const float* Wv    = (const float*)d_in[24];
    const float* bv    = (const float*)d_in[25];
    const float* fca_w = (const float*)d_in[26];
    const float* fca_b = (const float*)d_in[27];
    const float* fc_w  = (const float*)d_in[28];
    const float* fc_b  = (const float*)d_in[29];
    (void)bk;

    float* ws = (float*)d_ws;
    float* feat = ws;                         //  5,767,168 f
    float* Mm   = feat + 5767168;             //    524,288 f
    float* WkT  = Mm + 524288;                //    524,288 f
    float* kb   = WkT + 524288;               //      2,048 f
    float* bvc  = kb + 2048;                  //        256 f
    float* F    = bvc + 256;                  //    524,288 f
    float* fbar = F + 524288;                 //  2,097,152 f
    ushort* w2f = (ushort*)(fbar + 2097152);  //    212,992 u16
    ushort* w3f = w2f + 212992;               //    819,200 u16
    ushort* mfr = w3f + 819200;               //    524,288 u16
    ushort* region = mfr + 524288;            // a2f chunk

    size_t base_bytes = (size_t)((char*)region - (char*)d_ws);
    size_t budget = (ws_size > base_bytes + 4096) ? (ws_size - base_bytes - 4096) : 0;
    int ncA = 16;
    const int cand[5] = {1, 2, 4, 8, 16};
    for (int i = 0; i < 5; ++i) { if ((size_t)144179200 / cand[i] <= budget) { ncA = cand[i]; break; } }
    const int seqsA = NSEQ / ncA;

    // setup: 3 launches
    k_prep_misc<<<6217, 256, 0, stream>>>(w2, w2f, w3, w3f, Wk, WkT,
                                          bq, kb, bv, fca_w, fca_b, bvc, Wv, F);
    k_prep_attn_m<<<128, 256, 0, stream>>>(Wq, WkT, Mm);
    k_prep_mfrag<<<2048, 256, 0, stream>>>(Mm, mfr);

    // conv pipeline (a2f chunked through region)
    ushort* a2f = region;
    for (int c = 0; c < ncA; ++c) {
        int seqoff = c * seqsA;
        k_conv<<<seqsA / 8, 512, 0, stream>>>(av1, av2,
            w1, b1c, g1, be1, m1, v1,
            w2f, b2c, g2, be2, m2, v2,
            a2f, seqoff);
        k_conv3<<<seqsA / 64, 256, 0, stream>>>(a2f, w3f,
            b3c, g3, be3, m3, v3, feat, seqoff);
    }

    // fused attention + head
    k_attn_f<<<1024, 256, 0, stream>>>(feat, mfr, kb, fbar);
    k_pool<<<256, 256, 0, stream>>>(fbar, F, bvc, fc_w, fc_b, (float*)d_out);
}

// Round 9
// 581.156 us; speedup vs baseline: 9.3860x; 1.0348x over previous
//
#include <hip/hip_runtime.h>
#include <hip/hip_bf16.h>
#include <math.h>

// ---------------- problem constants ----------------
#define NSEQ 22528
#define HALFSEQ 11264

typedef __attribute__((ext_vector_type(8))) short short8;
typedef __attribute__((ext_vector_type(4))) float f32x4;
typedef __attribute__((ext_vector_type(4))) ushort ushort4v;

__device__ __forceinline__ ushort f2bf(float x) {
    __hip_bfloat16 h = __float2bfloat16(x);
    return *reinterpret_cast<ushort*>(&h);
}
__device__ __forceinline__ float bf2f(ushort u) {
    unsigned v = ((unsigned)u) << 16;
    return *reinterpret_cast<float*>(&v);
}

// ---------------- merged setup: WkT, kb, bvc, F ----------------
// grid 2185: [0,2048) WkT | [2048,2056) kb | [2056] bvc | [2057,2185) F
__global__ __launch_bounds__(256) void k_prep_misc(
    const float* __restrict__ Wk, float* __restrict__ WkT,
    const float* __restrict__ bq, float* __restrict__ kb,
    const float* __restrict__ bv, const float* __restrict__ fca_w,
    const float* __restrict__ fca_b, float* __restrict__ bvc,
    const float* __restrict__ Wv, float* __restrict__ F)
{
    __shared__ float smem[16 * 256];
    const int bid = blockIdx.x;
    const int tid = threadIdx.x;

    if (bid < 2048) {
        int idx = bid * 256 + tid;
        int b = idx >> 16;
        int rem = idx & 65535;
        int c = rem >> 8;
        int r = rem & 255;
        WkT[idx] = Wk[(size_t)(b * 256 + r) * 256 + c];
    } else if (bid < 2056) {
        int h = bid - 2048;
        smem[tid] = bq[h * 256 + tid];
        __syncthreads();
        const float* wk = Wk + (size_t)(h * 256 + tid) * 256;
        float a = 0.f;
        for (int o = 0; o < 256; ++o) a += wk[o] * smem[o];
        kb[h * 256 + tid] = a;
    } else if (bid < 2057) {
        for (int i = tid; i < 2048; i += 256) smem[i] = bv[i];
        __syncthreads();
        float acc = fca_b[tid];
        for (int k = 0; k < 2048; ++k) acc += smem[k] * fca_w[(size_t)k * 256 + tid];
        bvc[tid] = acc;
    } else {
        int lb = bid - 2057;
        int h = lb >> 4;
        int e0 = (lb & 15) * 16;
        for (int idx = tid; idx < 4096; idx += 256) {
            int r = idx >> 8;
            int c = idx & 255;
            smem[r * 256 + c] = Wv[(size_t)h * 65536 + (e0 + r) * 256 + c];
        }
        __syncthreads();
        float acc[16];
        #pragma unroll
        for (int r = 0; r < 16; ++r) acc[r] = 0.f;
        for (int o = 0; o < 256; ++o) {
            float w = fca_w[(size_t)(h * 256 + o) * 256 + tid];
            #pragma unroll
            for (int r = 0; r < 16; ++r) acc[r] += smem[r * 256 + o] * w;
        }
        #pragma unroll
        for (int r = 0; r < 16; ++r)
            F[(size_t)(h * 256 + e0 + r) * 256 + tid] = acc[r];
    }
}

// ---------------- w2f fragment pack via LDS tile ----------------
__global__ __launch_bounds__(256) void k_prep_w2t(
    const float* __restrict__ w2, ushort* __restrict__ w2f)
{
    __shared__ float tile[13312];
    const int mt = blockIdx.x >> 1;
    const int ich = blockIdx.x & 1;
    const int tid = threadIdx.x;
    for (int idx = tid; idx < 13312; idx += 256) {
        int oc16 = idx / 832;
        int rem = idx - oc16 * 832;
        tile[idx] = w2[(size_t)(mt * 16 + oc16) * 1664 + ich * 832 + rem];
    }
    __syncthreads();
    for (int wi = tid; wi < 26 * 512; wi += 256) {
        int t = wi >> 9;
        int li = wi & 511;
        int lane = li >> 3;
        int j = li & 7;
        int oc16 = lane & 15;
        int il = ((lane >> 4) << 3) + j;
        w2f[(size_t)(((2 * t + ich) * 8 + mt) << 9) + li] = f2bf(tile[oc16 * 832 + il * 26 + t]);
    }
}

// ---------------- w3f fragment pack via LDS tile ----------------
__global__ __launch_bounds__(256) void k_prep_w3t(
    const float* __restrict__ w3, ushort* __restrict__ w3f)
{
    __shared__ float tile[12800];
    const int mt = blockIdx.x >> 2;
    const int icb = blockIdx.x & 3;
    const int tid = threadIdx.x;
    for (int idx = tid; idx < 12800; idx += 256) {
        int oc16 = idx / 800;
        int rem = idx - oc16 * 800;
        tile[idx] = w3[(size_t)(mt * 16 + oc16) * 3200 + icb * 800 + rem];
    }
    __syncthreads();
    for (int wi = tid; wi < 25 * 512; wi += 256) {
        int pos = wi >> 9;
        int li = wi & 511;
        int lane = li >> 3;
        int j = li & 7;
        int oc16 = lane & 15;
        int il = ((lane >> 4) << 3) + j;
        w3f[(size_t)(((pos * 4 + icb) * 16 + mt) << 9) + li] = f2bf(tile[oc16 * 800 + il * 25 + pos]);
    }
}

// ---------------- setup: M = Wq Wk^T ----------------
__global__ __launch_bounds__(256) void k_prep_attn_m(
    const float* __restrict__ Wq, const float* __restrict__ WkT,
    float* __restrict__ M)
{
    const int h = blockIdx.x >> 4;
    const int e0 = (blockIdx.x & 15) * 16;
    const int tid = threadIdx.x;
    __shared__ float sq[16][256];
    for (int idx = tid; idx < 4096; idx += 256) {
        int r = idx >> 8;
        int c = idx & 255;
        sq[r][c] = Wq[(size_t)(h * 256 + e0 + r) * 256 + c];
    }
    __syncthreads();
    float acc[16];
    #pragma unroll
    for (int r = 0; r < 16; ++r) acc[r] = 0.f;
    const float* wkt = WkT + (size_t)h * 65536 + tid;
    for (int o = 0; o < 256; ++o) {
        float wk = wkt[o * 256];
        #pragma unroll
        for (int r = 0; r < 16; ++r) acc[r] += sq[r][o] * wk;
    }
    #pragma unroll
    for (int r = 0; r < 16; ++r)
        M[(size_t)(h * 256 + e0 + r) * 256 + tid] = acc[r];
}

// ---------------- setup: Mfrag + kbf ----------------
__global__ void k_prep_mfrag(const float* __restrict__ M, ushort* __restrict__ Mfrag,
                             const float* __restrict__ kb, ushort* __restrict__ kbf) {
    int bid = blockIdx.x;
    int tid = threadIdx.x;
    if (bid < 2048) {
        int idx = bid * 256 + tid;
        int j = idx & 7;
        int lane = (idx >> 3) & 63;
        int mt = (idx >> 9) & 15;
        int kt = (idx >> 13) & 7;
        int h = idx >> 16;
        int e = kt * 32 + ((lane >> 4) << 3) + j;
        int o = mt * 16 + (lane & 15);
        Mfrag[idx] = f2bf(M[(size_t)(h * 256 + e) * 256 + o]);
    } else {
        int idx = (bid - 2048) * 256 + tid;
        int j = idx & 7;
        int lane = (idx >> 3) & 63;
        int kt = idx >> 9;
        int h = lane & 15;
        int e = kt * 32 + ((lane >> 4) << 3) + j;
        kbf[idx] = (h < 8) ? f2bf(kb[h * 256 + e]) : (ushort)0;
    }
}

// ---------------- conv1 + conv2 MFMA, J=8 seqs/block, 512 threads ----------------
__global__ __launch_bounds__(512, 4) void k_conv(
    const float* __restrict__ av1, const float* __restrict__ av2,
    const float* __restrict__ w1,
    const float* __restrict__ b1c, const float* __restrict__ g1,
    const float* __restrict__ be1, const float* __restrict__ m1, const float* __restrict__ v1,
    const ushort* __restrict__ w2f,
    const float* __restrict__ b2c, const float* __restrict__ g2,
    const float* __restrict__ be2, const float* __restrict__ m2, const float* __restrict__ v2,
    ushort* __restrict__ a2f, int seqoff)
{
    __shared__ ushort s_a1[8 * 3200];
    __shared__ ushort s_w1f[2048];
    __shared__ ushort s_xb[8][80];
    __shared__ float s_sc1[64], s_sh1[64], s_sc2[128], s_sh2[128];

    const int tid = threadIdx.x;
    const int lane = tid & 63;
    const int w = tid >> 6;
    const int l15 = lane & 15;
    const int grp = lane >> 4;
    const int lseq0 = blockIdx.x * 8;
    const int gseq0 = seqoff + lseq0;

    for (int idx = tid; idx < 640; idx += 512) {
        int s = idx / 80;
        int i = idx - s * 80;
        int seq = gseq0 + s;
        const float* src;
        if (seq < HALFSEQ) { int b = seq / 22; int n = seq - b * 22; src = av1 + b * 600 + n * 25; }
        else { int q = seq - HALFSEQ; int b = q / 22; int n = q - b * 22; src = av2 + b * 600 + n * 25; }
        s_xb[s][i] = f2bf((i < 75) ? src[i] : 0.f);
    }
    for (int idx = tid; idx < 2048; idx += 512) {
        int j = idx & 7;
        int ln = (idx >> 3) & 63;
        int mt = idx >> 9;
        int oc = mt * 16 + (ln & 15);
        int k = ((ln >> 4) << 3) + j;
        s_w1f[idx] = (k < 26) ? f2bf(w1[oc * 26 + k]) : (ushort)0;
    }
    if (tid < 64) { float A = g1[tid] * rsqrtf(v1[tid] + 1e-5f); s_sc1[tid] = A; s_sh1[tid] = (b1c[tid] - m1[tid]) * A + be1[tid]; }
    if (tid >= 128 && tid < 256) {
        int o = tid - 128;
        float A = g2[o] * rsqrtf(v2[o] + 1e-5f); s_sc2[o] = A; s_sh2[o] = (b2c[o] - m2[o]) * A + be2[o];
    }
    __syncthreads();

    // ---- conv1 MFMA ----
    {
        short8 a1f[4];
        #pragma unroll
        for (int mt = 0; mt < 4; ++mt)
            a1f[mt] = *(const short8*)(s_w1f + mt * 512 + lane * 8);

        for (int nt = w; nt < 25; nt += 8) {
            int n = nt * 16 + l15;
            int s = n / 50;
            int p = n - s * 50;
            short8 bf;
            #pragma unroll
            for (int j = 0; j < 8; ++j) {
                int t = grp * 8 + j;
                bf[j] = (t < 26) ? (short)s_xb[s][p + t] : (short)0;
            }
            #pragma unroll
            for (int mt = 0; mt < 4; ++mt) {
                f32x4 acc1 = (f32x4){0.f, 0.f, 0.f, 0.f};
                acc1 = __builtin_amdgcn_mfma_f32_16x16x32_bf16(a1f[mt], bf, acc1, 0, 0, 0);
                int oc0 = mt * 16 + grp * 4;
                int icb = oc0 >> 3;
                int boff = s * 6400 + icb * 800 + p * 16 + (oc0 & 7) * 2;
                ushort4v u;
                #pragma unroll
                for (int r = 0; r < 4; ++r) {
                    float y = acc1[r] * s_sc1[oc0 + r] + s_sh1[oc0 + r];
                    y = y / (1.f + __expf(-y));
                    u[r] = f2bf(y);
                }
                *(ushort4v*)((char*)s_a1 + boff) = u;
            }
        }
    }
    __syncthreads();

    // ---- conv2 MFMA ----
    {
        const int mset = w & 3;
        const int nset = w >> 2;
        const int NT = nset ? 6 : 7;

        int vaddr[7];
        #pragma unroll
        for (int ni = 0; ni < 7; ++ni) {
            int nt = nset * 7 + ni;
            int n = nt * 16 + l15;
            int s = n / 25; if (s > 7) s = 7;
            int p = n - s * 25; if (p > 24) p = 24;
            vaddr[ni] = s * 6400 + grp * 800 + p * 16;
        }

        f32x4 acc[2][7];
        #pragma unroll
        for (int mi = 0; mi < 2; ++mi)
            #pragma unroll
            for (int ni = 0; ni < 7; ++ni)
                acc[mi][ni] = (f32x4){0.f, 0.f, 0.f, 0.f};

        const ushort* wpt = w2f + (size_t)(mset * 2) * 512 + lane * 8;
        short8 afA0 = *(const short8*)(wpt);
        short8 afA1 = *(const short8*)(wpt + 512);
        short8 afB0 = *(const short8*)(wpt + 4096);
        short8 afB1 = *(const short8*)(wpt + 4096 + 512);

        for (int t = 0; t < 26; ++t) {
            #pragma unroll
            for (int ni = 0; ni < 7; ++ni) {
                if (ni >= NT) break;
                short8 bf = *(const short8*)((const char*)s_a1 + vaddr[ni]);
                acc[0][ni] = __builtin_amdgcn_mfma_f32_16x16x32_bf16(afA0, bf, acc[0][ni], 0, 0, 0);
                acc[1][ni] = __builtin_amdgcn_mfma_f32_16x16x32_bf16(afA1, bf, acc[1][ni], 0, 0, 0);
            }
            if (t < 25) {
                afA0 = *(const short8*)(wpt + 8192);
                afA1 = *(const short8*)(wpt + 8192 + 512);
            }
            #pragma unroll
            for (int ni = 0; ni < 7; ++ni) {
                if (ni >= NT) break;
                short8 bf = *(const short8*)((const char*)s_a1 + vaddr[ni] + 3200);
                acc[0][ni] = __builtin_amdgcn_mfma_f32_16x16x32_bf16(afB0, bf, acc[0][ni], 0, 0, 0);
                acc[1][ni] = __builtin_amdgcn_mfma_f32_16x16x32_bf16(afB1, bf, acc[1][ni], 0, 0, 0);
            }
            if (t < 25) {
                afB0 = *(const short8*)(wpt + 12288);
                afB1 = *(const short8*)(wpt + 12288 + 512);
                wpt += 8192;
            }
            #pragma unroll
            for (int ni = 0; ni < 7; ++ni) vaddr[ni] += 16;
        }

        #pragma unroll
        for (int mi = 0; mi < 2; ++mi) {
            const int ocb = mset * 32 + mi * 16 + grp * 4;
            const int grp_dst = (ocb >> 3) & 3;
            const int jb = ocb & 7;
            const int kthi = ocb >> 5;
            #pragma unroll
            for (int ni = 0; ni < 7; ++ni) {
                if (ni >= NT) break;
                int n = (nset * 7 + ni) * 16 + l15;
                if (n < 200) {
                    int s = n / 25;
                    int p = n - s * 25;
                    int seq = lseq0 + s;
                    int kt3 = p * 4 + kthi;
                    ushort4v u;
                    #pragma unroll
                    for (int r = 0; r < 4; ++r) {
                        float y = acc[mi][ni][r] * s_sc2[ocb + r] + s_sh2[ocb + r];
                        y = y / (1.f + __expf(-y));
                        u[r] = f2bf(y);
                    }
                    *(ushort4v*)(a2f + (((size_t)(seq >> 4) * 100 + kt3) << 9)
                                 + ((seq & 15) + 16 * grp_dst) * 8 + jb) = u;
                }
            }
        }
    }
}

// ---------------- conv3 MFMA: M=128 (half, bid&1), N=64 seqs, K=3200 ----------------
__global__ __launch_bounds__(256) void k_conv3(
    const ushort* __restrict__ a2f, const ushort* __restrict__ w3f,
    const float* __restrict__ b3c, const float* __restrict__ g3,
    const float* __restrict__ be3, const float* __restrict__ m3, const float* __restrict__ v3,
    float* __restrict__ feat, int seqoff)
{
    const int tid = threadIdx.x;
    const int lane = tid & 63;
    const int wv = tid >> 6;
    const int l15 = lane & 15;
    const int grp = lane >> 4;
    const int sb = blockIdx.x >> 1;
    const int mh = blockIdx.x & 1;
    const int lseq0 = sb * 64;
    const int mtb = mh * 8 + wv * 2;

    f32x4 acc3[2][4];
    #pragma unroll
    for (int mi = 0; mi < 2; ++mi)
        #pragma unroll
        for (int nt = 0; nt < 4; ++nt)
            acc3[mi][nt] = (f32x4){0.f, 0.f, 0.f, 0.f};

    const ushort* bp = a2f + ((size_t)(lseq0 >> 4) * 100) * 512 + lane * 8;
    const ushort* ap = w3f + (size_t)mtb * 512 + lane * 8;

    for (int kt = 0; kt < 100; ++kt) {
        short8 bf[4];
        #pragma unroll
        for (int nt = 0; nt < 4; ++nt)
            bf[nt] = *(const short8*)(bp + (size_t)(nt * 100 + kt) * 512);
        #pragma unroll
        for (int mi = 0; mi < 2; ++mi) {
            short8 af = *(const short8*)(ap + (size_t)kt * 8192 + mi * 512);
            #pragma unroll
            for (int nt = 0; nt < 4; ++nt)
                acc3[mi][nt] = __builtin_amdgcn_mfma_f32_16x16x32_bf16(af, bf[nt], acc3[mi][nt], 0, 0, 0);
        }
    }

    #pragma unroll
    for (int nt = 0; nt < 4; ++nt) {
        int gseq = seqoff + lseq0 + nt * 16 + l15;
        #pragma unroll
        for (int mi = 0; mi < 2; ++mi) {
            int oc = (mtb + mi) * 16 + grp * 4;
            float4 o4;
            #pragma unroll
            for (int r = 0; r < 4; ++r) {
                float A = g3[oc + r] * rsqrtf(v3[oc + r] + 1e-5f);
                float y = acc3[mi][nt][r] * A + (b3c[oc + r] - m3[oc + r]) * A + be3[oc + r];
                ((float*)&o4)[r] = y / (1.f + __expf(-y));
            }
            *(float4*)(feat + (size_t)gseq * 256 + oc) = o4;
        }
    }
}

// ---------------- fused attention v2: 2 groups/block, 512 threads (8 waves) ----------------
// grid 512. Mfrag amortized over 2 groups; beta via MFMA; fbar from bf16 LDS.
__global__ __launch_bounds__(512, 2) void k_attn_f(
    const float* __restrict__ feat, const ushort* __restrict__ Mfrag,
    const ushort* __restrict__ kbf, float* __restrict__ fbar_all)
{
    const int g0 = blockIdx.x * 2;
    const int tid = threadIdx.x;
    const int lane = tid & 63;
    const int wv = tid >> 6;         // 0..7
    const int l15 = lane & 15;
    const int grp = lane >> 4;

    __shared__ __align__(16) ushort sfb[2 * 32 * 256];   // 32 KB bf16 swizzled
    __shared__ __align__(16) ushort sG[2 * 32 * 256];    // 32 KB
    __shared__ float sS[2 * 528];
    __shared__ float sbet[2 * 192];
    __shared__ float sab[2 * 24];

    char* const sfbb = (char*)sfb;
    char* const sGb = (char*)sG;

    // ---- load feat (2 groups) -> bf16 swizzled ----
    for (int idx = tid; idx < 16384; idx += 512) {
        int gg = idx >> 13;
        int s = (idx >> 8) & 31;
        int e = idx & 255;
        float f = (s < 22) ? feat[(size_t)(g0 + gg) * 5632 + s * 256 + e] : 0.f;
        int byte = gg * 16384 + s * 512 + ((e * 2) ^ ((s & 7) << 4));
        *(ushort*)(sfbb + byte) = f2bf(f);
    }
    __syncthreads();

    // ---- beta via MFMA: waves 0..3: (gg, row-half); D[t][h] ----
    if (wv < 4) {
        int gg = wv >> 1;
        int rowb = (wv & 1) * 16;
        int rA = rowb + l15;
        f32x4 acc = (f32x4){0.f, 0.f, 0.f, 0.f};
        for (int kt = 0; kt < 8; ++kt) {
            int e0b = (kt * 32 + grp * 8) * 2;
            short8 af = *(const short8*)(sfbb + gg * 16384 + rA * 512 + (e0b ^ ((rA & 7) << 4)));
            short8 bf = *(const short8*)(kbf + kt * 512 + lane * 8);
            acc = __builtin_amdgcn_mfma_f32_16x16x32_bf16(af, bf, acc, 0, 0, 0);
        }
        #pragma unroll
        for (int r = 0; r < 4; ++r) {
            int t = rowb + grp * 4 + r;
            int h = l15;
            if (t < 22 && h < 8) sbet[gg * 192 + h * 24 + t] = acc[r];
        }
    }
    __syncthreads();

    for (int h = 0; h < 8; ++h) {
        // ---- G-step: wave wv owns f-tiles {2wv, 2wv+1}; A = 4 mt (2 groups x 2 halves) ----
        {
            f32x4 accg[4][2];
            #pragma unroll
            for (int mt = 0; mt < 4; ++mt)
                #pragma unroll
                for (int fi = 0; fi < 2; ++fi)
                    accg[mt][fi] = (f32x4){0.f, 0.f, 0.f, 0.f};

            const ushort* mfb = Mfrag + (size_t)h * 65536;
            for (int kt = 0; kt < 8; ++kt) {
                int e0b = (kt * 32 + grp * 8) * 2;
                short8 af[4];
                #pragma unroll
                for (int mt = 0; mt < 4; ++mt) {
                    int gg = mt >> 1;
                    int rA = (mt & 1) * 16 + l15;
                    af[mt] = *(const short8*)(sfbb + gg * 16384 + rA * 512 + (e0b ^ ((rA & 7) << 4)));
                }
                #pragma unroll
                for (int fi = 0; fi < 2; ++fi) {
                    int ft = wv * 2 + fi;
                    short8 bfm = *(const short8*)(mfb + (size_t)((kt * 16 + ft) << 9) + lane * 8);
                    #pragma unroll
                    for (int mt = 0; mt < 4; ++mt)
                        accg[mt][fi] = __builtin_amdgcn_mfma_f32_16x16x32_bf16(af[mt], bfm, accg[mt][fi], 0, 0, 0);
                }
            }
            #pragma unroll
            for (int mt = 0; mt < 4; ++mt) {
                int gg = mt >> 1;
                #pragma unroll
                for (int fi = 0; fi < 2; ++fi) {
                    int f = (wv * 2 + fi) * 16 + l15;
                    #pragma unroll
                    for (int r = 0; r < 4; ++r) {
                        int s = (mt & 1) * 16 + grp * 4 + r;
                        if (s < 22) {
                            int byte = gg * 16384 + s * 512 + ((f * 2) ^ ((s & 7) << 4));
                            *(ushort*)(sGb + byte) = f2bf(accg[mt][fi][r]);
                        }
                    }
                }
            }
        }
        __syncthreads();

        // ---- S-step: 8 tiles (2 gg x 2 mt x 2 nt), one per wave ----
        {
            int gg = wv >> 2;
            int mt2 = (wv >> 1) & 1;
            int nt2 = wv & 1;
            f32x4 sacc = (f32x4){0.f, 0.f, 0.f, 0.f};
            int sA = mt2 * 16 + l15;
            int tB = nt2 * 16 + l15;
            for (int kt = 0; kt < 8; ++kt) {
                int f0b = (kt * 32 + grp * 8) * 2;
                short8 ga = *(const short8*)(sGb + gg * 16384 + sA * 512 + (f0b ^ ((sA & 7) << 4)));
                short8 fb = *(const short8*)(sfbb + gg * 16384 + tB * 512 + (f0b ^ ((tB & 7) << 4)));
                sacc = __builtin_amdgcn_mfma_f32_16x16x32_bf16(ga, fb, sacc, 0, 0, 0);
            }
            #pragma unroll
            for (int r = 0; r < 4; ++r) {
                int s = mt2 * 16 + grp * 4 + r;
                int t = nt2 * 16 + l15;
                if (s < 22 && t < 22)
                    sS[gg * 528 + s * 24 + t] = sacc[r] + sbet[gg * 192 + h * 24 + t];
            }
        }
        __syncthreads();

        // ---- softmax rows (44 parallel) ----
        if (tid < 44) {
            int gg = tid >= 22;
            int s = tid - gg * 22;
            float* row = sS + gg * 528 + s * 24;
            float mx = -1e30f;
            #pragma unroll
            for (int t = 0; t < 22; ++t) mx = fmaxf(mx, row[t]);
            float ex[22];
            float sum = 0.f;
            #pragma unroll
            for (int t = 0; t < 22; ++t) { float e2 = __expf(row[t] - mx); ex[t] = e2; sum += e2; }
            float inv = 1.f / sum;
            #pragma unroll
            for (int t = 0; t < 22; ++t) row[t] = ex[t] * inv;
        }
        __syncthreads();
        if (tid < 44) {
            int gg = tid >= 22;
            int t = tid - gg * 22;
            float a = 0.f;
            #pragma unroll
            for (int s = 0; s < 22; ++s) a += sS[gg * 528 + s * 24 + t];
            sab[gg * 24 + t] = a * (1.f / 22.f);
        }
        __syncthreads();

        // ---- fbar[e] = sum_t Abar[t] * feat_bf16[t][e]; 512 threads = 2 gg x 256 e ----
        {
            int gg = tid >> 8;
            int e = tid & 255;
            int e2b = e * 2;
            float a = 0.f;
            #pragma unroll
            for (int t = 0; t < 22; ++t) {
                ushort u = *(ushort*)(sfbb + gg * 16384 + t * 512 + (e2b ^ ((t & 7) << 4)));
                a += sab[gg * 24 + t] * bf2f(u);
            }
            fbar_all[((size_t)(g0 + gg) * 8 + h) * 256 + e] = a;
        }
        __syncthreads();
    }
}

// ---------------- k_pool: 8 groups/block ----------------
__global__ __launch_bounds__(256) void k_pool(
    const float* __restrict__ fbar_all, const float* __restrict__ F,
    const float* __restrict__ bvc,
    const float* __restrict__ fc_w, const float* __restrict__ fc_b,
    float* __restrict__ out)
{
    const int g0 = blockIdx.x * 8;
    const int tid = threadIdx.x;
    __shared__ __align__(16) float sfb[8 * 2048];
    __shared__ __align__(16) float sp[8 * 256];
    for (int idx = tid; idx < 16384; idx += 256)
        sfb[idx] = fbar_all[(size_t)g0 * 8 * 256 + idx];
    __syncthreads();

    float p[8];
    float bb = bvc[tid];
    #pragma unroll
    for (int j = 0; j < 8; ++j) p[j] = bb;
    for (int k = 0; k < 2048; k += 4) {
        float f0 = F[(size_t)(k + 0) * 256 + tid];
        float f1 = F[(size_t)(k + 1) * 256 + tid];
        float f2 = F[(size_t)(k + 2) * 256 + tid];
        float f3 = F[(size_t)(k + 3) * 256 + tid];
        #pragma unroll
        for (int j = 0; j < 8; ++j) {
            float4 v = *(const float4*)(sfb + j * 2048 + k);
            p[j] += v.x * f0 + v.y * f1 + v.z * f2 + v.w * f3;
        }
    }
    #pragma unroll
    for (int j = 0; j < 8; ++j) sp[j * 256 + tid] = p[j];
    __syncthreads();

    float y[8];
    float fb = fc_b[tid];
    #pragma unroll
    for (int j = 0; j < 8; ++j) y[j] = fb;
    for (int e = 0; e < 256; ++e) {
        float w = fc_w[(size_t)e * 256 + tid];
        #pragma unroll
        for (int j = 0; j < 8; ++j) y[j] += sp[j * 256 + e] * w;
    }
    #pragma unroll
    for (int j = 0; j < 8; ++j)
        out[(size_t)(g0 + j) * 256 + tid] = y[j];
}

// ---------------- launch ----------------
extern "C" void kernel_launch(void* const* d_in, const int* in_sizes, int n_in,
                              void* d_out, int out_size, void* d_ws, size_t ws_size,
                              hipStream_t stream) {
    (void)in_sizes; (void)n_in; (void)out_size;

    const float* av1   = (const float*)d_in[0];
    const float* av2   = (const float*)d_in[1];
    const float* w1    = (const float*)d_in[2];
    const float* b1c   = (const float*)d_in[3];
    const float* g1    = (const float*)d_in[4];
    const float* be1   = (const float*)d_in[5];
    const float* m1    = (const float*)d_in[6];
    const float* v1    = (const float*)d_in[7];
    const float* w2    = (const float*)d_in[8];
    const float* b2c   = (const float*)d_in[9];
    const float* g2    = (const float*)d_in[10];
    const float* be2   = (const float*)d_in[11];
    const float* m2    = (const float*)d_in[12];
    const float* v2    = (const float*)d_in[13];
    const float* w3    = (const float*)d_in[14];
    const float* b3c   = (const float*)d_in[15];
    const float* g3    = (const float*)d_in[16];
    const float* be3   = (const float*)d_in[17];
    const float* m3    = (const float*)d_in[18];
    const float* v3    = (const float*)d_in[19];
    const float* Wq    = (const float*)d_in[20];
    const float* bq    = (const float*)d_in[21];
    const float* Wk    = (const float*)d_in[22];
    const float* bk    = (const float*)d_in[23];
    const float* Wv    = (const float*)d_in[24];
    const float* bv    = (const float*)d_in[25];
    const float* fca_w = (const float*)d_in[26];
    const float* fca_b = (const float*)d_in[27];
    const float* fc_w  = (const float*)d_in[28];
    const float* fc_b  = (const float*)d_in[29];
    (void)bk;

    float* ws = (float*)d_ws;
    float* feat = ws;                         //  5,767,168 f
    float* Mm   = feat + 5767168;             //    524,288 f
    float* WkT  = Mm + 524288;                //    524,288 f
    float* kb   = WkT + 524288;               //      2,048 f
    float* bvc  = kb + 2048;                  //        256 f
    float* F    = bvc + 256;                  //    524,288 f
    float* fbar = F + 524288;                 //  2,097,152 f
    ushort* w2f = (ushort*)(fbar + 2097152);  //    212,992 u16
    ushort* w3f = w2f + 212992;               //    819,200 u16
    ushort* mfr = w3f + 819200;               //    524,288 u16
    ushort* kbf = mfr + 524288;               //      4,096 u16
    ushort* region = kbf + 4096;              // a2f chunk

    size_t base_bytes = (size_t)((char*)region - (char*)d_ws);
    size_t budget = (ws_size > base_bytes + 4096) ? (ws_size - base_bytes - 4096) : 0;
    int ncA = 16;
    const int cand[5] = {1, 2, 4, 8, 16};
    for (int i = 0; i < 5; ++i) { if ((size_t)144179200 / cand[i] <= budget) { ncA = cand[i]; break; } }
    const int seqsA = NSEQ / ncA;

    // setup
    k_prep_misc<<<2185, 256, 0, stream>>>(Wk, WkT, bq, kb, bv, fca_w, fca_b, bvc, Wv, F);
    k_prep_w2t<<<16, 256, 0, stream>>>(w2, w2f);
    k_prep_w3t<<<64, 256, 0, stream>>>(w3, w3f);
    k_prep_attn_m<<<128, 256, 0, stream>>>(Wq, WkT, Mm);
    k_prep_mfrag<<<2064, 256, 0, stream>>>(Mm, mfr, kb, kbf);

    // conv pipeline (a2f chunked through region)
    ushort* a2f = region;
    for (int c = 0; c < ncA; ++c) {
        int seqoff = c * seqsA;
        k_conv<<<seqsA / 8, 512, 0, stream>>>(av1, av2,
            w1, b1c, g1, be1, m1, v1,
            w2f, b2c, g2, be2, m2, v2,
            a2f, seqoff);
        k_conv3<<<(seqsA / 64) * 2, 256, 0, stream>>>(a2f, w3f,
            b3c, g3, be3, m3, v3, feat, seqoff);
    }

    // fused attention + head
    k_attn_f<<<512, 512, 0, stream>>>(feat, mfr, kbf, fbar);
    k_pool<<<128, 256, 0, stream>>>(fbar, F, bvc, fc_w, fc_b, (float*)d_out);
}